// Round 3
// baseline (429.553 us; speedup 1.0000x reference)
//
#include <hip/hip_runtime.h>

typedef unsigned short u16;
typedef unsigned int u32;

typedef __attribute__((ext_vector_type(8))) short short8;
typedef __attribute__((ext_vector_type(4))) float floatx4;

__device__ __forceinline__ float bf2f(u16 u) { return __uint_as_float(((u32)u) << 16); }
__device__ __forceinline__ u16 f2bf(float f) {
    u32 x = __float_as_uint(f);
    x += 0x7fffu + ((x >> 16) & 1u);
    return (u16)(x >> 16);
}
__device__ __forceinline__ void gl_lds16(const void* g, void* l) {
    __builtin_amdgcn_global_load_lds((const __attribute__((address_space(1))) u32*)g,
                                     (__attribute__((address_space(3))) u32*)l, 16, 0, 0);
}

// ---------------- Kernel 1: x (B,C,D,H,W) -> t (B,HW,DIM) bf16, + pos ----------------
__global__ __launch_bounds__(256) void k_tpos(const float* __restrict__ x,
                                              const float* __restrict__ pos,
                                              u16* __restrict__ t) {
    __shared__ float tile[64][65];
    const int b = blockIdx.z, hw0 = blockIdx.y * 64, cd0 = blockIdx.x * 64;
    const int tid = threadIdx.x;
#pragma unroll
    for (int i = 0; i < 16; i++) {
        int f = i * 256 + tid;
        int cdl = f >> 6, hwl = f & 63;
        int cd = cd0 + cdl, c = cd >> 3, d = cd & 7;
        tile[cdl][hwl] = x[(size_t)(((b * 96 + c) * 8 + d)) * 1024 + hw0 + hwl];
    }
    __syncthreads();
#pragma unroll
    for (int i = 0; i < 16; i++) {
        int f = i * 256 + tid;
        int hwl = f >> 6, cdl = f & 63;
        float v = tile[cdl][hwl] + pos[(size_t)(hw0 + hwl) * 768 + cd0 + cdl];
        t[(size_t)(b * 1024 + hw0 + hwl) * 768 + cd0 + cdl] = f2bf(v);
    }
}

// ---------------- weight fp32 -> bf16 (qkv_w, proj_w, pw_w concatenated) ----------------
__global__ __launch_bounds__(256) void k_cvt(const float* __restrict__ wq,
                                             const float* __restrict__ wp,
                                             const float* __restrict__ wpw,
                                             u16* __restrict__ out) {
    int i = blockIdx.x * 256 + threadIdx.x;
    const int NQ = 2304 * 768;
    const int NP = NQ + 768 * 768;
    float v;
    if (i < NQ) v = wq[i];
    else if (i < NP) v = wp[i - NQ];
    else v = wpw[i - NP];
    out[i] = f2bf(v);
}

// ---------------- GEMM: C(M,N) = A(M,K) * Bw(N,K)^T, bf16 MFMA ----------------
// LDS held in MFMA fragment order: chunk ch (16 rows x 32 k) of 1024B, element at lane*16.
// MODE 0: QKV epilogue -> q,k [b,h,n,dh] and v transposed [b,h,dh,n]
// MODE 1: proj epilogue -> Co fp32 row-major + bias
template <int MODE>
__global__ __launch_bounds__(256) void gemm_bt(const u16* __restrict__ A,
                                               const u16* __restrict__ Bw,
                                               int M, int N, int K,
                                               u16* __restrict__ qo, u16* __restrict__ ko,
                                               u16* __restrict__ vo,
                                               const float* __restrict__ bias,
                                               float* __restrict__ Co) {
    __shared__ __align__(16) u16 lA[128 * 32];
    __shared__ __align__(16) u16 lB[128 * 32];
    const int tid = threadIdx.x;
    const int lane = tid & 63;
    const int wv = tid >> 6;
    const int wr = wv >> 1, wc = wv & 1;
    const int ntiles = N >> 7;
    const int m0 = (blockIdx.x / ntiles) << 7;
    const int n0 = (blockIdx.x % ntiles) << 7;
    const int lr = lane & 15;
    const int lq = lane >> 4;

    floatx4 acc[4][4];
#pragma unroll
    for (int i = 0; i < 4; i++)
#pragma unroll
        for (int j = 0; j < 4; j++) acc[i][j] = (floatx4){0.f, 0.f, 0.f, 0.f};

    for (int kt = 0; kt < K; kt += 32) {
        __syncthreads();
#pragma unroll
        for (int i = 0; i < 2; i++) {
            int ch = i * 4 + wv;  // 0..7 : 16-row block of the 128-row tile
            const u16* ga = A + (size_t)(m0 + ch * 16 + lr) * K + kt + lq * 8;
            gl_lds16(ga, (char*)lA + ch * 1024);
            const u16* gb = Bw + (size_t)(n0 + ch * 16 + lr) * K + kt + lq * 8;
            gl_lds16(gb, (char*)lB + ch * 1024);
        }
        __syncthreads();
        short8 af[4], bfr[4];
#pragma unroll
        for (int tt = 0; tt < 4; tt++) {
            af[tt] = *(const short8*)(lA + ((wr * 4 + tt) * 64 + lane) * 8);
            bfr[tt] = *(const short8*)(lB + ((wc * 4 + tt) * 64 + lane) * 8);
        }
#pragma unroll
        for (int mt = 0; mt < 4; mt++)
#pragma unroll
            for (int nt = 0; nt < 4; nt++)
                acc[mt][nt] = __builtin_amdgcn_mfma_f32_16x16x32_bf16(af[mt], bfr[nt], acc[mt][nt], 0, 0, 0);
    }

    if (MODE == 0) {
#pragma unroll
        for (int nt = 0; nt < 4; nt++) {
            int col = n0 + wc * 64 + nt * 16 + lr;
            int three = col / 768;
            int rem = col - three * 768;
            int h = rem / 192;
            int dh = rem - h * 192;
#pragma unroll
            for (int mt = 0; mt < 4; mt++) {
#pragma unroll
                for (int r = 0; r < 4; r++) {
                    int row = m0 + wr * 64 + mt * 16 + lq * 4 + r;
                    int b = row >> 10, n = row & 1023;
                    u16 val = f2bf(acc[mt][nt][r]);
                    size_t bh = (size_t)(b * 4 + h);
                    if (three == 0)
                        qo[(bh * 1024 + n) * 192 + dh] = val;
                    else if (three == 1)
                        ko[(bh * 1024 + n) * 192 + dh] = val;
                    else
                        vo[(bh * 192 + dh) * 1024 + n] = val;
                }
            }
        }
    } else {
#pragma unroll
        for (int nt = 0; nt < 4; nt++) {
            int col = n0 + wc * 64 + nt * 16 + lr;
            float bv = bias[col];
#pragma unroll
            for (int mt = 0; mt < 4; mt++) {
#pragma unroll
                for (int r = 0; r < 4; r++) {
                    int row = m0 + wr * 64 + mt * 16 + lq * 4 + r;
                    Co[(size_t)row * N + col] = acc[mt][nt][r] + bv;
                }
            }
        }
    }
}

// ---------------- column sum-of-squares over sequence (for l2norm over dim=-2) ----------------
__global__ void k_sq(const u16* __restrict__ q, const u16* __restrict__ k,
                     float* __restrict__ sqq, float* __restrict__ sqk) {
    int bh = blockIdx.x;
    int part = blockIdx.y;
    int dh = threadIdx.x;  // 192
    const u16* qp = q + ((size_t)bh * 1024 + part * 128) * 192 + dh;
    const u16* kp = k + ((size_t)bh * 1024 + part * 128) * 192 + dh;
    float aq = 0.f, ak = 0.f;
#pragma unroll 4
    for (int n = 0; n < 128; n++) {
        float a = bf2f(qp[(size_t)n * 192]);
        aq += a * a;
        float c2 = bf2f(kp[(size_t)n * 192]);
        ak += c2 * c2;
    }
    atomicAdd(&sqq[bh * 192 + dh], aq);
    atomicAdd(&sqk[bh * 192 + dh], ak);
}

__global__ void k_scale(const float* __restrict__ sqq, const float* __restrict__ sqk,
                        const float* __restrict__ temp, float* __restrict__ cs) {
    int bh = blockIdx.x;
    int dh = threadIdx.x;
    float rq = 1.f / fmaxf(sqrtf(sqq[bh * 192 + dh]), 1e-12f);
    float rk = 1.f / fmaxf(sqrtf(sqk[bh * 192 + dh]), 1e-12f);
    cs[bh * 192 + dh] = rq * rk * temp[bh & 3];
}

// ---------------- flash attention: one WG per (bh, 64-row q block) ----------------
// K/V/P all held in LDS in MFMA fragment order -> every ds_read is base+lane*16 (conflict-free).
// Block mapping: xcd = lin&7, bh = xcd*4 + (lin>>7)  => each XCD sees 4 bh (3MB K+V, fits L2).
__global__ __launch_bounds__(256) void k_attn(const u16* __restrict__ q,
                                              const u16* __restrict__ kmat,
                                              const u16* __restrict__ vT,
                                              const float* __restrict__ cs,
                                              u16* __restrict__ o) {
    __shared__ __align__(16) u16 lK[24 * 512];  // 24KB, chunk(ks,nt): K[nt*16+lr][ks*32+lq*8]
    __shared__ __align__(16) u16 lV[24 * 512];  // 24KB, chunk(ks2,vt): vT[vt*16+lr][ks2*32+lq*8]
    __shared__ __align__(16) u16 lP[4 * 1024];  // 8KB per-wave fragment-order P
    const int lin = blockIdx.x;
    const int qb = (lin >> 3) & 15;
    const int bh = (lin & 7) * 4 + (lin >> 7);
    const int b = bh >> 2, h = bh & 3;
    const int tid = threadIdx.x;
    const int lane = tid & 63;
    const int wv = tid >> 6;
    const int lr = lane & 15;
    const int lq = lane >> 4;
    const int koff = lq * 8;

    const u16* qbase = q + (size_t)bh * 1024 * 192;
    const u16* kbase = kmat + (size_t)bh * 1024 * 192;
    const u16* vbase = vT + (size_t)bh * 192 * 1024;
    const float* cp = cs + bh * 192;

    // Q fragments in registers, scaled by combined norm/temperature factor
    const int qrow = qb * 64 + wv * 16 + lr;
    const u16* qp = qbase + (size_t)qrow * 192;
    short8 qf[6];
#pragma unroll
    for (int ks = 0; ks < 6; ks++) {
        short8 raw = *(const short8*)(qp + ks * 32 + koff);
        short8 sc;
#pragma unroll
        for (int j = 0; j < 8; j++) {
            float f = bf2f((u16)raw[j]) * cp[ks * 32 + koff + j];
            sc[j] = (short)f2bf(f);
        }
        qf[ks] = sc;
    }

    float m_r[4], l_r[4];
    floatx4 oacc[12];
#pragma unroll
    for (int r = 0; r < 4; r++) { m_r[r] = -1e30f; l_r[r] = 0.f; }
#pragma unroll
    for (int vt = 0; vt < 12; vt++) oacc[vt] = (floatx4){0.f, 0.f, 0.f, 0.f};

    u16* lp = lP + wv * 1024;

    for (int kb = 0; kb < 16; kb++) {
        __syncthreads();
        // stage K and V in fragment order: each wave fills 6 chunks of each
#pragma unroll
        for (int i = 0; i < 6; i++) {
            int ch = i * 4 + wv;  // 0..23
            int ks = ch >> 2, nt = ch & 3;
            const u16* gk = kbase + (size_t)(kb * 64 + nt * 16 + lr) * 192 + ks * 32 + koff;
            gl_lds16(gk, (char*)lK + ch * 1024);
            int ks2 = ch / 12, vt2 = ch - ks2 * 12;
            const u16* gv = vbase + (size_t)(vt2 * 16 + lr) * 1024 + kb * 64 + ks2 * 32 + koff;
            gl_lds16(gv, (char*)lV + ch * 1024);
        }
        __syncthreads();

        // S = Qs * K^T : 4 n-tiles of 16
        floatx4 s[4];
#pragma unroll
        for (int nt = 0; nt < 4; nt++) s[nt] = (floatx4){0.f, 0.f, 0.f, 0.f};
#pragma unroll
        for (int ks = 0; ks < 6; ks++) {
#pragma unroll
            for (int nt = 0; nt < 4; nt++) {
                short8 kf = *(const short8*)(lK + ((ks * 4 + nt) * 64 + lane) * 8);
                s[nt] = __builtin_amdgcn_mfma_f32_16x16x32_bf16(qf[ks], kf, s[nt], 0, 0, 0);
            }
        }

        // online softmax (rows = lq*4 + r, consistent across the 16 lanes of each quad)
        float rmax[4];
#pragma unroll
        for (int r = 0; r < 4; r++)
            rmax[r] = fmaxf(fmaxf(s[0][r], s[1][r]), fmaxf(s[2][r], s[3][r]));
#pragma unroll
        for (int m = 1; m < 16; m <<= 1)
#pragma unroll
            for (int r = 0; r < 4; r++) rmax[r] = fmaxf(rmax[r], __shfl_xor(rmax[r], m));
        float alpha[4];
#pragma unroll
        for (int r = 0; r < 4; r++) {
            float mn = fmaxf(m_r[r], rmax[r]);
            alpha[r] = __expf(m_r[r] - mn);
            m_r[r] = mn;
        }
        float rsum[4] = {0.f, 0.f, 0.f, 0.f};
#pragma unroll
        for (int nt = 0; nt < 4; nt++)
#pragma unroll
            for (int r = 0; r < 4; r++) {
                float p = __expf(s[nt][r] - m_r[r]);
                s[nt][r] = p;
                rsum[r] += p;
            }
#pragma unroll
        for (int m = 1; m < 16; m <<= 1)
#pragma unroll
            for (int r = 0; r < 4; r++) rsum[r] += __shfl_xor(rsum[r], m);
#pragma unroll
        for (int r = 0; r < 4; r++) l_r[r] = l_r[r] * alpha[r] + rsum[r];
#pragma unroll
        for (int vt = 0; vt < 12; vt++)
#pragma unroll
            for (int r = 0; r < 4; r++) oacc[vt][r] *= alpha[r];

        // P -> per-wave LDS directly in A-fragment order:
        // element (m = lq*4+r, n = nt*16+lr) -> u16 addr ks2*512 + readlane*8 + (n&7)
        //   ks2 = nt>>1, readlane = m + 16*((nt&1)*2 + (lr>>3))
#pragma unroll
        for (int nt = 0; nt < 4; nt++) {
            int base2 = (nt >> 1) * 512 + ((nt & 1) * 2 + (lr >> 3)) * 128 + (lr & 7);
#pragma unroll
            for (int r = 0; r < 4; r++)
                lp[base2 + (lq * 4 + r) * 8] = f2bf(s[nt][r]);
        }

        // O += P * V (per-wave P, fragment-order reads)
#pragma unroll
        for (int ks2 = 0; ks2 < 2; ks2++) {
            short8 pf = *(const short8*)(lp + ks2 * 512 + lane * 8);
#pragma unroll
            for (int vt = 0; vt < 12; vt++) {
                short8 vf = *(const short8*)(lV + ((ks2 * 12 + vt) * 64 + lane) * 8);
                oacc[vt] = __builtin_amdgcn_mfma_f32_16x16x32_bf16(pf, vf, oacc[vt], 0, 0, 0);
            }
        }
    }

    // epilogue: divide by l, write to o (B,HW,DIM) bf16
    float inv[4];
#pragma unroll
    for (int r = 0; r < 4; r++) inv[r] = 1.f / l_r[r];
#pragma unroll
    for (int vt = 0; vt < 12; vt++) {
        int dh = vt * 16 + lr;
#pragma unroll
        for (int r = 0; r < 4; r++) {
            int row = qb * 64 + wv * 16 + lq * 4 + r;
            o[(size_t)(b * 1024 + row) * 768 + h * 192 + dh] = f2bf(oacc[vt][r] * inv[r]);
        }
    }
}

// ---------------- LN stats per row ----------------
__global__ __launch_bounds__(256) void k_lnstats(const float* __restrict__ o2,
                                                 float* __restrict__ mu,
                                                 float* __restrict__ rstd) {
    int row = blockIdx.x;
    int tid = threadIdx.x;
    const float* p = o2 + (size_t)row * 768;
    float s = 0.f, ss = 0.f;
    for (int i = tid; i < 768; i += 256) {
        float v = p[i];
        s += v;
        ss += v * v;
    }
#pragma unroll
    for (int m = 32; m >= 1; m >>= 1) {
        s += __shfl_xor(s, m);
        ss += __shfl_xor(ss, m);
    }
    __shared__ float as[4], ass[4];
    if ((tid & 63) == 0) {
        as[tid >> 6] = s;
        ass[tid >> 6] = ss;
    }
    __syncthreads();
    if (tid == 0) {
        float S = as[0] + as[1] + as[2] + as[3];
        float SS = ass[0] + ass[1] + ass[2] + ass[3];
        float m_ = S * (1.f / 768.f);
        float v = SS * (1.f / 768.f) - m_ * m_;
        v = fmaxf(v, 0.f);
        mu[row] = m_;
        rstd[row] = rsqrtf(v + 1e-5f);
    }
}

// ---------------- LN apply + transpose back + residual: y = LN(o2)^T + x ----------------
__global__ __launch_bounds__(256) void k_lnt(const float* __restrict__ o2,
                                             const float* __restrict__ mu,
                                             const float* __restrict__ rstd,
                                             const float* __restrict__ gamma,
                                             const float* __restrict__ beta,
                                             const float* __restrict__ x,
                                             float* __restrict__ y) {
    __shared__ float tile[64][65];
    const int b = blockIdx.z, hw0 = blockIdx.y * 64, cd0 = blockIdx.x * 64;
    const int tid = threadIdx.x;
#pragma unroll
    for (int i = 0; i < 16; i++) {
        int f = i * 256 + tid;
        int hwl = f >> 6, cdl = f & 63;
        int row = b * 1024 + hw0 + hwl;
        float v = o2[(size_t)row * 768 + cd0 + cdl];
        v = (v - mu[row]) * rstd[row] * gamma[cd0 + cdl] + beta[cd0 + cdl];
        tile[hwl][cdl] = v;
    }
    __syncthreads();
#pragma unroll
    for (int i = 0; i < 16; i++) {
        int f = i * 256 + tid;
        int cdl = f >> 6, hwl = f & 63;
        int cd = cd0 + cdl, c = cd >> 3, d = cd & 7;
        size_t addr = (size_t)((b * 96 + c) * 8 + d) * 1024 + hw0 + hwl;
        y[addr] = tile[hwl][cdl] + x[addr];
    }
}

// ---------------- depthwise 3x3x3 conv (x-layout), z = dw(y) + dw_b ----------------
__global__ __launch_bounds__(256) void k_dw(const float* __restrict__ y,
                                            const float* __restrict__ w,
                                            const float* __restrict__ bias,
                                            float* __restrict__ z) {
    int e = blockIdx.x * 256 + threadIdx.x;
    int hw = e & 1023;
    int rest = e >> 10;
    int d = rest & 7;
    int c = (rest >> 3) % 96;
    int h = hw >> 5, ww = hw & 31;
    float acc = bias[c];
    const float* wp = w + c * 27;
#pragma unroll
    for (int kd = 0; kd < 3; kd++) {
        int dd = d + kd - 1;
        if (dd < 0 || dd >= 8) continue;
#pragma unroll
        for (int kh = 0; kh < 3; kh++) {
            int hh = h + kh - 1;
            if ((unsigned)hh >= 32u) continue;
#pragma unroll
            for (int kw = 0; kw < 3; kw++) {
                int w2 = ww + kw - 1;
                if ((unsigned)w2 >= 32u) continue;
                acc += wp[kd * 9 + kh * 3 + kw] * y[e + (kd - 1) * 1024 + (kh - 1) * 32 + (kw - 1)];
            }
        }
    }
    z[e] = acc;
}

// ---------------- pointwise conv via MFMA: out = y + pw_b + W(96x96) * Z(96 x pos) ----------------
__global__ __launch_bounds__(256) void k_pw(const float* __restrict__ z,
                                            const u16* __restrict__ wbf,   // bf16 96x96 [c][cc]
                                            const float* __restrict__ bias,
                                            float* __restrict__ out) {     // also y input (in-place)
    __shared__ __align__(16) u16 lZ[128 * 104];  // [pos][cc], stride 104
    __shared__ __align__(16) u16 lW[96 * 104];   // [c][cc], stride 104
    const int tid = threadIdx.x;
    const int lane = tid & 63;
    const int wv = tid >> 6;
    const int lr = lane & 15;
    const int lq = lane >> 4;
    const int koff = lq * 8;

    const int idx = blockIdx.x;
    const int q = idx & 7;          // pos chunk
    const int bd = idx >> 3;
    const int b = bd >> 3, d = bd & 7;
    const int pos0 = q * 128;

    // stage W -> LDS (rows of 96, stride 104)
    for (int i = tid; i < 96 * 96; i += 256) {
        int row = i / 96, col = i - row * 96;
        lW[row * 104 + col] = wbf[i];
    }

    // stage Z transposed: thread covers pos = tid&127, cc = (tid>>7)*48 .. +47
    {
        const int pos = tid & 127;
        const int cc0 = (tid >> 7) * 48;
        const size_t gbase = ((size_t)b * 96 * 8 + d) * 1024 + pos0 + pos;
#pragma unroll
        for (int g = 0; g < 6; g++) {
            short8 v;
#pragma unroll
            for (int j = 0; j < 8; j++) {
                int cc = cc0 + g * 8 + j;
                v[j] = (short)f2bf(z[gbase + (size_t)cc * 8192]);
            }
            *(short8*)(lZ + pos * 104 + cc0 + g * 8) = v;
        }
    }
    __syncthreads();

    // MFMA: 6 m-tiles (c), 2 n-tiles per wave (pos), K=96 in 3 steps
    floatx4 acc[6][2];
#pragma unroll
    for (int m = 0; m < 6; m++)
#pragma unroll
        for (int nt = 0; nt < 2; nt++) acc[m][nt] = (floatx4){0.f, 0.f, 0.f, 0.f};

#pragma unroll
    for (int ks = 0; ks < 3; ks++) {
        short8 bfrg[2];
#pragma unroll
        for (int nt = 0; nt < 2; nt++)
            bfrg[nt] = *(const short8*)(lZ + (wv * 32 + nt * 16 + lr) * 104 + ks * 32 + koff);
#pragma unroll
        for (int m = 0; m < 6; m++) {
            short8 afr = *(const short8*)(lW + (m * 16 + lr) * 104 + ks * 32 + koff);
#pragma unroll
            for (int nt = 0; nt < 2; nt++)
                acc[m][nt] = __builtin_amdgcn_mfma_f32_16x16x32_bf16(afr, bfrg[nt], acc[m][nt], 0, 0, 0);
        }
    }

    // epilogue: out = y(out) + bias[c] + acc   (each addr read+written by same thread)
#pragma unroll
    for (int m = 0; m < 6; m++) {
#pragma unroll
        for (int r = 0; r < 4; r++) {
            int c = m * 16 + lq * 4 + r;
            float bv = bias[c];
            size_t rowbase = ((size_t)(b * 96 + c) * 8 + d) * 1024 + pos0;
#pragma unroll
            for (int nt = 0; nt < 2; nt++) {
                int pos = wv * 32 + nt * 16 + lr;
                size_t a = rowbase + pos;
                out[a] = out[a] + bv + acc[m][nt][r];
            }
        }
    }
}

extern "C" void kernel_launch(void* const* d_in, const int* in_sizes, int n_in,
                              void* d_out, int out_size, void* d_ws, size_t ws_size,
                              hipStream_t stream) {
    (void)in_sizes; (void)n_in; (void)out_size; (void)ws_size;
    const float* x      = (const float*)d_in[0];
    const float* pos    = (const float*)d_in[1];
    const float* qkv_w  = (const float*)d_in[2];
    const float* proj_w = (const float*)d_in[3];
    const float* proj_b = (const float*)d_in[4];
    const float* temp   = (const float*)d_in[5];
    const float* ln_g   = (const float*)d_in[6];
    const float* ln_b   = (const float*)d_in[7];
    const float* dw_w   = (const float*)d_in[8];
    const float* dw_b   = (const float*)d_in[9];
    const float* pw_w   = (const float*)d_in[10];
    const float* pw_b   = (const float*)d_in[11];
    float* out = (float*)d_out;
    char* ws = (char*)d_ws;

    u16* t    = (u16*)(ws + 0);           // 12.58MB ; later aliased by z (with vT)
    u16* vT   = (u16*)(ws + 12582912);    // 12.58MB
    u16* q    = (u16*)(ws + 25165824);    // 12.58MB ; later aliased by o2 (with k)
    u16* kk   = (u16*)(ws + 37748736);    // 12.58MB
    u16* wqb  = (u16*)(ws + 50331648);    // qkv_w + proj_w + pw_w bf16, ~4.74MB
    float* cs   = (float*)(ws + 55150592);
    float* sqq  = (float*)(ws + 55175168);
    float* sqk  = (float*)(ws + 55199744);
    float* mu   = (float*)(ws + 55224320);
    float* rstd = (float*)(ws + 55257088);
    u16* wpb  = wqb + 2304 * 768;
    u16* wpwb = wqb + 2304 * 768 + 768 * 768;
    u16* o   = t;          // attention output, aliases t (dead after QKV GEMM)
    float* o2 = (float*)q; // proj output fp32, aliases q+k (dead after attention)
    float* z  = (float*)t; // depthwise output, aliases t+vT (dead after proj GEMM)
    float* y  = out;       // residual-1 output lives in d_out

    k_tpos<<<dim3(12, 16, 8), 256, 0, stream>>>(x, pos, t);
    k_cvt<<<9252, 256, 0, stream>>>(qkv_w, proj_w, pw_w, wqb);
    gemm_bt<0><<<1152, 256, 0, stream>>>(t, wqb, 8192, 2304, 768, q, kk, vT, nullptr, nullptr);
    hipMemsetAsync(sqq, 0, 49152, stream);
    k_sq<<<dim3(32, 8), 192, 0, stream>>>(q, kk, sqq, sqk);
    k_scale<<<32, 192, 0, stream>>>(sqq, sqk, temp, cs);
    k_attn<<<512, 256, 0, stream>>>(q, kk, vT, cs, o);
    gemm_bt<1><<<384, 256, 0, stream>>>(o, wpb, 8192, 768, 768, nullptr, nullptr, nullptr, proj_b, o2);
    k_lnstats<<<8192, 256, 0, stream>>>(o2, mu, rstd);
    k_lnt<<<dim3(12, 16, 8), 256, 0, stream>>>(o2, mu, rstd, ln_g, ln_b, x, y);
    k_dw<<<24576, 256, 0, stream>>>(y, dw_w, dw_b, z);
    k_pw<<<512, 256, 0, stream>>>(z, wpwb, pw_b, out);
}

// Round 4
// 404.287 us; speedup vs baseline: 1.0625x; 1.0625x over previous
//
#include <hip/hip_runtime.h>

typedef unsigned short u16;
typedef unsigned int u32;

typedef __attribute__((ext_vector_type(8))) short short8;
typedef __attribute__((ext_vector_type(4))) float floatx4;

__device__ __forceinline__ float bf2f(u16 u) { return __uint_as_float(((u32)u) << 16); }
__device__ __forceinline__ u16 f2bf(float f) {
    u32 x = __float_as_uint(f);
    x += 0x7fffu + ((x >> 16) & 1u);
    return (u16)(x >> 16);
}
__device__ __forceinline__ void gl_lds16(const void* g, void* l) {
    __builtin_amdgcn_global_load_lds((const __attribute__((address_space(1))) u32*)g,
                                     (__attribute__((address_space(3))) u32*)l, 16, 0, 0);
}

// Fragment-tiled ("swiz") layouts: data grouped in 1024B chunks of [16 rows x 32 k],
// element order = gl_lds16 lane order: u16 off = chunk*512 + (((k>>3)&3)*16 + (row&15))*8 + (k&7).
// A-operands (t, o): chunk = (row>>4)*24 + (k>>5)   [K=768 -> 24 kchunks]
// W-operands (qkv_w, proj_w): same with row=n.
// K-swiz (per bh, n x dh): chunk = (n>>4)*6 + (dh>>5)
// V-swiz (per bh): chunk = (n>>5)*12 + (dh>>4), lane = ((n>>3)&3)*16 + (dh&15), low3 = n&7

// ---------------- Kernel 1: x (B,C,D,H,W) -> t swiz bf16, + pos ----------------
__global__ __launch_bounds__(256) void k_tpos(const float* __restrict__ x,
                                              const float* __restrict__ pos,
                                              u16* __restrict__ t) {
    __shared__ float tile[64][65];
    const int b = blockIdx.z, hw0 = blockIdx.y * 64, cd0 = blockIdx.x * 64;
    const int tid = threadIdx.x;
#pragma unroll
    for (int i = 0; i < 16; i++) {
        int f = i * 256 + tid;
        int cdl = f >> 6, hwl = f & 63;
        int cd = cd0 + cdl, c = cd >> 3, d = cd & 7;
        tile[cdl][hwl] = x[(size_t)(((b * 96 + c) * 8 + d)) * 1024 + hw0 + hwl];
    }
    __syncthreads();
#pragma unroll
    for (int it = 0; it < 2; it++) {
        int u = it * 256 + tid;       // 512 units of 16B
        int ch = u >> 6, l = u & 63;
        int n16l = ch >> 1, kcl = ch & 1;
        int hwl = n16l * 16 + (l & 15);
        int cdl = kcl * 32 + (l >> 4) * 8;
        int row = b * 1024 + hw0 + hwl;
        int cd = cd0 + cdl;
        const float* pp = pos + (size_t)(hw0 + hwl) * 768 + cd;
        float4 p0 = *(const float4*)pp;
        float4 p1 = *(const float4*)(pp + 4);
        short8 v;
        v[0] = (short)f2bf(tile[cdl + 0][hwl] + p0.x);
        v[1] = (short)f2bf(tile[cdl + 1][hwl] + p0.y);
        v[2] = (short)f2bf(tile[cdl + 2][hwl] + p0.z);
        v[3] = (short)f2bf(tile[cdl + 3][hwl] + p0.w);
        v[4] = (short)f2bf(tile[cdl + 4][hwl] + p1.x);
        v[5] = (short)f2bf(tile[cdl + 5][hwl] + p1.y);
        v[6] = (short)f2bf(tile[cdl + 6][hwl] + p1.z);
        v[7] = (short)f2bf(tile[cdl + 7][hwl] + p1.w);
        size_t chunk = (size_t)(row >> 4) * 24 + (cd >> 5);
        *(short8*)(t + chunk * 512 + l * 8) = v;
    }
}

// ---------------- weight cvt: qkv_w swiz, proj_w swiz, pw_w row-major ----------------
__global__ __launch_bounds__(256) void k_cvt(const float* __restrict__ wq,
                                             const float* __restrict__ wp,
                                             const float* __restrict__ wpw,
                                             u16* __restrict__ out) {
    const int NQ = 144 * 24 * 64;          // qkv 16B-units
    const int NP = NQ + 48 * 24 * 64;      // + proj 16B-units
    int u = blockIdx.x * 256 + threadIdx.x;
    if (u < NP) {
        const float* w = (u < NQ) ? wq : wp;
        int ub = (u < NQ) ? u : u - NQ;
        int chunk = ub >> 6, l = ub & 63;
        int n16 = chunk / 24, kc = chunk - n16 * 24;
        int n = n16 * 16 + (l & 15);
        int k0 = kc * 32 + (l >> 4) * 8;
        const float* src = w + (size_t)n * 768 + k0;
        float4 a = *(const float4*)src;
        float4 b2 = *(const float4*)(src + 4);
        short8 v;
        v[0] = (short)f2bf(a.x);  v[1] = (short)f2bf(a.y);
        v[2] = (short)f2bf(a.z);  v[3] = (short)f2bf(a.w);
        v[4] = (short)f2bf(b2.x); v[5] = (short)f2bf(b2.y);
        v[6] = (short)f2bf(b2.z); v[7] = (short)f2bf(b2.w);
        *(short8*)(out + (size_t)u * 8) = v;
    } else {
        int i = u - NP;  // 9216 pw elements
        out[(size_t)NP * 8 + i] = f2bf(wpw[i]);
    }
}

// ---------------- GEMM: C(M,N) = A_swiz(M,K) * W_swiz(N,K)^T, bf16 MFMA ----------------
// MODE 0: QKV epilogue -> q row-major [b,h,n,dh], k swiz, v swiz
// MODE 1: proj epilogue -> Co fp32 row-major + bias
template <int MODE>
__global__ __launch_bounds__(256) void gemm_bt(const u16* __restrict__ A,
                                               const u16* __restrict__ Bw,
                                               int M, int N, int K,
                                               u16* __restrict__ qo, u16* __restrict__ ko,
                                               u16* __restrict__ vo,
                                               const float* __restrict__ bias,
                                               float* __restrict__ Co) {
    __shared__ __align__(16) u16 lA[128 * 32];
    __shared__ __align__(16) u16 lB[128 * 32];
    const int tid = threadIdx.x;
    const int lane = tid & 63;
    const int wv = tid >> 6;
    const int wr = wv >> 1, wc = wv & 1;
    const int ntiles = N >> 7;
    const int m0 = (blockIdx.x / ntiles) << 7;
    const int n0 = (blockIdx.x % ntiles) << 7;
    const int lr = lane & 15;
    const int lq = lane >> 4;

    floatx4 acc[4][4];
#pragma unroll
    for (int i = 0; i < 4; i++)
#pragma unroll
        for (int j = 0; j < 4; j++) acc[i][j] = (floatx4){0.f, 0.f, 0.f, 0.f};

    const int m16 = m0 >> 4, n16 = n0 >> 4;
    for (int kc = 0; kc < (K >> 5); kc++) {
        __syncthreads();
#pragma unroll
        for (int i = 0; i < 2; i++) {
            int ch = i * 4 + wv;  // 16-row block of the 128-row tile
            const u16* ga = A + ((size_t)(m16 + ch) * 24 + kc) * 512 + lane * 8;
            gl_lds16(ga, (char*)lA + ch * 1024);
            const u16* gb = Bw + ((size_t)(n16 + ch) * 24 + kc) * 512 + lane * 8;
            gl_lds16(gb, (char*)lB + ch * 1024);
        }
        __syncthreads();
        short8 af[4], bfr[4];
#pragma unroll
        for (int tt = 0; tt < 4; tt++) {
            af[tt] = *(const short8*)(lA + ((wr * 4 + tt) * 64 + lane) * 8);
            bfr[tt] = *(const short8*)(lB + ((wc * 4 + tt) * 64 + lane) * 8);
        }
#pragma unroll
        for (int mt = 0; mt < 4; mt++)
#pragma unroll
            for (int nt = 0; nt < 4; nt++)
                acc[mt][nt] = __builtin_amdgcn_mfma_f32_16x16x32_bf16(af[mt], bfr[nt], acc[mt][nt], 0, 0, 0);
    }

    if (MODE == 0) {
        const int region = n0 / 768;       // whole block is q, k, or v
        const int n0r = n0 - region * 768;
#pragma unroll
        for (int nt = 0; nt < 4; nt++) {
            int colb = n0r + wc * 64 + nt * 16;   // 16-aligned, within one h
            int h = colb / 192;
            int dh = colb - h * 192 + lr;
#pragma unroll
            for (int mt = 0; mt < 4; mt++) {
#pragma unroll
                for (int r = 0; r < 4; r++) {
                    int row = m0 + wr * 64 + mt * 16 + lq * 4 + r;
                    int b = row >> 10, n = row & 1023;
                    u16 val = f2bf(acc[mt][nt][r]);
                    size_t bh = (size_t)(b * 4 + h);
                    if (region == 0) {
                        qo[(bh * 1024 + n) * 192 + dh] = val;
                    } else if (region == 1) {
                        ko[bh * 196608 + (n >> 4) * 3072 + (dh >> 5) * 512 +
                           ((dh >> 3) & 3) * 128 + (n & 15) * 8 + (dh & 7)] = val;
                    } else {
                        vo[bh * 196608 + (n >> 5) * 6144 + (dh >> 4) * 512 +
                           ((n >> 3) & 3) * 128 + (dh & 15) * 8 + (n & 7)] = val;
                    }
                }
            }
        }
    } else {
#pragma unroll
        for (int nt = 0; nt < 4; nt++) {
            int col = n0 + wc * 64 + nt * 16 + lr;
            float bv = bias[col];
#pragma unroll
            for (int mt = 0; mt < 4; mt++) {
#pragma unroll
                for (int r = 0; r < 4; r++) {
                    int row = m0 + wr * 64 + mt * 16 + lq * 4 + r;
                    Co[(size_t)row * N + col] = acc[mt][nt][r] + bv;
                }
            }
        }
    }
}

// ---------------- column sum-of-squares over sequence (q row-major, k swiz) ----------------
__global__ void k_sq(const u16* __restrict__ q, const u16* __restrict__ k,
                     float* __restrict__ sqq, float* __restrict__ sqk) {
    int bh = blockIdx.x;
    int part = blockIdx.y;
    int dh = threadIdx.x;  // 192
    const u16* qp = q + ((size_t)bh * 1024 + part * 128) * 192 + dh;
    float aq = 0.f;
#pragma unroll 4
    for (int n = 0; n < 128; n++) {
        float a = bf2f(qp[(size_t)n * 192]);
        aq += a * a;
    }
    const u16* kbase = k + (size_t)bh * 196608 + (dh >> 5) * 512 + ((dh >> 3) & 3) * 128 + (dh & 7);
    float ak = 0.f;
#pragma unroll 4
    for (int n = 0; n < 128; n++) {
        int nn = part * 128 + n;
        float c2 = bf2f(kbase[(nn >> 4) * 3072 + (nn & 15) * 8]);
        ak += c2 * c2;
    }
    atomicAdd(&sqq[bh * 192 + dh], aq);
    atomicAdd(&sqk[bh * 192 + dh], ak);
}

__global__ void k_scale(const float* __restrict__ sqq, const float* __restrict__ sqk,
                        const float* __restrict__ temp, float* __restrict__ cs) {
    int bh = blockIdx.x;
    int dh = threadIdx.x;
    float rq = 1.f / fmaxf(sqrtf(sqq[bh * 192 + dh]), 1e-12f);
    float rk = 1.f / fmaxf(sqrtf(sqk[bh * 192 + dh]), 1e-12f);
    cs[bh * 192 + dh] = rq * rk * temp[bh & 3];
}

// ---------------- flash attention: one WG per (bh, 64-row q block) ----------------
// K/V pre-swizzled in global: staging = contiguous 1024B per gl_lds16, LDS reads identity.
__global__ __launch_bounds__(256) void k_attn(const u16* __restrict__ q,
                                              const u16* __restrict__ kmat,
                                              const u16* __restrict__ vT,
                                              const float* __restrict__ cs,
                                              u16* __restrict__ o) {
    __shared__ __align__(16) u16 lK[24 * 512];
    __shared__ __align__(16) u16 lV[24 * 512];
    __shared__ __align__(16) u16 lP[4 * 1024];
    const int lin = blockIdx.x;
    const int qb = (lin >> 3) & 15;
    const int bh = (lin & 7) * 4 + (lin >> 7);
    const int b = bh >> 2, h = bh & 3;
    const int tid = threadIdx.x;
    const int lane = tid & 63;
    const int wv = tid >> 6;
    const int lr = lane & 15;
    const int lq = lane >> 4;
    const int koff = lq * 8;

    const u16* qbase = q + (size_t)bh * 1024 * 192;
    const u16* kbase = kmat + (size_t)bh * 196608;
    const u16* vbase = vT + (size_t)bh * 196608;
    const float* cp = cs + bh * 192;

    const int qrow = qb * 64 + wv * 16 + lr;
    const u16* qp = qbase + (size_t)qrow * 192;
    short8 qf[6];
#pragma unroll
    for (int ks = 0; ks < 6; ks++) {
        short8 raw = *(const short8*)(qp + ks * 32 + koff);
        short8 sc;
#pragma unroll
        for (int j = 0; j < 8; j++) {
            float f = bf2f((u16)raw[j]) * cp[ks * 32 + koff + j];
            sc[j] = (short)f2bf(f);
        }
        qf[ks] = sc;
    }

    float m_r[4], l_r[4];
    floatx4 oacc[12];
#pragma unroll
    for (int r = 0; r < 4; r++) { m_r[r] = -1e30f; l_r[r] = 0.f; }
#pragma unroll
    for (int vt = 0; vt < 12; vt++) oacc[vt] = (floatx4){0.f, 0.f, 0.f, 0.f};

    u16* lp = lP + wv * 1024;

    for (int kb = 0; kb < 16; kb++) {
        __syncthreads();
#pragma unroll
        for (int i = 0; i < 6; i++) {
            int ch = i * 4 + wv;  // 0..23
            int ks = ch >> 2, nt = ch & 3;
            const u16* gk = kbase + ((size_t)(kb * 4 + nt) * 6 + ks) * 512 + lane * 8;
            gl_lds16(gk, (char*)lK + ch * 1024);
            int ks2 = ch / 12, vt2 = ch - ks2 * 12;
            const u16* gv = vbase + ((size_t)(kb * 2 + ks2) * 12 + vt2) * 512 + lane * 8;
            gl_lds16(gv, (char*)lV + ch * 1024);
        }
        __syncthreads();

        floatx4 s[4];
#pragma unroll
        for (int nt = 0; nt < 4; nt++) s[nt] = (floatx4){0.f, 0.f, 0.f, 0.f};
#pragma unroll
        for (int ks = 0; ks < 6; ks++) {
#pragma unroll
            for (int nt = 0; nt < 4; nt++) {
                short8 kf = *(const short8*)(lK + ((ks * 4 + nt) * 64 + lane) * 8);
                s[nt] = __builtin_amdgcn_mfma_f32_16x16x32_bf16(qf[ks], kf, s[nt], 0, 0, 0);
            }
        }

        float rmax[4];
#pragma unroll
        for (int r = 0; r < 4; r++)
            rmax[r] = fmaxf(fmaxf(s[0][r], s[1][r]), fmaxf(s[2][r], s[3][r]));
#pragma unroll
        for (int m = 1; m < 16; m <<= 1)
#pragma unroll
            for (int r = 0; r < 4; r++) rmax[r] = fmaxf(rmax[r], __shfl_xor(rmax[r], m));
        float alpha[4];
#pragma unroll
        for (int r = 0; r < 4; r++) {
            float mn = fmaxf(m_r[r], rmax[r]);
            alpha[r] = __expf(m_r[r] - mn);
            m_r[r] = mn;
        }
        float rsum[4] = {0.f, 0.f, 0.f, 0.f};
#pragma unroll
        for (int nt = 0; nt < 4; nt++)
#pragma unroll
            for (int r = 0; r < 4; r++) {
                float p = __expf(s[nt][r] - m_r[r]);
                s[nt][r] = p;
                rsum[r] += p;
            }
#pragma unroll
        for (int m = 1; m < 16; m <<= 1)
#pragma unroll
            for (int r = 0; r < 4; r++) rsum[r] += __shfl_xor(rsum[r], m);
#pragma unroll
        for (int r = 0; r < 4; r++) l_r[r] = l_r[r] * alpha[r] + rsum[r];
#pragma unroll
        for (int vt = 0; vt < 12; vt++)
#pragma unroll
            for (int r = 0; r < 4; r++) oacc[vt][r] *= alpha[r];

        // P -> per-wave LDS in A-fragment order
#pragma unroll
        for (int nt = 0; nt < 4; nt++) {
            int base2 = (nt >> 1) * 512 + ((nt & 1) * 2 + (lr >> 3)) * 128 + (lr & 7);
#pragma unroll
            for (int r = 0; r < 4; r++)
                lp[base2 + (lq * 4 + r) * 8] = f2bf(s[nt][r]);
        }

#pragma unroll
        for (int ks2 = 0; ks2 < 2; ks2++) {
            short8 pf = *(const short8*)(lp + ks2 * 512 + lane * 8);
#pragma unroll
            for (int vt = 0; vt < 12; vt++) {
                short8 vf = *(const short8*)(lV + ((ks2 * 12 + vt) * 64 + lane) * 8);
                oacc[vt] = __builtin_amdgcn_mfma_f32_16x16x32_bf16(pf, vf, oacc[vt], 0, 0, 0);
            }
        }
    }

    // epilogue: divide by l, write o in swiz (A-operand) layout for proj gemm
    float inv[4];
#pragma unroll
    for (int r = 0; r < 4; r++) inv[r] = 1.f / l_r[r];
#pragma unroll
    for (int vt = 0; vt < 12; vt++) {
        int col = h * 192 + vt * 16 + lr;
#pragma unroll
        for (int r = 0; r < 4; r++) {
            int rowg = b * 1024 + qb * 64 + wv * 16 + lq * 4 + r;
            size_t addr = (size_t)(rowg >> 4) * 12288 + (col >> 5) * 512 +
                          ((col >> 3) & 3) * 128 + (rowg & 15) * 8 + (col & 7);
            o[addr] = f2bf(oacc[vt][r] * inv[r]);
        }
    }
}

// ---------------- LN stats per row ----------------
__global__ __launch_bounds__(256) void k_lnstats(const float* __restrict__ o2,
                                                 float* __restrict__ mu,
                                                 float* __restrict__ rstd) {
    int row = blockIdx.x;
    int tid = threadIdx.x;
    const float* p = o2 + (size_t)row * 768;
    float s = 0.f, ss = 0.f;
    for (int i = tid; i < 768; i += 256) {
        float v = p[i];
        s += v;
        ss += v * v;
    }
#pragma unroll
    for (int m = 32; m >= 1; m >>= 1) {
        s += __shfl_xor(s, m);
        ss += __shfl_xor(ss, m);
    }
    __shared__ float as[4], ass[4];
    if ((tid & 63) == 0) {
        as[tid >> 6] = s;
        ass[tid >> 6] = ss;
    }
    __syncthreads();
    if (tid == 0) {
        float S = as[0] + as[1] + as[2] + as[3];
        float SS = ass[0] + ass[1] + ass[2] + ass[3];
        float m_ = S * (1.f / 768.f);
        float v = SS * (1.f / 768.f) - m_ * m_;
        v = fmaxf(v, 0.f);
        mu[row] = m_;
        rstd[row] = rsqrtf(v + 1e-5f);
    }
}

// ---------------- LN apply + transpose back + residual: y = LN(o2)^T + x ----------------
__global__ __launch_bounds__(256) void k_lnt(const float* __restrict__ o2,
                                             const float* __restrict__ mu,
                                             const float* __restrict__ rstd,
                                             const float* __restrict__ gamma,
                                             const float* __restrict__ beta,
                                             const float* __restrict__ x,
                                             float* __restrict__ y) {
    __shared__ float tile[64][65];
    const int b = blockIdx.z, hw0 = blockIdx.y * 64, cd0 = blockIdx.x * 64;
    const int tid = threadIdx.x;
#pragma unroll
    for (int i = 0; i < 16; i++) {
        int f = i * 256 + tid;
        int hwl = f >> 6, cdl = f & 63;
        int row = b * 1024 + hw0 + hwl;
        float v = o2[(size_t)row * 768 + cd0 + cdl];
        v = (v - mu[row]) * rstd[row] * gamma[cd0 + cdl] + beta[cd0 + cdl];
        tile[hwl][cdl] = v;
    }
    __syncthreads();
#pragma unroll
    for (int i = 0; i < 16; i++) {
        int f = i * 256 + tid;
        int cdl = f >> 6, hwl = f & 63;
        int cd = cd0 + cdl, c = cd >> 3, d = cd & 7;
        size_t addr = (size_t)((b * 96 + c) * 8 + d) * 1024 + hw0 + hwl;
        y[addr] = tile[hwl][cdl] + x[addr];
    }
}

// ---------------- depthwise 3x3x3 conv (x-layout), z = dw(y) + dw_b ----------------
__global__ __launch_bounds__(256) void k_dw(const float* __restrict__ y,
                                            const float* __restrict__ w,
                                            const float* __restrict__ bias,
                                            float* __restrict__ z) {
    int e = blockIdx.x * 256 + threadIdx.x;
    int hw = e & 1023;
    int rest = e >> 10;
    int d = rest & 7;
    int c = (rest >> 3) % 96;
    int h = hw >> 5, ww = hw & 31;
    float acc = bias[c];
    const float* wp = w + c * 27;
#pragma unroll
    for (int kd = 0; kd < 3; kd++) {
        int dd = d + kd - 1;
        if (dd < 0 || dd >= 8) continue;
#pragma unroll
        for (int kh = 0; kh < 3; kh++) {
            int hh = h + kh - 1;
            if ((unsigned)hh >= 32u) continue;
#pragma unroll
            for (int kw = 0; kw < 3; kw++) {
                int w2 = ww + kw - 1;
                if ((unsigned)w2 >= 32u) continue;
                acc += wp[kd * 9 + kh * 3 + kw] * y[e + (kd - 1) * 1024 + (kh - 1) * 32 + (kw - 1)];
            }
        }
    }
    z[e] = acc;
}

// ---------------- pointwise conv via MFMA: out = y + pw_b + W(96x96) * Z(96 x pos) ----------------
__global__ __launch_bounds__(256) void k_pw(const float* __restrict__ z,
                                            const u16* __restrict__ wbf,   // bf16 96x96 row-major
                                            const float* __restrict__ bias,
                                            float* __restrict__ out) {
    __shared__ __align__(16) u16 lZ[128 * 104];
    __shared__ __align__(16) u16 lW[96 * 104];
    const int tid = threadIdx.x;
    const int lane = tid & 63;
    const int wv = tid >> 6;
    const int lr = lane & 15;
    const int lq = lane >> 4;
    const int koff = lq * 8;

    const int idx = blockIdx.x;
    const int q = idx & 7;
    const int bd = idx >> 3;
    const int b = bd >> 3, d = bd & 7;
    const int pos0 = q * 128;

    for (int i = tid; i < 96 * 96; i += 256) {
        int row = i / 96, col = i - row * 96;
        lW[row * 104 + col] = wbf[i];
    }
    {
        const int pos = tid & 127;
        const int cc0 = (tid >> 7) * 48;
        const size_t gbase = ((size_t)b * 96 * 8 + d) * 1024 + pos0 + pos;
#pragma unroll
        for (int g = 0; g < 6; g++) {
            short8 v;
#pragma unroll
            for (int j = 0; j < 8; j++) {
                int cc = cc0 + g * 8 + j;
                v[j] = (short)f2bf(z[gbase + (size_t)cc * 8192]);
            }
            *(short8*)(lZ + pos * 104 + cc0 + g * 8) = v;
        }
    }
    __syncthreads();

    floatx4 acc[6][2];
#pragma unroll
    for (int m = 0; m < 6; m++)
#pragma unroll
        for (int nt = 0; nt < 2; nt++) acc[m][nt] = (floatx4){0.f, 0.f, 0.f, 0.f};

#pragma unroll
    for (int ks = 0; ks < 3; ks++) {
        short8 bfrg[2];
#pragma unroll
        for (int nt = 0; nt < 2; nt++)
            bfrg[nt] = *(const short8*)(lZ + (wv * 32 + nt * 16 + lr) * 104 + ks * 32 + koff);
#pragma unroll
        for (int m = 0; m < 6; m++) {
            short8 afr = *(const short8*)(lW + (m * 16 + lr) * 104 + ks * 32 + koff);
#pragma unroll
            for (int nt = 0; nt < 2; nt++)
                acc[m][nt] = __builtin_amdgcn_mfma_f32_16x16x32_bf16(afr, bfrg[nt], acc[m][nt], 0, 0, 0);
        }
    }

#pragma unroll
    for (int m = 0; m < 6; m++) {
#pragma unroll
        for (int r = 0; r < 4; r++) {
            int c = m * 16 + lq * 4 + r;
            float bv = bias[c];
            size_t rowbase = ((size_t)(b * 96 + c) * 8 + d) * 1024 + pos0;
#pragma unroll
            for (int nt = 0; nt < 2; nt++) {
                int pos = wv * 32 + nt * 16 + lr;
                size_t a = rowbase + pos;
                out[a] = out[a] + bv + acc[m][nt][r];
            }
        }
    }
}

extern "C" void kernel_launch(void* const* d_in, const int* in_sizes, int n_in,
                              void* d_out, int out_size, void* d_ws, size_t ws_size,
                              hipStream_t stream) {
    (void)in_sizes; (void)n_in; (void)out_size; (void)ws_size;
    const float* x      = (const float*)d_in[0];
    const float* pos    = (const float*)d_in[1];
    const float* qkv_w  = (const float*)d_in[2];
    const float* proj_w = (const float*)d_in[3];
    const float* proj_b = (const float*)d_in[4];
    const float* temp   = (const float*)d_in[5];
    const float* ln_g   = (const float*)d_in[6];
    const float* ln_b   = (const float*)d_in[7];
    const float* dw_w   = (const float*)d_in[8];
    const float* dw_b   = (const float*)d_in[9];
    const float* pw_w   = (const float*)d_in[10];
    const float* pw_b   = (const float*)d_in[11];
    float* out = (float*)d_out;
    char* ws = (char*)d_ws;

    u16* t    = (u16*)(ws + 0);           // swiz A, 12.58MB ; later aliased by o (swiz) and z
    u16* vT   = (u16*)(ws + 12582912);    // v swiz, 12.58MB
    u16* q    = (u16*)(ws + 25165824);    // row-major, 12.58MB ; later o2 (with kk)
    u16* kk   = (u16*)(ws + 37748736);    // k swiz, 12.58MB
    u16* wqb  = (u16*)(ws + 50331648);    // qkv_w swiz + proj_w swiz + pw_w, ~4.74MB
    float* cs   = (float*)(ws + 55150592);
    float* sqq  = (float*)(ws + 55175168);
    float* sqk  = (float*)(ws + 55199744);
    float* mu   = (float*)(ws + 55224320);
    float* rstd = (float*)(ws + 55257088);
    u16* wpb  = wqb + 2304 * 768;
    u16* wpwb = wqb + 2304 * 768 + 768 * 768;
    u16* o   = t;
    float* o2 = (float*)q;
    float* z  = (float*)t;
    float* y  = out;

    k_tpos<<<dim3(12, 16, 8), 256, 0, stream>>>(x, pos, t);
    k_cvt<<<1188, 256, 0, stream>>>(qkv_w, proj_w, pw_w, wqb);
    gemm_bt<0><<<1152, 256, 0, stream>>>(t, wqb, 8192, 2304, 768, q, kk, vT, nullptr, nullptr);
    hipMemsetAsync(sqq, 0, 49152, stream);
    k_sq<<<dim3(32, 8), 192, 0, stream>>>(q, kk, sqq, sqk);
    k_scale<<<32, 192, 0, stream>>>(sqq, sqk, temp, cs);
    k_attn<<<512, 256, 0, stream>>>(q, kk, vT, cs, o);
    gemm_bt<1><<<384, 256, 0, stream>>>(o, wpb, 8192, 768, 768, nullptr, nullptr, nullptr, proj_b, o2);
    k_lnstats<<<8192, 256, 0, stream>>>(o2, mu, rstd);
    k_lnt<<<dim3(12, 16, 8), 256, 0, stream>>>(o2, mu, rstd, ln_g, ln_b, x, y);
    k_dw<<<24576, 256, 0, stream>>>(y, dw_w, dw_b, z);
    k_pw<<<512, 256, 0, stream>>>(z, wpwb, pw_b, out);
}

// Round 5
// 335.246 us; speedup vs baseline: 1.2813x; 1.2059x over previous
//
#include <hip/hip_runtime.h>

typedef unsigned short u16;
typedef unsigned int u32;

typedef __attribute__((ext_vector_type(8))) short short8;
typedef __attribute__((ext_vector_type(4))) float floatx4;

__device__ __forceinline__ float bf2f(u16 u) { return __uint_as_float(((u32)u) << 16); }
__device__ __forceinline__ u16 f2bf(float f) {
    u32 x = __float_as_uint(f);
    x += 0x7fffu + ((x >> 16) & 1u);
    return (u16)(x >> 16);
}
__device__ __forceinline__ void gl_lds16(const void* g, void* l) {
    __builtin_amdgcn_global_load_lds((const __attribute__((address_space(1))) u32*)g,
                                     (__attribute__((address_space(3))) u32*)l, 16, 0, 0);
}

// Fragment-tiled ("swiz") layouts: data grouped in 1024B chunks of [16 rows x 32 k],
// element order = gl_lds16 lane order: u16 off = chunk*512 + (((k>>3)&3)*16 + (row&15))*8 + (k&7).
// A-operands (t, o): chunk = (row>>4)*24 + (k>>5)   [K=768 -> 24 kchunks]
// W-operands (qkv_w, proj_w): same with row=n.
// K-swiz (per bh, n x dh): chunk = (n>>4)*6 + (dh>>5)
// V-swiz (per bh): chunk = (n>>5)*12 + (dh>>4), lane = ((n>>3)&3)*16 + (dh&15), low3 = n&7

// ---------------- Kernel 1: x (B,C,D,H,W) -> t swiz bf16, + pos ----------------
__global__ __launch_bounds__(256) void k_tpos(const float* __restrict__ x,
                                              const float* __restrict__ pos,
                                              u16* __restrict__ t) {
    __shared__ float tile[64][65];
    const int b = blockIdx.z, hw0 = blockIdx.y * 64, cd0 = blockIdx.x * 64;
    const int tid = threadIdx.x;
#pragma unroll
    for (int i = 0; i < 16; i++) {
        int f = i * 256 + tid;
        int cdl = f >> 6, hwl = f & 63;
        int cd = cd0 + cdl, c = cd >> 3, d = cd & 7;
        tile[cdl][hwl] = x[(size_t)(((b * 96 + c) * 8 + d)) * 1024 + hw0 + hwl];
    }
    __syncthreads();
#pragma unroll
    for (int it = 0; it < 2; it++) {
        int u = it * 256 + tid;       // 512 units of 16B
        int ch = u >> 6, l = u & 63;
        int n16l = ch >> 1, kcl = ch & 1;
        int hwl = n16l * 16 + (l & 15);
        int cdl = kcl * 32 + (l >> 4) * 8;
        int row = b * 1024 + hw0 + hwl;
        int cd = cd0 + cdl;
        const float* pp = pos + (size_t)(hw0 + hwl) * 768 + cd;
        float4 p0 = *(const float4*)pp;
        float4 p1 = *(const float4*)(pp + 4);
        short8 v;
        v[0] = (short)f2bf(tile[cdl + 0][hwl] + p0.x);
        v[1] = (short)f2bf(tile[cdl + 1][hwl] + p0.y);
        v[2] = (short)f2bf(tile[cdl + 2][hwl] + p0.z);
        v[3] = (short)f2bf(tile[cdl + 3][hwl] + p0.w);
        v[4] = (short)f2bf(tile[cdl + 4][hwl] + p1.x);
        v[5] = (short)f2bf(tile[cdl + 5][hwl] + p1.y);
        v[6] = (short)f2bf(tile[cdl + 6][hwl] + p1.z);
        v[7] = (short)f2bf(tile[cdl + 7][hwl] + p1.w);
        size_t chunk = (size_t)(row >> 4) * 24 + (cd >> 5);
        *(short8*)(t + chunk * 512 + l * 8) = v;
    }
}

// ---------------- weight cvt: qkv_w swiz, proj_w swiz, pw_w row-major ----------------
__global__ __launch_bounds__(256) void k_cvt(const float* __restrict__ wq,
                                             const float* __restrict__ wp,
                                             const float* __restrict__ wpw,
                                             u16* __restrict__ out) {
    const int NQ = 144 * 24 * 64;          // qkv 16B-units
    const int NP = NQ + 48 * 24 * 64;      // + proj 16B-units
    int u = blockIdx.x * 256 + threadIdx.x;
    if (u < NP) {
        const float* w = (u < NQ) ? wq : wp;
        int ub = (u < NQ) ? u : u - NQ;
        int chunk = ub >> 6, l = ub & 63;
        int n16 = chunk / 24, kc = chunk - n16 * 24;
        int n = n16 * 16 + (l & 15);
        int k0 = kc * 32 + (l >> 4) * 8;
        const float* src = w + (size_t)n * 768 + k0;
        float4 a = *(const float4*)src;
        float4 b2 = *(const float4*)(src + 4);
        short8 v;
        v[0] = (short)f2bf(a.x);  v[1] = (short)f2bf(a.y);
        v[2] = (short)f2bf(a.z);  v[3] = (short)f2bf(a.w);
        v[4] = (short)f2bf(b2.x); v[5] = (short)f2bf(b2.y);
        v[6] = (short)f2bf(b2.z); v[7] = (short)f2bf(b2.w);
        *(short8*)(out + (size_t)u * 8) = v;
    } else {
        int i = u - NP;  // 9216 pw elements
        out[(size_t)NP * 8 + i] = f2bf(wpw[i]);
    }
}

// ---------------- GEMM: C(M,N) = A_swiz(M,K) * W_swiz(N,K)^T, bf16 MFMA ----------------
// MODE 0: QKV epilogue -> q row-major [b,h,n,dh], k swiz, v swiz
// MODE 1: proj epilogue -> Co fp32 row-major + bias
template <int MODE>
__global__ __launch_bounds__(256) void gemm_bt(const u16* __restrict__ A,
                                               const u16* __restrict__ Bw,
                                               int M, int N, int K,
                                               u16* __restrict__ qo, u16* __restrict__ ko,
                                               u16* __restrict__ vo,
                                               const float* __restrict__ bias,
                                               float* __restrict__ Co) {
    __shared__ __align__(16) u16 lA[128 * 32];
    __shared__ __align__(16) u16 lB[128 * 32];
    const int tid = threadIdx.x;
    const int lane = tid & 63;
    const int wv = tid >> 6;
    const int wr = wv >> 1, wc = wv & 1;
    const int ntiles = N >> 7;
    const int m0 = (blockIdx.x / ntiles) << 7;
    const int n0 = (blockIdx.x % ntiles) << 7;
    const int lr = lane & 15;
    const int lq = lane >> 4;

    floatx4 acc[4][4];
#pragma unroll
    for (int i = 0; i < 4; i++)
#pragma unroll
        for (int j = 0; j < 4; j++) acc[i][j] = (floatx4){0.f, 0.f, 0.f, 0.f};

    const int m16 = m0 >> 4, n16 = n0 >> 4;
    for (int kc = 0; kc < (K >> 5); kc++) {
        __syncthreads();
#pragma unroll
        for (int i = 0; i < 2; i++) {
            int ch = i * 4 + wv;  // 16-row block of the 128-row tile
            const u16* ga = A + ((size_t)(m16 + ch) * 24 + kc) * 512 + lane * 8;
            gl_lds16(ga, (char*)lA + ch * 1024);
            const u16* gb = Bw + ((size_t)(n16 + ch) * 24 + kc) * 512 + lane * 8;
            gl_lds16(gb, (char*)lB + ch * 1024);
        }
        __syncthreads();
        short8 af[4], bfr[4];
#pragma unroll
        for (int tt = 0; tt < 4; tt++) {
            af[tt] = *(const short8*)(lA + ((wr * 4 + tt) * 64 + lane) * 8);
            bfr[tt] = *(const short8*)(lB + ((wc * 4 + tt) * 64 + lane) * 8);
        }
#pragma unroll
        for (int mt = 0; mt < 4; mt++)
#pragma unroll
            for (int nt = 0; nt < 4; nt++)
                acc[mt][nt] = __builtin_amdgcn_mfma_f32_16x16x32_bf16(af[mt], bfr[nt], acc[mt][nt], 0, 0, 0);
    }

    if (MODE == 0) {
        const int region = n0 / 768;       // whole block is q, k, or v
        const int n0r = n0 - region * 768;
#pragma unroll
        for (int nt = 0; nt < 4; nt++) {
            int colb = n0r + wc * 64 + nt * 16;   // 16-aligned, within one h
            int h = colb / 192;
            int dh = colb - h * 192 + lr;
#pragma unroll
            for (int mt = 0; mt < 4; mt++) {
#pragma unroll
                for (int r = 0; r < 4; r++) {
                    int row = m0 + wr * 64 + mt * 16 + lq * 4 + r;
                    int b = row >> 10, n = row & 1023;
                    u16 val = f2bf(acc[mt][nt][r]);
                    size_t bh = (size_t)(b * 4 + h);
                    if (region == 0) {
                        qo[(bh * 1024 + n) * 192 + dh] = val;
                    } else if (region == 1) {
                        ko[bh * 196608 + (n >> 4) * 3072 + (dh >> 5) * 512 +
                           ((dh >> 3) & 3) * 128 + (n & 15) * 8 + (dh & 7)] = val;
                    } else {
                        vo[bh * 196608 + (n >> 5) * 6144 + (dh >> 4) * 512 +
                           ((n >> 3) & 3) * 128 + (dh & 15) * 8 + (n & 7)] = val;
                    }
                }
            }
        }
    } else {
#pragma unroll
        for (int nt = 0; nt < 4; nt++) {
            int col = n0 + wc * 64 + nt * 16 + lr;
            float bv = bias[col];
#pragma unroll
            for (int mt = 0; mt < 4; mt++) {
#pragma unroll
                for (int r = 0; r < 4; r++) {
                    int row = m0 + wr * 64 + mt * 16 + lq * 4 + r;
                    Co[(size_t)row * N + col] = acc[mt][nt][r] + bv;
                }
            }
        }
    }
}

// ---------------- column sum-of-squares over sequence (q row-major, k swiz) ----------------
__global__ void k_sq(const u16* __restrict__ q, const u16* __restrict__ k,
                     float* __restrict__ sqq, float* __restrict__ sqk) {
    int bh = blockIdx.x;
    int part = blockIdx.y;
    int dh = threadIdx.x;  // 192
    const u16* qp = q + ((size_t)bh * 1024 + part * 128) * 192 + dh;
    float aq = 0.f;
#pragma unroll 4
    for (int n = 0; n < 128; n++) {
        float a = bf2f(qp[(size_t)n * 192]);
        aq += a * a;
    }
    const u16* kbase = k + (size_t)bh * 196608 + (dh >> 5) * 512 + ((dh >> 3) & 3) * 128 + (dh & 7);
    float ak = 0.f;
#pragma unroll 4
    for (int n = 0; n < 128; n++) {
        int nn = part * 128 + n;
        float c2 = bf2f(kbase[(nn >> 4) * 3072 + (nn & 15) * 8]);
        ak += c2 * c2;
    }
    atomicAdd(&sqq[bh * 192 + dh], aq);
    atomicAdd(&sqk[bh * 192 + dh], ak);
}

__global__ void k_scale(const float* __restrict__ sqq, const float* __restrict__ sqk,
                        const float* __restrict__ temp, float* __restrict__ cs) {
    int bh = blockIdx.x;
    int dh = threadIdx.x;
    float rq = 1.f / fmaxf(sqrtf(sqq[bh * 192 + dh]), 1e-12f);
    float rk = 1.f / fmaxf(sqrtf(sqk[bh * 192 + dh]), 1e-12f);
    cs[bh * 192 + dh] = rq * rk * temp[bh & 3];
}

// ---------------- flash attention: one WG per (bh, 64-row q block) ----------------
// K/V pre-swizzled in global: staging = contiguous 1024B per gl_lds16, LDS reads identity.
__global__ __launch_bounds__(256) void k_attn(const u16* __restrict__ q,
                                              const u16* __restrict__ kmat,
                                              const u16* __restrict__ vT,
                                              const float* __restrict__ cs,
                                              u16* __restrict__ o) {
    __shared__ __align__(16) u16 lK[24 * 512];
    __shared__ __align__(16) u16 lV[24 * 512];
    __shared__ __align__(16) u16 lP[4 * 1024];
    const int lin = blockIdx.x;
    const int qb = (lin >> 3) & 15;
    const int bh = (lin & 7) * 4 + (lin >> 7);
    const int b = bh >> 2, h = bh & 3;
    const int tid = threadIdx.x;
    const int lane = tid & 63;
    const int wv = tid >> 6;
    const int lr = lane & 15;
    const int lq = lane >> 4;
    const int koff = lq * 8;

    const u16* qbase = q + (size_t)bh * 1024 * 192;
    const u16* kbase = kmat + (size_t)bh * 196608;
    const u16* vbase = vT + (size_t)bh * 196608;
    const float* cp = cs + bh * 192;

    const int qrow = qb * 64 + wv * 16 + lr;
    const u16* qp = qbase + (size_t)qrow * 192;
    short8 qf[6];
#pragma unroll
    for (int ks = 0; ks < 6; ks++) {
        short8 raw = *(const short8*)(qp + ks * 32 + koff);
        short8 sc;
#pragma unroll
        for (int j = 0; j < 8; j++) {
            float f = bf2f((u16)raw[j]) * cp[ks * 32 + koff + j];
            sc[j] = (short)f2bf(f);
        }
        qf[ks] = sc;
    }

    float m_r[4], l_r[4];
    floatx4 oacc[12];
#pragma unroll
    for (int r = 0; r < 4; r++) { m_r[r] = -1e30f; l_r[r] = 0.f; }
#pragma unroll
    for (int vt = 0; vt < 12; vt++) oacc[vt] = (floatx4){0.f, 0.f, 0.f, 0.f};

    u16* lp = lP + wv * 1024;

    for (int kb = 0; kb < 16; kb++) {
        __syncthreads();
#pragma unroll
        for (int i = 0; i < 6; i++) {
            int ch = i * 4 + wv;  // 0..23
            int ks = ch >> 2, nt = ch & 3;
            const u16* gk = kbase + ((size_t)(kb * 4 + nt) * 6 + ks) * 512 + lane * 8;
            gl_lds16(gk, (char*)lK + ch * 1024);
            int ks2 = ch / 12, vt2 = ch - ks2 * 12;
            const u16* gv = vbase + ((size_t)(kb * 2 + ks2) * 12 + vt2) * 512 + lane * 8;
            gl_lds16(gv, (char*)lV + ch * 1024);
        }
        __syncthreads();

        floatx4 s[4];
#pragma unroll
        for (int nt = 0; nt < 4; nt++) s[nt] = (floatx4){0.f, 0.f, 0.f, 0.f};
#pragma unroll
        for (int ks = 0; ks < 6; ks++) {
#pragma unroll
            for (int nt = 0; nt < 4; nt++) {
                short8 kf = *(const short8*)(lK + ((ks * 4 + nt) * 64 + lane) * 8);
                s[nt] = __builtin_amdgcn_mfma_f32_16x16x32_bf16(qf[ks], kf, s[nt], 0, 0, 0);
            }
        }

        float rmax[4];
#pragma unroll
        for (int r = 0; r < 4; r++)
            rmax[r] = fmaxf(fmaxf(s[0][r], s[1][r]), fmaxf(s[2][r], s[3][r]));
#pragma unroll
        for (int m = 1; m < 16; m <<= 1)
#pragma unroll
            for (int r = 0; r < 4; r++) rmax[r] = fmaxf(rmax[r], __shfl_xor(rmax[r], m));
        float alpha[4];
#pragma unroll
        for (int r = 0; r < 4; r++) {
            float mn = fmaxf(m_r[r], rmax[r]);
            alpha[r] = __expf(m_r[r] - mn);
            m_r[r] = mn;
        }
        float rsum[4] = {0.f, 0.f, 0.f, 0.f};
#pragma unroll
        for (int nt = 0; nt < 4; nt++)
#pragma unroll
            for (int r = 0; r < 4; r++) {
                float p = __expf(s[nt][r] - m_r[r]);
                s[nt][r] = p;
                rsum[r] += p;
            }
#pragma unroll
        for (int m = 1; m < 16; m <<= 1)
#pragma unroll
            for (int r = 0; r < 4; r++) rsum[r] += __shfl_xor(rsum[r], m);
#pragma unroll
        for (int r = 0; r < 4; r++) l_r[r] = l_r[r] * alpha[r] + rsum[r];
#pragma unroll
        for (int vt = 0; vt < 12; vt++)
#pragma unroll
            for (int r = 0; r < 4; r++) oacc[vt][r] *= alpha[r];

        // P -> per-wave LDS in A-fragment order
#pragma unroll
        for (int nt = 0; nt < 4; nt++) {
            int base2 = (nt >> 1) * 512 + ((nt & 1) * 2 + (lr >> 3)) * 128 + (lr & 7);
#pragma unroll
            for (int r = 0; r < 4; r++)
                lp[base2 + (lq * 4 + r) * 8] = f2bf(s[nt][r]);
        }

#pragma unroll
        for (int ks2 = 0; ks2 < 2; ks2++) {
            short8 pf = *(const short8*)(lp + ks2 * 512 + lane * 8);
#pragma unroll
            for (int vt = 0; vt < 12; vt++) {
                short8 vf = *(const short8*)(lV + ((ks2 * 12 + vt) * 64 + lane) * 8);
                oacc[vt] = __builtin_amdgcn_mfma_f32_16x16x32_bf16(pf, vf, oacc[vt], 0, 0, 0);
            }
        }
    }

    // epilogue: divide by l, write o in swiz (A-operand) layout for proj gemm
    float inv[4];
#pragma unroll
    for (int r = 0; r < 4; r++) inv[r] = 1.f / l_r[r];
#pragma unroll
    for (int vt = 0; vt < 12; vt++) {
        int col = h * 192 + vt * 16 + lr;
#pragma unroll
        for (int r = 0; r < 4; r++) {
            int rowg = b * 1024 + qb * 64 + wv * 16 + lq * 4 + r;
            size_t addr = (size_t)(rowg >> 4) * 12288 + (col >> 5) * 512 +
                          ((col >> 3) & 3) * 128 + (rowg & 15) * 8 + (col & 7);
            o[addr] = f2bf(oacc[vt][r] * inv[r]);
        }
    }
}

// ---------------- LN stats per row ----------------
__global__ __launch_bounds__(256) void k_lnstats(const float* __restrict__ o2,
                                                 float* __restrict__ mu,
                                                 float* __restrict__ rstd) {
    int row = blockIdx.x;
    int tid = threadIdx.x;
    const float* p = o2 + (size_t)row * 768;
    float s = 0.f, ss = 0.f;
    for (int i = tid; i < 768; i += 256) {
        float v = p[i];
        s += v;
        ss += v * v;
    }
#pragma unroll
    for (int m = 32; m >= 1; m >>= 1) {
        s += __shfl_xor(s, m);
        ss += __shfl_xor(ss, m);
    }
    __shared__ float as[4], ass[4];
    if ((tid & 63) == 0) {
        as[tid >> 6] = s;
        ass[tid >> 6] = ss;
    }
    __syncthreads();
    if (tid == 0) {
        float S = as[0] + as[1] + as[2] + as[3];
        float SS = ass[0] + ass[1] + ass[2] + ass[3];
        float m_ = S * (1.f / 768.f);
        float v = SS * (1.f / 768.f) - m_ * m_;
        v = fmaxf(v, 0.f);
        mu[row] = m_;
        rstd[row] = rsqrtf(v + 1e-5f);
    }
}

// ---------------- LN apply + transpose back + residual: y = LN(o2)^T + x ----------------
__global__ __launch_bounds__(256) void k_lnt(const float* __restrict__ o2,
                                             const float* __restrict__ mu,
                                             const float* __restrict__ rstd,
                                             const float* __restrict__ gamma,
                                             const float* __restrict__ beta,
                                             const float* __restrict__ x,
                                             float* __restrict__ y) {
    __shared__ float tile[64][65];
    const int b = blockIdx.z, hw0 = blockIdx.y * 64, cd0 = blockIdx.x * 64;
    const int tid = threadIdx.x;
#pragma unroll
    for (int i = 0; i < 16; i++) {
        int f = i * 256 + tid;
        int hwl = f >> 6, cdl = f & 63;
        int row = b * 1024 + hw0 + hwl;
        float v = o2[(size_t)row * 768 + cd0 + cdl];
        v = (v - mu[row]) * rstd[row] * gamma[cd0 + cdl] + beta[cd0 + cdl];
        tile[hwl][cdl] = v;
    }
    __syncthreads();
#pragma unroll
    for (int i = 0; i < 16; i++) {
        int f = i * 256 + tid;
        int cdl = f >> 6, hwl = f & 63;
        int cd = cd0 + cdl, c = cd >> 3, d = cd & 7;
        size_t addr = (size_t)((b * 96 + c) * 8 + d) * 1024 + hw0 + hwl;
        y[addr] = tile[hwl][cdl] + x[addr];
    }
}

// ---------------- depthwise 3x3x3 conv: LDS-staged channel + rolling d-window ----------------
// One block per (b,c): stage the 8x32x32 channel (32KB) in LDS, each thread computes
// 32 outputs (fixed h,w per hb-iter, all 8 d) with a rolling 3-plane register window.
__global__ __launch_bounds__(256) void k_dw(const float* __restrict__ y,
                                            const float* __restrict__ w,
                                            const float* __restrict__ bias,
                                            float* __restrict__ z) {
    __shared__ float ly[8192];  // [d][h][w]
    const int bc = blockIdx.x;
    const int c = bc % 96;
    const int tid = threadIdx.x;
    const size_t base = (size_t)bc * 8192;

#pragma unroll
    for (int i = 0; i < 8; i++) {
        int i4 = i * 256 + tid;
        *(float4*)(ly + i4 * 4) = *(const float4*)(y + base + i4 * 4);
    }
    float wt[27];
#pragma unroll
    for (int j = 0; j < 27; j++) wt[j] = w[c * 27 + j];
    const float bv = bias[c];
    __syncthreads();

    const int wcol = tid & 31;
    const int hh = tid >> 5;  // 0..7

    for (int hb = 0; hb < 4; hb++) {
        const int h = hb * 8 + hh;
        float pl[3][9];
        // plane loader: 3x3 neighborhood at depth dd (zeros outside)
        auto loadplane = [&](int dd, float* p) {
#pragma unroll
            for (int kh = 0; kh < 3; kh++) {
                int h2 = h + kh - 1;
                bool hok = (unsigned)h2 < 32u;
                const float* row = ly + dd * 1024 + h2 * 32;
#pragma unroll
                for (int kw = 0; kw < 3; kw++) {
                    int w2 = wcol + kw - 1;
                    bool ok = hok && (unsigned)w2 < 32u;
                    p[kh * 3 + kw] = ok ? row[w2] : 0.f;
                }
            }
        };
#pragma unroll
        for (int j = 0; j < 9; j++) pl[0][j] = 0.f;  // d=-1 plane
        loadplane(0, pl[1]);
#pragma unroll
        for (int d = 0; d < 8; d++) {
            if (d < 7) loadplane(d + 1, pl[2]);
            else {
#pragma unroll
                for (int j = 0; j < 9; j++) pl[2][j] = 0.f;
            }
            float acc = bv;
#pragma unroll
            for (int kd = 0; kd < 3; kd++)
#pragma unroll
                for (int j = 0; j < 9; j++) acc += wt[kd * 9 + j] * pl[kd][j];
            z[base + d * 1024 + h * 32 + wcol] = acc;
#pragma unroll
            for (int j = 0; j < 9; j++) { pl[0][j] = pl[1][j]; pl[1][j] = pl[2][j]; }
        }
    }
}

// ---------------- pointwise conv via MFMA: out = y + pw_b + W(96x96) * Z(96 x pos) ----------------
__global__ __launch_bounds__(256) void k_pw(const float* __restrict__ z,
                                            const u16* __restrict__ wbf,   // bf16 96x96 row-major
                                            const float* __restrict__ bias,
                                            float* __restrict__ out) {
    __shared__ __align__(16) u16 lZ[128 * 104];
    __shared__ __align__(16) u16 lW[96 * 104];
    const int tid = threadIdx.x;
    const int lane = tid & 63;
    const int wv = tid >> 6;
    const int lr = lane & 15;
    const int lq = lane >> 4;
    const int koff = lq * 8;

    const int idx = blockIdx.x;
    const int q = idx & 7;
    const int bd = idx >> 3;
    const int b = bd >> 3, d = bd & 7;
    const int pos0 = q * 128;

    for (int i = tid; i < 96 * 96; i += 256) {
        int row = i / 96, col = i - row * 96;
        lW[row * 104 + col] = wbf[i];
    }
    {
        const int pos = tid & 127;
        const int cc0 = (tid >> 7) * 48;
        const size_t gbase = ((size_t)b * 96 * 8 + d) * 1024 + pos0 + pos;
#pragma unroll
        for (int g = 0; g < 6; g++) {
            short8 v;
#pragma unroll
            for (int j = 0; j < 8; j++) {
                int cc = cc0 + g * 8 + j;
                v[j] = (short)f2bf(z[gbase + (size_t)cc * 8192]);
            }
            *(short8*)(lZ + pos * 104 + cc0 + g * 8) = v;
        }
    }
    __syncthreads();

    floatx4 acc[6][2];
#pragma unroll
    for (int m = 0; m < 6; m++)
#pragma unroll
        for (int nt = 0; nt < 2; nt++) acc[m][nt] = (floatx4){0.f, 0.f, 0.f, 0.f};

#pragma unroll
    for (int ks = 0; ks < 3; ks++) {
        short8 bfrg[2];
#pragma unroll
        for (int nt = 0; nt < 2; nt++)
            bfrg[nt] = *(const short8*)(lZ + (wv * 32 + nt * 16 + lr) * 104 + ks * 32 + koff);
#pragma unroll
        for (int m = 0; m < 6; m++) {
            short8 afr = *(const short8*)(lW + (m * 16 + lr) * 104 + ks * 32 + koff);
#pragma unroll
            for (int nt = 0; nt < 2; nt++)
                acc[m][nt] = __builtin_amdgcn_mfma_f32_16x16x32_bf16(afr, bfrg[nt], acc[m][nt], 0, 0, 0);
        }
    }

#pragma unroll
    for (int m = 0; m < 6; m++) {
#pragma unroll
        for (int r = 0; r < 4; r++) {
            int c = m * 16 + lq * 4 + r;
            float bv = bias[c];
            size_t rowbase = ((size_t)(b * 96 + c) * 8 + d) * 1024 + pos0;
#pragma unroll
            for (int nt = 0; nt < 2; nt++) {
                int pos = wv * 32 + nt * 16 + lr;
                size_t a = rowbase + pos;
                out[a] = out[a] + bv + acc[m][nt][r];
            }
        }
    }
}

extern "C" void kernel_launch(void* const* d_in, const int* in_sizes, int n_in,
                              void* d_out, int out_size, void* d_ws, size_t ws_size,
                              hipStream_t stream) {
    (void)in_sizes; (void)n_in; (void)out_size; (void)ws_size;
    const float* x      = (const float*)d_in[0];
    const float* pos    = (const float*)d_in[1];
    const float* qkv_w  = (const float*)d_in[2];
    const float* proj_w = (const float*)d_in[3];
    const float* proj_b = (const float*)d_in[4];
    const float* temp   = (const float*)d_in[5];
    const float* ln_g   = (const float*)d_in[6];
    const float* ln_b   = (const float*)d_in[7];
    const float* dw_w   = (const float*)d_in[8];
    const float* dw_b   = (const float*)d_in[9];
    const float* pw_w   = (const float*)d_in[10];
    const float* pw_b   = (const float*)d_in[11];
    float* out = (float*)d_out;
    char* ws = (char*)d_ws;

    u16* t    = (u16*)(ws + 0);           // swiz A, 12.58MB ; later aliased by o (swiz) and z
    u16* vT   = (u16*)(ws + 12582912);    // v swiz, 12.58MB
    u16* q    = (u16*)(ws + 25165824);    // row-major, 12.58MB ; later o2 (with kk)
    u16* kk   = (u16*)(ws + 37748736);    // k swiz, 12.58MB
    u16* wqb  = (u16*)(ws + 50331648);    // qkv_w swiz + proj_w swiz + pw_w, ~4.74MB
    float* cs   = (float*)(ws + 55150592);
    float* sqq  = (float*)(ws + 55175168);
    float* sqk  = (float*)(ws + 55199744);
    float* mu   = (float*)(ws + 55224320);
    float* rstd = (float*)(ws + 55257088);
    u16* wpb  = wqb + 2304 * 768;
    u16* wpwb = wqb + 2304 * 768 + 768 * 768;
    u16* o   = t;
    float* o2 = (float*)q;
    float* z  = (float*)t;
    float* y  = out;

    k_tpos<<<dim3(12, 16, 8), 256, 0, stream>>>(x, pos, t);
    k_cvt<<<1188, 256, 0, stream>>>(qkv_w, proj_w, pw_w, wqb);
    gemm_bt<0><<<1152, 256, 0, stream>>>(t, wqb, 8192, 2304, 768, q, kk, vT, nullptr, nullptr);
    hipMemsetAsync(sqq, 0, 49152, stream);
    k_sq<<<dim3(32, 8), 192, 0, stream>>>(q, kk, sqq, sqk);
    k_scale<<<32, 192, 0, stream>>>(sqq, sqk, temp, cs);
    k_attn<<<512, 256, 0, stream>>>(q, kk, vT, cs, o);
    gemm_bt<1><<<384, 256, 0, stream>>>(o, wpb, 8192, 768, 768, nullptr, nullptr, nullptr, proj_b, o2);
    k_lnstats<<<8192, 256, 0, stream>>>(o2, mu, rstd);
    k_lnt<<<dim3(12, 16, 8), 256, 0, stream>>>(o2, mu, rstd, ln_g, ln_b, x, y);
    k_dw<<<768, 256, 0, stream>>>(y, dw_w, dw_b, z);
    k_pw<<<512, 256, 0, stream>>>(z, wpwb, pw_b, out);
}

// Round 6
// 317.935 us; speedup vs baseline: 1.3511x; 1.0544x over previous
//
#include <hip/hip_runtime.h>

typedef unsigned short u16;
typedef unsigned int u32;

typedef __attribute__((ext_vector_type(8))) short short8;
typedef __attribute__((ext_vector_type(4))) float floatx4;

__device__ __forceinline__ float bf2f(u16 u) { return __uint_as_float(((u32)u) << 16); }
__device__ __forceinline__ u16 f2bf(float f) {
    u32 x = __float_as_uint(f);
    x += 0x7fffu + ((x >> 16) & 1u);
    return (u16)(x >> 16);
}
__device__ __forceinline__ void gl_lds16(const void* g, void* l) {
    __builtin_amdgcn_global_load_lds((const __attribute__((address_space(1))) u32*)g,
                                     (__attribute__((address_space(3))) u32*)l, 16, 0, 0);
}

// Fragment-tiled ("swiz") layouts: data grouped in 1024B chunks of [16 rows x 32 k],
// element order = gl_lds16 lane order: u16 off = chunk*512 + (((k>>3)&3)*16 + (row&15))*8 + (k&7).
// A-operands (t, o): chunk = (row>>4)*24 + (k>>5)   [K=768 -> 24 kchunks]
// W-operands (qkv_w, proj_w): same with row=n.
// K-swiz (per bh, n x dh): chunk = (n>>4)*6 + (dh>>5)
// V-swiz (per bh): chunk = (n>>5)*12 + (dh>>4), lane = ((n>>3)&3)*16 + (dh&15), low3 = n&7

// ---------------- Kernel 1: x (B,C,D,H,W) -> t swiz bf16, + pos ----------------
__global__ __launch_bounds__(256) void k_tpos(const float* __restrict__ x,
                                              const float* __restrict__ pos,
                                              u16* __restrict__ t) {
    __shared__ float tile[64][65];
    const int b = blockIdx.z, hw0 = blockIdx.y * 64, cd0 = blockIdx.x * 64;
    const int tid = threadIdx.x;
#pragma unroll
    for (int i = 0; i < 16; i++) {
        int f = i * 256 + tid;
        int cdl = f >> 6, hwl = f & 63;
        int cd = cd0 + cdl, c = cd >> 3, d = cd & 7;
        tile[cdl][hwl] = x[(size_t)(((b * 96 + c) * 8 + d)) * 1024 + hw0 + hwl];
    }
    __syncthreads();
#pragma unroll
    for (int it = 0; it < 2; it++) {
        int u = it * 256 + tid;       // 512 units of 16B
        int ch = u >> 6, l = u & 63;
        int n16l = ch >> 1, kcl = ch & 1;
        int hwl = n16l * 16 + (l & 15);
        int cdl = kcl * 32 + (l >> 4) * 8;
        int row = b * 1024 + hw0 + hwl;
        int cd = cd0 + cdl;
        const float* pp = pos + (size_t)(hw0 + hwl) * 768 + cd;
        float4 p0 = *(const float4*)pp;
        float4 p1 = *(const float4*)(pp + 4);
        short8 v;
        v[0] = (short)f2bf(tile[cdl + 0][hwl] + p0.x);
        v[1] = (short)f2bf(tile[cdl + 1][hwl] + p0.y);
        v[2] = (short)f2bf(tile[cdl + 2][hwl] + p0.z);
        v[3] = (short)f2bf(tile[cdl + 3][hwl] + p0.w);
        v[4] = (short)f2bf(tile[cdl + 4][hwl] + p1.x);
        v[5] = (short)f2bf(tile[cdl + 5][hwl] + p1.y);
        v[6] = (short)f2bf(tile[cdl + 6][hwl] + p1.z);
        v[7] = (short)f2bf(tile[cdl + 7][hwl] + p1.w);
        size_t chunk = (size_t)(row >> 4) * 24 + (cd >> 5);
        *(short8*)(t + chunk * 512 + l * 8) = v;
    }
}

// ---------------- weight cvt: qkv_w swiz, proj_w swiz, pw_w row-major ----------------
__global__ __launch_bounds__(256) void k_cvt(const float* __restrict__ wq,
                                             const float* __restrict__ wp,
                                             const float* __restrict__ wpw,
                                             u16* __restrict__ out) {
    const int NQ = 144 * 24 * 64;          // qkv 16B-units
    const int NP = NQ + 48 * 24 * 64;      // + proj 16B-units
    int u = blockIdx.x * 256 + threadIdx.x;
    if (u < NP) {
        const float* w = (u < NQ) ? wq : wp;
        int ub = (u < NQ) ? u : u - NQ;
        int chunk = ub >> 6, l = ub & 63;
        int n16 = chunk / 24, kc = chunk - n16 * 24;
        int n = n16 * 16 + (l & 15);
        int k0 = kc * 32 + (l >> 4) * 8;
        const float* src = w + (size_t)n * 768 + k0;
        float4 a = *(const float4*)src;
        float4 b2 = *(const float4*)(src + 4);
        short8 v;
        v[0] = (short)f2bf(a.x);  v[1] = (short)f2bf(a.y);
        v[2] = (short)f2bf(a.z);  v[3] = (short)f2bf(a.w);
        v[4] = (short)f2bf(b2.x); v[5] = (short)f2bf(b2.y);
        v[6] = (short)f2bf(b2.z); v[7] = (short)f2bf(b2.w);
        *(short8*)(out + (size_t)u * 8) = v;
    } else {
        int i = u - NP;  // 9216 pw elements
        out[(size_t)NP * 8 + i] = f2bf(wpw[i]);
    }
}

// ---------------- GEMM: C(M,N) = A_swiz(M,K) * W_swiz(N,K)^T, bf16 MFMA ----------------
// BK=64 (two 32-k halves per barrier: 8 loads/thread in flight, half the drains).
// XCD-pinned swizzle: all n-blocks of one m-tile run on one XCD -> A stays in that L2.
// MODE 0: QKV epilogue -> q row-major [b,h,n,dh], k swiz, v swiz
// MODE 1: proj epilogue -> Co fp32 row-major + bias
template <int MODE>
__global__ __launch_bounds__(256) void gemm_bt(const u16* __restrict__ A,
                                               const u16* __restrict__ Bw,
                                               int M, int N, int K,
                                               u16* __restrict__ qo, u16* __restrict__ ko,
                                               u16* __restrict__ vo,
                                               const float* __restrict__ bias,
                                               float* __restrict__ Co) {
    __shared__ __align__(16) u16 lA[16 * 512];  // 16KB: chunks [khalf*8 + rowblock]
    __shared__ __align__(16) u16 lB[16 * 512];
    const int tid = threadIdx.x;
    const int lane = tid & 63;
    const int wv = tid >> 6;
    const int wr = wv >> 1, wc = wv & 1;
    const int ntiles = N >> 7;
    const int mtiles = M >> 7;                 // 64
    const int lin = blockIdx.x;
    const int xcd = lin & 7;
    const int idx = lin >> 3;
    const int mlocal = idx / ntiles;
    const int ntile = idx - mlocal * ntiles;
    const int m0 = (xcd * (mtiles >> 3) + mlocal) << 7;
    const int n0 = ntile << 7;
    const int lr = lane & 15;
    const int lq = lane >> 4;

    floatx4 acc[4][4];
#pragma unroll
    for (int i = 0; i < 4; i++)
#pragma unroll
        for (int j = 0; j < 4; j++) acc[i][j] = (floatx4){0.f, 0.f, 0.f, 0.f};

    const int m16 = m0 >> 4, n16 = n0 >> 4;
    for (int kc2 = 0; kc2 < (K >> 6); kc2++) {
        __syncthreads();
#pragma unroll
        for (int kh = 0; kh < 2; kh++) {
#pragma unroll
            for (int i = 0; i < 2; i++) {
                int ch16 = i * 4 + wv;       // 16-row block of the 128-row tile
                int kc = kc2 * 2 + kh;
                const u16* ga = A + ((size_t)(m16 + ch16) * 24 + kc) * 512 + lane * 8;
                gl_lds16(ga, (char*)lA + (kh * 8 + ch16) * 1024);
                const u16* gb = Bw + ((size_t)(n16 + ch16) * 24 + kc) * 512 + lane * 8;
                gl_lds16(gb, (char*)lB + (kh * 8 + ch16) * 1024);
            }
        }
        __syncthreads();
#pragma unroll
        for (int kh = 0; kh < 2; kh++) {
            short8 af[4], bfr[4];
#pragma unroll
            for (int tt = 0; tt < 4; tt++) {
                af[tt] = *(const short8*)(lA + ((kh * 8 + wr * 4 + tt) * 64 + lane) * 8);
                bfr[tt] = *(const short8*)(lB + ((kh * 8 + wc * 4 + tt) * 64 + lane) * 8);
            }
#pragma unroll
            for (int mt = 0; mt < 4; mt++)
#pragma unroll
                for (int nt = 0; nt < 4; nt++)
                    acc[mt][nt] = __builtin_amdgcn_mfma_f32_16x16x32_bf16(af[mt], bfr[nt], acc[mt][nt], 0, 0, 0);
        }
    }

    if (MODE == 0) {
        const int region = n0 / 768;       // whole block is q, k, or v
        const int n0r = n0 - region * 768;
#pragma unroll
        for (int nt = 0; nt < 4; nt++) {
            int colb = n0r + wc * 64 + nt * 16;   // 16-aligned, within one h
            int h = colb / 192;
            int dh = colb - h * 192 + lr;
#pragma unroll
            for (int mt = 0; mt < 4; mt++) {
#pragma unroll
                for (int r = 0; r < 4; r++) {
                    int row = m0 + wr * 64 + mt * 16 + lq * 4 + r;
                    int b = row >> 10, n = row & 1023;
                    u16 val = f2bf(acc[mt][nt][r]);
                    size_t bh = (size_t)(b * 4 + h);
                    if (region == 0) {
                        qo[(bh * 1024 + n) * 192 + dh] = val;
                    } else if (region == 1) {
                        ko[bh * 196608 + (n >> 4) * 3072 + (dh >> 5) * 512 +
                           ((dh >> 3) & 3) * 128 + (n & 15) * 8 + (dh & 7)] = val;
                    } else {
                        vo[bh * 196608 + (n >> 5) * 6144 + (dh >> 4) * 512 +
                           ((n >> 3) & 3) * 128 + (dh & 15) * 8 + (n & 7)] = val;
                    }
                }
            }
        }
    } else {
#pragma unroll
        for (int nt = 0; nt < 4; nt++) {
            int col = n0 + wc * 64 + nt * 16 + lr;
            float bv = bias[col];
#pragma unroll
            for (int mt = 0; mt < 4; mt++) {
#pragma unroll
                for (int r = 0; r < 4; r++) {
                    int row = m0 + wr * 64 + mt * 16 + lq * 4 + r;
                    Co[(size_t)row * N + col] = acc[mt][nt][r] + bv;
                }
            }
        }
    }
}

// ---------------- column sum-of-squares over sequence (q row-major, k swiz) ----------------
__global__ void k_sq(const u16* __restrict__ q, const u16* __restrict__ k,
                     float* __restrict__ sqq, float* __restrict__ sqk) {
    int bh = blockIdx.x;
    int part = blockIdx.y;
    int dh = threadIdx.x;  // 192
    const u16* qp = q + ((size_t)bh * 1024 + part * 128) * 192 + dh;
    float aq = 0.f;
#pragma unroll 4
    for (int n = 0; n < 128; n++) {
        float a = bf2f(qp[(size_t)n * 192]);
        aq += a * a;
    }
    const u16* kbase = k + (size_t)bh * 196608 + (dh >> 5) * 512 + ((dh >> 3) & 3) * 128 + (dh & 7);
    float ak = 0.f;
#pragma unroll 4
    for (int n = 0; n < 128; n++) {
        int nn = part * 128 + n;
        float c2 = bf2f(kbase[(nn >> 4) * 3072 + (nn & 15) * 8]);
        ak += c2 * c2;
    }
    atomicAdd(&sqq[bh * 192 + dh], aq);
    atomicAdd(&sqk[bh * 192 + dh], ak);
}

__global__ void k_scale(const float* __restrict__ sqq, const float* __restrict__ sqk,
                        const float* __restrict__ temp, float* __restrict__ cs) {
    int bh = blockIdx.x;
    int dh = threadIdx.x;
    float rq = 1.f / fmaxf(sqrtf(sqq[bh * 192 + dh]), 1e-12f);
    float rk = 1.f / fmaxf(sqrtf(sqk[bh * 192 + dh]), 1e-12f);
    cs[bh * 192 + dh] = rq * rk * temp[bh & 3];
}

// ---------------- flash attention: one WG per (bh, 64-row q block) ----------------
// K/V pre-swizzled in global: staging = contiguous 1024B per gl_lds16, LDS reads identity.
__global__ __launch_bounds__(256) void k_attn(const u16* __restrict__ q,
                                              const u16* __restrict__ kmat,
                                              const u16* __restrict__ vT,
                                              const float* __restrict__ cs,
                                              u16* __restrict__ o) {
    __shared__ __align__(16) u16 lK[24 * 512];
    __shared__ __align__(16) u16 lV[24 * 512];
    __shared__ __align__(16) u16 lP[4 * 1024];
    const int lin = blockIdx.x;
    const int qb = (lin >> 3) & 15;
    const int bh = (lin & 7) * 4 + (lin >> 7);
    const int b = bh >> 2, h = bh & 3;
    const int tid = threadIdx.x;
    const int lane = tid & 63;
    const int wv = tid >> 6;
    const int lr = lane & 15;
    const int lq = lane >> 4;
    const int koff = lq * 8;

    const u16* qbase = q + (size_t)bh * 1024 * 192;
    const u16* kbase = kmat + (size_t)bh * 196608;
    const u16* vbase = vT + (size_t)bh * 196608;
    const float* cp = cs + bh * 192;

    const int qrow = qb * 64 + wv * 16 + lr;
    const u16* qp = qbase + (size_t)qrow * 192;
    short8 qf[6];
#pragma unroll
    for (int ks = 0; ks < 6; ks++) {
        short8 raw = *(const short8*)(qp + ks * 32 + koff);
        short8 sc;
#pragma unroll
        for (int j = 0; j < 8; j++) {
            float f = bf2f((u16)raw[j]) * cp[ks * 32 + koff + j];
            sc[j] = (short)f2bf(f);
        }
        qf[ks] = sc;
    }

    float m_r[4], l_r[4];
    floatx4 oacc[12];
#pragma unroll
    for (int r = 0; r < 4; r++) { m_r[r] = -1e30f; l_r[r] = 0.f; }
#pragma unroll
    for (int vt = 0; vt < 12; vt++) oacc[vt] = (floatx4){0.f, 0.f, 0.f, 0.f};

    u16* lp = lP + wv * 1024;

    for (int kb = 0; kb < 16; kb++) {
        __syncthreads();
#pragma unroll
        for (int i = 0; i < 6; i++) {
            int ch = i * 4 + wv;  // 0..23
            int ks = ch >> 2, nt = ch & 3;
            const u16* gk = kbase + ((size_t)(kb * 4 + nt) * 6 + ks) * 512 + lane * 8;
            gl_lds16(gk, (char*)lK + ch * 1024);
            int ks2 = ch / 12, vt2 = ch - ks2 * 12;
            const u16* gv = vbase + ((size_t)(kb * 2 + ks2) * 12 + vt2) * 512 + lane * 8;
            gl_lds16(gv, (char*)lV + ch * 1024);
        }
        __syncthreads();

        floatx4 s[4];
#pragma unroll
        for (int nt = 0; nt < 4; nt++) s[nt] = (floatx4){0.f, 0.f, 0.f, 0.f};
#pragma unroll
        for (int ks = 0; ks < 6; ks++) {
#pragma unroll
            for (int nt = 0; nt < 4; nt++) {
                short8 kf = *(const short8*)(lK + ((ks * 4 + nt) * 64 + lane) * 8);
                s[nt] = __builtin_amdgcn_mfma_f32_16x16x32_bf16(qf[ks], kf, s[nt], 0, 0, 0);
            }
        }

        float rmax[4];
#pragma unroll
        for (int r = 0; r < 4; r++)
            rmax[r] = fmaxf(fmaxf(s[0][r], s[1][r]), fmaxf(s[2][r], s[3][r]));
#pragma unroll
        for (int m = 1; m < 16; m <<= 1)
#pragma unroll
            for (int r = 0; r < 4; r++) rmax[r] = fmaxf(rmax[r], __shfl_xor(rmax[r], m));
        float alpha[4];
#pragma unroll
        for (int r = 0; r < 4; r++) {
            float mn = fmaxf(m_r[r], rmax[r]);
            alpha[r] = __expf(m_r[r] - mn);
            m_r[r] = mn;
        }
        float rsum[4] = {0.f, 0.f, 0.f, 0.f};
#pragma unroll
        for (int nt = 0; nt < 4; nt++)
#pragma unroll
            for (int r = 0; r < 4; r++) {
                float p = __expf(s[nt][r] - m_r[r]);
                s[nt][r] = p;
                rsum[r] += p;
            }
#pragma unroll
        for (int m = 1; m < 16; m <<= 1)
#pragma unroll
            for (int r = 0; r < 4; r++) rsum[r] += __shfl_xor(rsum[r], m);
#pragma unroll
        for (int r = 0; r < 4; r++) l_r[r] = l_r[r] * alpha[r] + rsum[r];
#pragma unroll
        for (int vt = 0; vt < 12; vt++)
#pragma unroll
            for (int r = 0; r < 4; r++) oacc[vt][r] *= alpha[r];

        // P -> per-wave LDS in A-fragment order
#pragma unroll
        for (int nt = 0; nt < 4; nt++) {
            int base2 = (nt >> 1) * 512 + ((nt & 1) * 2 + (lr >> 3)) * 128 + (lr & 7);
#pragma unroll
            for (int r = 0; r < 4; r++)
                lp[base2 + (lq * 4 + r) * 8] = f2bf(s[nt][r]);
        }

#pragma unroll
        for (int ks2 = 0; ks2 < 2; ks2++) {
            short8 pf = *(const short8*)(lp + ks2 * 512 + lane * 8);
#pragma unroll
            for (int vt = 0; vt < 12; vt++) {
                short8 vf = *(const short8*)(lV + ((ks2 * 12 + vt) * 64 + lane) * 8);
                oacc[vt] = __builtin_amdgcn_mfma_f32_16x16x32_bf16(pf, vf, oacc[vt], 0, 0, 0);
            }
        }
    }

    // epilogue: divide by l, write o in swiz (A-operand) layout for proj gemm
    float inv[4];
#pragma unroll
    for (int r = 0; r < 4; r++) inv[r] = 1.f / l_r[r];
#pragma unroll
    for (int vt = 0; vt < 12; vt++) {
        int col = h * 192 + vt * 16 + lr;
#pragma unroll
        for (int r = 0; r < 4; r++) {
            int rowg = b * 1024 + qb * 64 + wv * 16 + lq * 4 + r;
            size_t addr = (size_t)(rowg >> 4) * 12288 + (col >> 5) * 512 +
                          ((col >> 3) & 3) * 128 + (rowg & 15) * 8 + (col & 7);
            o[addr] = f2bf(oacc[vt][r] * inv[r]);
        }
    }
}

// ---------------- LN stats per row ----------------
__global__ __launch_bounds__(256) void k_lnstats(const float* __restrict__ o2,
                                                 float* __restrict__ mu,
                                                 float* __restrict__ rstd) {
    int row = blockIdx.x;
    int tid = threadIdx.x;
    const float* p = o2 + (size_t)row * 768;
    float s = 0.f, ss = 0.f;
    for (int i = tid; i < 768; i += 256) {
        float v = p[i];
        s += v;
        ss += v * v;
    }
#pragma unroll
    for (int m = 32; m >= 1; m >>= 1) {
        s += __shfl_xor(s, m);
        ss += __shfl_xor(ss, m);
    }
    __shared__ float as[4], ass[4];
    if ((tid & 63) == 0) {
        as[tid >> 6] = s;
        ass[tid >> 6] = ss;
    }
    __syncthreads();
    if (tid == 0) {
        float S = as[0] + as[1] + as[2] + as[3];
        float SS = ass[0] + ass[1] + ass[2] + ass[3];
        float m_ = S * (1.f / 768.f);
        float v = SS * (1.f / 768.f) - m_ * m_;
        v = fmaxf(v, 0.f);
        mu[row] = m_;
        rstd[row] = rsqrtf(v + 1e-5f);
    }
}

// ---------------- LN apply + transpose back + residual: y = LN(o2)^T + x ----------------
__global__ __launch_bounds__(256) void k_lnt(const float* __restrict__ o2,
                                             const float* __restrict__ mu,
                                             const float* __restrict__ rstd,
                                             const float* __restrict__ gamma,
                                             const float* __restrict__ beta,
                                             const float* __restrict__ x,
                                             float* __restrict__ y) {
    __shared__ float tile[64][65];
    const int b = blockIdx.z, hw0 = blockIdx.y * 64, cd0 = blockIdx.x * 64;
    const int tid = threadIdx.x;
#pragma unroll
    for (int i = 0; i < 16; i++) {
        int f = i * 256 + tid;
        int hwl = f >> 6, cdl = f & 63;
        int row = b * 1024 + hw0 + hwl;
        float v = o2[(size_t)row * 768 + cd0 + cdl];
        v = (v - mu[row]) * rstd[row] * gamma[cd0 + cdl] + beta[cd0 + cdl];
        tile[hwl][cdl] = v;
    }
    __syncthreads();
#pragma unroll
    for (int i = 0; i < 16; i++) {
        int f = i * 256 + tid;
        int cdl = f >> 6, hwl = f & 63;
        int cd = cd0 + cdl, c = cd >> 3, d = cd & 7;
        size_t addr = (size_t)((b * 96 + c) * 8 + d) * 1024 + hw0 + hwl;
        y[addr] = tile[hwl][cdl] + x[addr];
    }
}

// ---------------- depthwise 3x3x3 conv: LDS-staged channel + rolling d-window ----------------
__global__ __launch_bounds__(256) void k_dw(const float* __restrict__ y,
                                            const float* __restrict__ w,
                                            const float* __restrict__ bias,
                                            float* __restrict__ z) {
    __shared__ float ly[8192];  // [d][h][w]
    const int bc = blockIdx.x;
    const int c = bc % 96;
    const int tid = threadIdx.x;
    const size_t base = (size_t)bc * 8192;

#pragma unroll
    for (int i = 0; i < 8; i++) {
        int i4 = i * 256 + tid;
        *(float4*)(ly + i4 * 4) = *(const float4*)(y + base + i4 * 4);
    }
    float wt[27];
#pragma unroll
    for (int j = 0; j < 27; j++) wt[j] = w[c * 27 + j];
    const float bv = bias[c];
    __syncthreads();

    const int wcol = tid & 31;
    const int hh = tid >> 5;  // 0..7

    for (int hb = 0; hb < 4; hb++) {
        const int h = hb * 8 + hh;
        float pl[3][9];
        auto loadplane = [&](int dd, float* p) {
#pragma unroll
            for (int kh = 0; kh < 3; kh++) {
                int h2 = h + kh - 1;
                bool hok = (unsigned)h2 < 32u;
                const float* row = ly + dd * 1024 + h2 * 32;
#pragma unroll
                for (int kw = 0; kw < 3; kw++) {
                    int w2 = wcol + kw - 1;
                    bool ok = hok && (unsigned)w2 < 32u;
                    p[kh * 3 + kw] = ok ? row[w2] : 0.f;
                }
            }
        };
#pragma unroll
        for (int j = 0; j < 9; j++) pl[0][j] = 0.f;  // d=-1 plane
        loadplane(0, pl[1]);
#pragma unroll
        for (int d = 0; d < 8; d++) {
            if (d < 7) loadplane(d + 1, pl[2]);
            else {
#pragma unroll
                for (int j = 0; j < 9; j++) pl[2][j] = 0.f;
            }
            float acc = bv;
#pragma unroll
            for (int kd = 0; kd < 3; kd++)
#pragma unroll
                for (int j = 0; j < 9; j++) acc += wt[kd * 9 + j] * pl[kd][j];
            z[base + d * 1024 + h * 32 + wcol] = acc;
#pragma unroll
            for (int j = 0; j < 9; j++) { pl[0][j] = pl[1][j]; pl[1][j] = pl[2][j]; }
        }
    }
}

// ---------------- pointwise conv via MFMA: out = y + pw_b + W(96x96) * Z(96 x pos) ----------------
__global__ __launch_bounds__(256) void k_pw(const float* __restrict__ z,
                                            const u16* __restrict__ wbf,   // bf16 96x96 row-major
                                            const float* __restrict__ bias,
                                            float* __restrict__ out) {
    __shared__ __align__(16) u16 lZ[128 * 104];
    __shared__ __align__(16) u16 lW[96 * 104];
    const int tid = threadIdx.x;
    const int lane = tid & 63;
    const int wv = tid >> 6;
    const int lr = lane & 15;
    const int lq = lane >> 4;
    const int koff = lq * 8;

    const int idx = blockIdx.x;
    const int q = idx & 7;
    const int bd = idx >> 3;
    const int b = bd >> 3, d = bd & 7;
    const int pos0 = q * 128;

    for (int i = tid; i < 96 * 96; i += 256) {
        int row = i / 96, col = i - row * 96;
        lW[row * 104 + col] = wbf[i];
    }
    {
        const int pos = tid & 127;
        const int cc0 = (tid >> 7) * 48;
        const size_t gbase = ((size_t)b * 96 * 8 + d) * 1024 + pos0 + pos;
#pragma unroll
        for (int g = 0; g < 6; g++) {
            short8 v;
#pragma unroll
            for (int j = 0; j < 8; j++) {
                int cc = cc0 + g * 8 + j;
                v[j] = (short)f2bf(z[gbase + (size_t)cc * 8192]);
            }
            *(short8*)(lZ + pos * 104 + cc0 + g * 8) = v;
        }
    }
    __syncthreads();

    floatx4 acc[6][2];
#pragma unroll
    for (int m = 0; m < 6; m++)
#pragma unroll
        for (int nt = 0; nt < 2; nt++) acc[m][nt] = (floatx4){0.f, 0.f, 0.f, 0.f};

#pragma unroll
    for (int ks = 0; ks < 3; ks++) {
        short8 bfrg[2];
#pragma unroll
        for (int nt = 0; nt < 2; nt++)
            bfrg[nt] = *(const short8*)(lZ + (wv * 32 + nt * 16 + lr) * 104 + ks * 32 + koff);
#pragma unroll
        for (int m = 0; m < 6; m++) {
            short8 afr = *(const short8*)(lW + (m * 16 + lr) * 104 + ks * 32 + koff);
#pragma unroll
            for (int nt = 0; nt < 2; nt++)
                acc[m][nt] = __builtin_amdgcn_mfma_f32_16x16x32_bf16(afr, bfrg[nt], acc[m][nt], 0, 0, 0);
        }
    }

#pragma unroll
    for (int m = 0; m < 6; m++) {
#pragma unroll
        for (int r = 0; r < 4; r++) {
            int c = m * 16 + lq * 4 + r;
            float bv = bias[c];
            size_t rowbase = ((size_t)(b * 96 + c) * 8 + d) * 1024 + pos0;
#pragma unroll
            for (int nt = 0; nt < 2; nt++) {
                int pos = wv * 32 + nt * 16 + lr;
                size_t a = rowbase + pos;
                out[a] = out[a] + bv + acc[m][nt][r];
            }
        }
    }
}

extern "C" void kernel_launch(void* const* d_in, const int* in_sizes, int n_in,
                              void* d_out, int out_size, void* d_ws, size_t ws_size,
                              hipStream_t stream) {
    (void)in_sizes; (void)n_in; (void)out_size; (void)ws_size;
    const float* x      = (const float*)d_in[0];
    const float* pos    = (const float*)d_in[1];
    const float* qkv_w  = (const float*)d_in[2];
    const float* proj_w = (const float*)d_in[3];
    const float* proj_b = (const float*)d_in[4];
    const float* temp   = (const float*)d_in[5];
    const float* ln_g   = (const float*)d_in[6];
    const float* ln_b   = (const float*)d_in[7];
    const float* dw_w   = (const float*)d_in[8];
    const float* dw_b   = (const float*)d_in[9];
    const float* pw_w   = (const float*)d_in[10];
    const float* pw_b   = (const float*)d_in[11];
    float* out = (float*)d_out;
    char* ws = (char*)d_ws;

    u16* t    = (u16*)(ws + 0);           // swiz A, 12.58MB ; later aliased by o (swiz) and z
    u16* vT   = (u16*)(ws + 12582912);    // v swiz, 12.58MB
    u16* q    = (u16*)(ws + 25165824);    // row-major, 12.58MB ; later o2 (with kk)
    u16* kk   = (u16*)(ws + 37748736);    // k swiz, 12.58MB
    u16* wqb  = (u16*)(ws + 50331648);    // qkv_w swiz + proj_w swiz + pw_w, ~4.74MB
    float* cs   = (float*)(ws + 55150592);
    float* sqq  = (float*)(ws + 55175168);
    float* sqk  = (float*)(ws + 55199744);
    float* mu   = (float*)(ws + 55224320);
    float* rstd = (float*)(ws + 55257088);
    u16* wpb  = wqb + 2304 * 768;
    u16* wpwb = wqb + 2304 * 768 + 768 * 768;
    u16* o   = t;
    float* o2 = (float*)q;
    float* z  = (float*)t;
    float* y  = out;

    k_tpos<<<dim3(12, 16, 8), 256, 0, stream>>>(x, pos, t);
    k_cvt<<<1188, 256, 0, stream>>>(qkv_w, proj_w, pw_w, wqb);
    gemm_bt<0><<<1152, 256, 0, stream>>>(t, wqb, 8192, 2304, 768, q, kk, vT, nullptr, nullptr);
    hipMemsetAsync(sqq, 0, 49152, stream);
    k_sq<<<dim3(32, 8), 192, 0, stream>>>(q, kk, sqq, sqk);
    k_scale<<<32, 192, 0, stream>>>(sqq, sqk, temp, cs);
    k_attn<<<512, 256, 0, stream>>>(q, kk, vT, cs, o);
    gemm_bt<1><<<384, 256, 0, stream>>>(o, wpb, 8192, 768, 768, nullptr, nullptr, nullptr, proj_b, o2);
    k_lnstats<<<8192, 256, 0, stream>>>(o2, mu, rstd);
    k_lnt<<<dim3(12, 16, 8), 256, 0, stream>>>(o2, mu, rstd, ln_g, ln_b, x, y);
    k_dw<<<768, 256, 0, stream>>>(y, dw_w, dw_b, z);
    k_pw<<<512, 256, 0, stream>>>(z, wpwb, pw_b, out);
}

// Round 7
// 295.232 us; speedup vs baseline: 1.4550x; 1.0769x over previous
//
#include <hip/hip_runtime.h>

typedef unsigned short u16;
typedef unsigned int u32;

typedef __attribute__((ext_vector_type(8))) short short8;
typedef __attribute__((ext_vector_type(4))) float floatx4;

__device__ __forceinline__ float bf2f(u16 u) { return __uint_as_float(((u32)u) << 16); }
__device__ __forceinline__ u16 f2bf(float f) {
    u32 x = __float_as_uint(f);
    x += 0x7fffu + ((x >> 16) & 1u);
    return (u16)(x >> 16);
}
__device__ __forceinline__ void gl_lds16(const void* g, void* l) {
    __builtin_amdgcn_global_load_lds((const __attribute__((address_space(1))) u32*)g,
                                     (__attribute__((address_space(3))) u32*)l, 16, 0, 0);
}

// Fragment-tiled ("swiz") layouts: data grouped in 1024B chunks of [16 rows x 32 k],
// element order = gl_lds16 lane order: u16 off = chunk*512 + (((k>>3)&3)*16 + (row&15))*8 + (k&7).
// A-operands (t, o): chunk = (row>>4)*24 + (k>>5)   [K=768 -> 24 kchunks]
// W-operands (qkv_w, proj_w): same with row=n.
// K-swiz (per bh, n x dh): chunk = (n>>4)*6 + (dh>>5)
// V-swiz (per bh): chunk = (n>>5)*12 + (dh>>4), lane = ((n>>3)&3)*16 + (dh&15), low3 = n&7

// ---------------- Kernel 1: x (B,C,D,H,W) -> t swiz bf16, + pos ----------------
__global__ __launch_bounds__(256) void k_tpos(const float* __restrict__ x,
                                              const float* __restrict__ pos,
                                              u16* __restrict__ t) {
    __shared__ float tile[64][65];
    const int b = blockIdx.z, hw0 = blockIdx.y * 64, cd0 = blockIdx.x * 64;
    const int tid = threadIdx.x;
#pragma unroll
    for (int i = 0; i < 16; i++) {
        int f = i * 256 + tid;
        int cdl = f >> 6, hwl = f & 63;
        int cd = cd0 + cdl, c = cd >> 3, d = cd & 7;
        tile[cdl][hwl] = x[(size_t)(((b * 96 + c) * 8 + d)) * 1024 + hw0 + hwl];
    }
    __syncthreads();
#pragma unroll
    for (int it = 0; it < 2; it++) {
        int u = it * 256 + tid;       // 512 units of 16B
        int ch = u >> 6, l = u & 63;
        int n16l = ch >> 1, kcl = ch & 1;
        int hwl = n16l * 16 + (l & 15);
        int cdl = kcl * 32 + (l >> 4) * 8;
        int row = b * 1024 + hw0 + hwl;
        int cd = cd0 + cdl;
        const float* pp = pos + (size_t)(hw0 + hwl) * 768 + cd;
        float4 p0 = *(const float4*)pp;
        float4 p1 = *(const float4*)(pp + 4);
        short8 v;
        v[0] = (short)f2bf(tile[cdl + 0][hwl] + p0.x);
        v[1] = (short)f2bf(tile[cdl + 1][hwl] + p0.y);
        v[2] = (short)f2bf(tile[cdl + 2][hwl] + p0.z);
        v[3] = (short)f2bf(tile[cdl + 3][hwl] + p0.w);
        v[4] = (short)f2bf(tile[cdl + 4][hwl] + p1.x);
        v[5] = (short)f2bf(tile[cdl + 5][hwl] + p1.y);
        v[6] = (short)f2bf(tile[cdl + 6][hwl] + p1.z);
        v[7] = (short)f2bf(tile[cdl + 7][hwl] + p1.w);
        size_t chunk = (size_t)(row >> 4) * 24 + (cd >> 5);
        *(short8*)(t + chunk * 512 + l * 8) = v;
    }
}

// ---------------- weight cvt: qkv_w swiz, proj_w swiz, pw_w row-major ----------------
__global__ __launch_bounds__(256) void k_cvt(const float* __restrict__ wq,
                                             const float* __restrict__ wp,
                                             const float* __restrict__ wpw,
                                             u16* __restrict__ out) {
    const int NQ = 144 * 24 * 64;          // qkv 16B-units
    const int NP = NQ + 48 * 24 * 64;      // + proj 16B-units
    int u = blockIdx.x * 256 + threadIdx.x;
    if (u < NP) {
        const float* w = (u < NQ) ? wq : wp;
        int ub = (u < NQ) ? u : u - NQ;
        int chunk = ub >> 6, l = ub & 63;
        int n16 = chunk / 24, kc = chunk - n16 * 24;
        int n = n16 * 16 + (l & 15);
        int k0 = kc * 32 + (l >> 4) * 8;
        const float* src = w + (size_t)n * 768 + k0;
        float4 a = *(const float4*)src;
        float4 b2 = *(const float4*)(src + 4);
        short8 v;
        v[0] = (short)f2bf(a.x);  v[1] = (short)f2bf(a.y);
        v[2] = (short)f2bf(a.z);  v[3] = (short)f2bf(a.w);
        v[4] = (short)f2bf(b2.x); v[5] = (short)f2bf(b2.y);
        v[6] = (short)f2bf(b2.z); v[7] = (short)f2bf(b2.w);
        *(short8*)(out + (size_t)u * 8) = v;
    } else {
        int i = u - NP;  // 9216 pw elements
        out[(size_t)NP * 8 + i] = f2bf(wpw[i]);
    }
}

// ---------------- GEMM: C(M,N) = A_swiz(M,K) * W_swiz(N,K)^T, bf16 MFMA ----------------
// BK=64, XCD-pinned swizzle. MODE 0 k/v epilogue staged through LDS -> 1024B coalesced stores.
template <int MODE>
__global__ __launch_bounds__(256) void gemm_bt(const u16* __restrict__ A,
                                               const u16* __restrict__ Bw,
                                               int M, int N, int K,
                                               u16* __restrict__ qo, u16* __restrict__ ko,
                                               u16* __restrict__ vo,
                                               const float* __restrict__ bias,
                                               float* __restrict__ Co) {
    __shared__ __align__(16) u16 lAB[32 * 512];  // 32KB: lA = [0..16), lB = [16..32) chunks
    u16* lA = lAB;
    u16* lB = lAB + 16 * 512;
    const int tid = threadIdx.x;
    const int lane = tid & 63;
    const int wv = tid >> 6;
    const int wr = wv >> 1, wc = wv & 1;
    const int ntiles = N >> 7;
    const int mtiles = M >> 7;                 // 64
    const int lin = blockIdx.x;
    const int xcd = lin & 7;
    const int idx = lin >> 3;
    const int mlocal = idx / ntiles;
    const int ntile = idx - mlocal * ntiles;
    const int m0 = (xcd * (mtiles >> 3) + mlocal) << 7;
    const int n0 = ntile << 7;
    const int lr = lane & 15;
    const int lq = lane >> 4;

    floatx4 acc[4][4];
#pragma unroll
    for (int i = 0; i < 4; i++)
#pragma unroll
        for (int j = 0; j < 4; j++) acc[i][j] = (floatx4){0.f, 0.f, 0.f, 0.f};

    const int m16 = m0 >> 4, n16 = n0 >> 4;
    for (int kc2 = 0; kc2 < (K >> 6); kc2++) {
        __syncthreads();
#pragma unroll
        for (int kh = 0; kh < 2; kh++) {
#pragma unroll
            for (int i = 0; i < 2; i++) {
                int ch16 = i * 4 + wv;       // 16-row block of the 128-row tile
                int kc = kc2 * 2 + kh;
                const u16* ga = A + ((size_t)(m16 + ch16) * 24 + kc) * 512 + lane * 8;
                gl_lds16(ga, (char*)lA + (kh * 8 + ch16) * 1024);
                const u16* gb = Bw + ((size_t)(n16 + ch16) * 24 + kc) * 512 + lane * 8;
                gl_lds16(gb, (char*)lB + (kh * 8 + ch16) * 1024);
            }
        }
        __syncthreads();
#pragma unroll
        for (int kh = 0; kh < 2; kh++) {
            short8 af[4], bfr[4];
#pragma unroll
            for (int tt = 0; tt < 4; tt++) {
                af[tt] = *(const short8*)(lA + ((kh * 8 + wr * 4 + tt) * 64 + lane) * 8);
                bfr[tt] = *(const short8*)(lB + ((kh * 8 + wc * 4 + tt) * 64 + lane) * 8);
            }
#pragma unroll
            for (int mt = 0; mt < 4; mt++)
#pragma unroll
                for (int nt = 0; nt < 4; nt++)
                    acc[mt][nt] = __builtin_amdgcn_mfma_f32_16x16x32_bf16(af[mt], bfr[nt], acc[mt][nt], 0, 0, 0);
        }
    }

    if (MODE == 0) {
        const int region = n0 / 768;       // whole block is q, k, or v
        const int n0r = n0 - region * 768;
        if (region == 0) {
            // q: direct row-major stores (32B segments)
#pragma unroll
            for (int nt = 0; nt < 4; nt++) {
                int colb = n0r + wc * 64 + nt * 16;
                int h = colb / 192;
                int dh = colb - h * 192 + lr;
#pragma unroll
                for (int mt = 0; mt < 4; mt++) {
#pragma unroll
                    for (int r = 0; r < 4; r++) {
                        int row = m0 + wr * 64 + mt * 16 + lq * 4 + r;
                        int b = row >> 10, n = row & 1023;
                        qo[((size_t)(b * 4 + h) * 1024 + n) * 192 + dh] = f2bf(acc[mt][nt][r]);
                    }
                }
            }
        } else {
            // k/v: stage the 128x128 bf16 tile in LDS at swiz-exact offsets, bulk-copy out
            __syncthreads();
            if (region == 1) {
#pragma unroll
                for (int nt = 0; nt < 4; nt++) {
                    int lch = wc * 2 + (nt >> 1);
                    int offbase = (((nt & 1) * 2 + (lr >> 3)) * 16) * 8 + (lr & 7);
#pragma unroll
                    for (int mt = 0; mt < 4; mt++) {
                        u16* cp2 = lAB + (((wr * 4 + mt) * 4 + lch) * 512);
#pragma unroll
                        for (int r = 0; r < 4; r++)
                            cp2[offbase + (lq * 4 + r) * 8] = f2bf(acc[mt][nt][r]);
                    }
                }
            } else {
#pragma unroll
                for (int nt = 0; nt < 4; nt++) {
#pragma unroll
                    for (int mt = 0; mt < 4; mt++) {
                        u16* cp2 = lAB + (((wr * 2 + (mt >> 1)) * 8 + wc * 4 + nt) * 512);
                        int ob = (((mt & 1) * 2 + (lq >> 1)) * 16 + lr) * 8 + (lq & 1) * 4;
#pragma unroll
                        for (int r = 0; r < 4; r++)
                            cp2[ob + r] = f2bf(acc[mt][nt][r]);
                    }
                }
            }
            __syncthreads();
            const int b = m0 >> 10;
            const int ml = m0 & 1023;
#pragma unroll
            for (int i = 0; i < 8; i++) {
                int ci = wv * 8 + i;
                short8 val = *(const short8*)(lAB + ci * 512 + lane * 8);
                if (region == 1) {
                    int a = ci >> 2, bb = ci & 3;
                    int cg = n0r + bb * 32;
                    int h = cg / 192;
                    int dh32 = (cg - h * 192) >> 5;
                    size_t gaddr = (size_t)(b * 4 + h) * 196608 +
                                   (size_t)((((ml >> 4) + a) * 6 + dh32)) * 512 + lane * 8;
                    *(short8*)(ko + gaddr) = val;
                } else {
                    int a = ci >> 3, bb = ci & 7;
                    int cg = n0r + bb * 16;
                    int h = cg / 192;
                    int dh16 = (cg - h * 192) >> 4;
                    size_t gaddr = (size_t)(b * 4 + h) * 196608 +
                                   (size_t)((((ml >> 5) + a) * 12 + dh16)) * 512 + lane * 8;
                    *(short8*)(vo + gaddr) = val;
                }
            }
        }
    } else {
#pragma unroll
        for (int nt = 0; nt < 4; nt++) {
            int col = n0 + wc * 64 + nt * 16 + lr;
            float bv = bias[col];
#pragma unroll
            for (int mt = 0; mt < 4; mt++) {
#pragma unroll
                for (int r = 0; r < 4; r++) {
                    int row = m0 + wr * 64 + mt * 16 + lq * 4 + r;
                    Co[(size_t)row * N + col] = acc[mt][nt][r] + bv;
                }
            }
        }
    }
}

// ---------------- column sum-of-squares over sequence (q row-major, k swiz) ----------------
__global__ void k_sq(const u16* __restrict__ q, const u16* __restrict__ k,
                     float* __restrict__ sqq, float* __restrict__ sqk) {
    int bh = blockIdx.x;
    int part = blockIdx.y;
    int dh = threadIdx.x;  // 192
    const u16* qp = q + ((size_t)bh * 1024 + part * 128) * 192 + dh;
    float aq = 0.f;
#pragma unroll 4
    for (int n = 0; n < 128; n++) {
        float a = bf2f(qp[(size_t)n * 192]);
        aq += a * a;
    }
    const u16* kbase = k + (size_t)bh * 196608 + (dh >> 5) * 512 + ((dh >> 3) & 3) * 128 + (dh & 7);
    float ak = 0.f;
#pragma unroll 4
    for (int n = 0; n < 128; n++) {
        int nn = part * 128 + n;
        float c2 = bf2f(kbase[(nn >> 4) * 3072 + (nn & 15) * 8]);
        ak += c2 * c2;
    }
    atomicAdd(&sqq[bh * 192 + dh], aq);
    atomicAdd(&sqk[bh * 192 + dh], ak);
}

__global__ void k_scale(const float* __restrict__ sqq, const float* __restrict__ sqk,
                        const float* __restrict__ temp, float* __restrict__ cs) {
    int bh = blockIdx.x;
    int dh = threadIdx.x;
    float rq = 1.f / fmaxf(sqrtf(sqq[bh * 192 + dh]), 1e-12f);
    float rk = 1.f / fmaxf(sqrtf(sqk[bh * 192 + dh]), 1e-12f);
    cs[bh * 192 + dh] = rq * rk * temp[bh & 3];
}

// ---------------- flash attention: one WG per (bh, 64-row q block) ----------------
__global__ __launch_bounds__(256) void k_attn(const u16* __restrict__ q,
                                              const u16* __restrict__ kmat,
                                              const u16* __restrict__ vT,
                                              const float* __restrict__ cs,
                                              u16* __restrict__ o) {
    __shared__ __align__(16) u16 lK[24 * 512];
    __shared__ __align__(16) u16 lV[24 * 512];
    __shared__ __align__(16) u16 lP[4 * 1024];
    const int lin = blockIdx.x;
    const int qb = (lin >> 3) & 15;
    const int bh = (lin & 7) * 4 + (lin >> 7);
    const int b = bh >> 2, h = bh & 3;
    const int tid = threadIdx.x;
    const int lane = tid & 63;
    const int wv = tid >> 6;
    const int lr = lane & 15;
    const int lq = lane >> 4;
    const int koff = lq * 8;

    const u16* qbase = q + (size_t)bh * 1024 * 192;
    const u16* kbase = kmat + (size_t)bh * 196608;
    const u16* vbase = vT + (size_t)bh * 196608;
    const float* cp = cs + bh * 192;

    const int qrow = qb * 64 + wv * 16 + lr;
    const u16* qp = qbase + (size_t)qrow * 192;
    short8 qf[6];
#pragma unroll
    for (int ks = 0; ks < 6; ks++) {
        short8 raw = *(const short8*)(qp + ks * 32 + koff);
        short8 sc;
#pragma unroll
        for (int j = 0; j < 8; j++) {
            float f = bf2f((u16)raw[j]) * cp[ks * 32 + koff + j];
            sc[j] = (short)f2bf(f);
        }
        qf[ks] = sc;
    }

    float m_r[4], l_r[4];
    floatx4 oacc[12];
#pragma unroll
    for (int r = 0; r < 4; r++) { m_r[r] = -1e30f; l_r[r] = 0.f; }
#pragma unroll
    for (int vt = 0; vt < 12; vt++) oacc[vt] = (floatx4){0.f, 0.f, 0.f, 0.f};

    u16* lp = lP + wv * 1024;

    for (int kb = 0; kb < 16; kb++) {
        __syncthreads();
#pragma unroll
        for (int i = 0; i < 6; i++) {
            int ch = i * 4 + wv;  // 0..23
            int ks = ch >> 2, nt = ch & 3;
            const u16* gk = kbase + ((size_t)(kb * 4 + nt) * 6 + ks) * 512 + lane * 8;
            gl_lds16(gk, (char*)lK + ch * 1024);
            int ks2 = ch / 12, vt2 = ch - ks2 * 12;
            const u16* gv = vbase + ((size_t)(kb * 2 + ks2) * 12 + vt2) * 512 + lane * 8;
            gl_lds16(gv, (char*)lV + ch * 1024);
        }
        __syncthreads();

        floatx4 s[4];
#pragma unroll
        for (int nt = 0; nt < 4; nt++) s[nt] = (floatx4){0.f, 0.f, 0.f, 0.f};
#pragma unroll
        for (int ks = 0; ks < 6; ks++) {
#pragma unroll
            for (int nt = 0; nt < 4; nt++) {
                short8 kf = *(const short8*)(lK + ((ks * 4 + nt) * 64 + lane) * 8);
                s[nt] = __builtin_amdgcn_mfma_f32_16x16x32_bf16(qf[ks], kf, s[nt], 0, 0, 0);
            }
        }

        float rmax[4];
#pragma unroll
        for (int r = 0; r < 4; r++)
            rmax[r] = fmaxf(fmaxf(s[0][r], s[1][r]), fmaxf(s[2][r], s[3][r]));
#pragma unroll
        for (int m = 1; m < 16; m <<= 1)
#pragma unroll
            for (int r = 0; r < 4; r++) rmax[r] = fmaxf(rmax[r], __shfl_xor(rmax[r], m));
        float alpha[4];
#pragma unroll
        for (int r = 0; r < 4; r++) {
            float mn = fmaxf(m_r[r], rmax[r]);
            alpha[r] = __expf(m_r[r] - mn);
            m_r[r] = mn;
        }
        float rsum[4] = {0.f, 0.f, 0.f, 0.f};
#pragma unroll
        for (int nt = 0; nt < 4; nt++)
#pragma unroll
            for (int r = 0; r < 4; r++) {
                float p = __expf(s[nt][r] - m_r[r]);
                s[nt][r] = p;
                rsum[r] += p;
            }
#pragma unroll
        for (int m = 1; m < 16; m <<= 1)
#pragma unroll
            for (int r = 0; r < 4; r++) rsum[r] += __shfl_xor(rsum[r], m);
#pragma unroll
        for (int r = 0; r < 4; r++) l_r[r] = l_r[r] * alpha[r] + rsum[r];
#pragma unroll
        for (int vt = 0; vt < 12; vt++)
#pragma unroll
            for (int r = 0; r < 4; r++) oacc[vt][r] *= alpha[r];

        // P -> per-wave LDS in A-fragment order
#pragma unroll
        for (int nt = 0; nt < 4; nt++) {
            int base2 = (nt >> 1) * 512 + ((nt & 1) * 2 + (lr >> 3)) * 128 + (lr & 7);
#pragma unroll
            for (int r = 0; r < 4; r++)
                lp[base2 + (lq * 4 + r) * 8] = f2bf(s[nt][r]);
        }

#pragma unroll
        for (int ks2 = 0; ks2 < 2; ks2++) {
            short8 pf = *(const short8*)(lp + ks2 * 512 + lane * 8);
#pragma unroll
            for (int vt = 0; vt < 12; vt++) {
                short8 vf = *(const short8*)(lV + ((ks2 * 12 + vt) * 64 + lane) * 8);
                oacc[vt] = __builtin_amdgcn_mfma_f32_16x16x32_bf16(pf, vf, oacc[vt], 0, 0, 0);
            }
        }
    }

    // epilogue: divide by l, write o in swiz (A-operand) layout for proj gemm
    float inv[4];
#pragma unroll
    for (int r = 0; r < 4; r++) inv[r] = 1.f / l_r[r];
#pragma unroll
    for (int vt = 0; vt < 12; vt++) {
        int col = h * 192 + vt * 16 + lr;
#pragma unroll
        for (int r = 0; r < 4; r++) {
            int rowg = b * 1024 + qb * 64 + wv * 16 + lq * 4 + r;
            size_t addr = (size_t)(rowg >> 4) * 12288 + (col >> 5) * 512 +
                          ((col >> 3) & 3) * 128 + (rowg & 15) * 8 + (col & 7);
            o[addr] = f2bf(oacc[vt][r] * inv[r]);
        }
    }
}

// ---------------- LN stats per row ----------------
__global__ __launch_bounds__(256) void k_lnstats(const float* __restrict__ o2,
                                                 float* __restrict__ mu,
                                                 float* __restrict__ rstd) {
    int row = blockIdx.x;
    int tid = threadIdx.x;
    const float* p = o2 + (size_t)row * 768;
    float s = 0.f, ss = 0.f;
    for (int i = tid; i < 768; i += 256) {
        float v = p[i];
        s += v;
        ss += v * v;
    }
#pragma unroll
    for (int m = 32; m >= 1; m >>= 1) {
        s += __shfl_xor(s, m);
        ss += __shfl_xor(ss, m);
    }
    __shared__ float as[4], ass[4];
    if ((tid & 63) == 0) {
        as[tid >> 6] = s;
        ass[tid >> 6] = ss;
    }
    __syncthreads();
    if (tid == 0) {
        float S = as[0] + as[1] + as[2] + as[3];
        float SS = ass[0] + ass[1] + ass[2] + ass[3];
        float m_ = S * (1.f / 768.f);
        float v = SS * (1.f / 768.f) - m_ * m_;
        v = fmaxf(v, 0.f);
        mu[row] = m_;
        rstd[row] = rsqrtf(v + 1e-5f);
    }
}

// ---------------- LN apply + transpose back + residual: y = LN(o2)^T + x ----------------
__global__ __launch_bounds__(256) void k_lnt(const float* __restrict__ o2,
                                             const float* __restrict__ mu,
                                             const float* __restrict__ rstd,
                                             const float* __restrict__ gamma,
                                             const float* __restrict__ beta,
                                             const float* __restrict__ x,
                                             float* __restrict__ y) {
    __shared__ float tile[64][65];
    const int b = blockIdx.z, hw0 = blockIdx.y * 64, cd0 = blockIdx.x * 64;
    const int tid = threadIdx.x;
#pragma unroll
    for (int i = 0; i < 16; i++) {
        int f = i * 256 + tid;
        int hwl = f >> 6, cdl = f & 63;
        int row = b * 1024 + hw0 + hwl;
        float v = o2[(size_t)row * 768 + cd0 + cdl];
        v = (v - mu[row]) * rstd[row] * gamma[cd0 + cdl] + beta[cd0 + cdl];
        tile[hwl][cdl] = v;
    }
    __syncthreads();
#pragma unroll
    for (int i = 0; i < 16; i++) {
        int f = i * 256 + tid;
        int cdl = f >> 6, hwl = f & 63;
        int cd = cd0 + cdl, c = cd >> 3, d = cd & 7;
        size_t addr = (size_t)((b * 96 + c) * 8 + d) * 1024 + hw0 + hwl;
        y[addr] = tile[hwl][cdl] + x[addr];
    }
}

// ---------------- depthwise 3x3x3 conv: LDS-staged channel + rolling d-window ----------------
__global__ __launch_bounds__(256) void k_dw(const float* __restrict__ y,
                                            const float* __restrict__ w,
                                            const float* __restrict__ bias,
                                            float* __restrict__ z) {
    __shared__ float ly[8192];  // [d][h][w]
    const int bc = blockIdx.x;
    const int c = bc % 96;
    const int tid = threadIdx.x;
    const size_t base = (size_t)bc * 8192;

#pragma unroll
    for (int i = 0; i < 8; i++) {
        int i4 = i * 256 + tid;
        *(float4*)(ly + i4 * 4) = *(const float4*)(y + base + i4 * 4);
    }
    float wt[27];
#pragma unroll
    for (int j = 0; j < 27; j++) wt[j] = w[c * 27 + j];
    const float bv = bias[c];
    __syncthreads();

    const int wcol = tid & 31;
    const int hh = tid >> 5;  // 0..7

    for (int hb = 0; hb < 4; hb++) {
        const int h = hb * 8 + hh;
        float pl[3][9];
        auto loadplane = [&](int dd, float* p) {
#pragma unroll
            for (int kh = 0; kh < 3; kh++) {
                int h2 = h + kh - 1;
                bool hok = (unsigned)h2 < 32u;
                const float* row = ly + dd * 1024 + h2 * 32;
#pragma unroll
                for (int kw = 0; kw < 3; kw++) {
                    int w2 = wcol + kw - 1;
                    bool ok = hok && (unsigned)w2 < 32u;
                    p[kh * 3 + kw] = ok ? row[w2] : 0.f;
                }
            }
        };
#pragma unroll
        for (int j = 0; j < 9; j++) pl[0][j] = 0.f;  // d=-1 plane
        loadplane(0, pl[1]);
#pragma unroll
        for (int d = 0; d < 8; d++) {
            if (d < 7) loadplane(d + 1, pl[2]);
            else {
#pragma unroll
                for (int j = 0; j < 9; j++) pl[2][j] = 0.f;
            }
            float acc = bv;
#pragma unroll
            for (int kd = 0; kd < 3; kd++)
#pragma unroll
                for (int j = 0; j < 9; j++) acc += wt[kd * 9 + j] * pl[kd][j];
            z[base + d * 1024 + h * 32 + wcol] = acc;
#pragma unroll
            for (int j = 0; j < 9; j++) { pl[0][j] = pl[1][j]; pl[1][j] = pl[2][j]; }
        }
    }
}

// ---------------- pointwise conv via MFMA: out = y + pw_b + W(96x96) * Z(96 x pos) ----------------
__global__ __launch_bounds__(256) void k_pw(const float* __restrict__ z,
                                            const u16* __restrict__ wbf,   // bf16 96x96 row-major
                                            const float* __restrict__ bias,
                                            float* __restrict__ out) {
    __shared__ __align__(16) u16 lZ[128 * 104];
    __shared__ __align__(16) u16 lW[96 * 104];
    const int tid = threadIdx.x;
    const int lane = tid & 63;
    const int wv = tid >> 6;
    const int lr = lane & 15;
    const int lq = lane >> 4;
    const int koff = lq * 8;

    const int idx = blockIdx.x;
    const int q = idx & 7;
    const int bd = idx >> 3;
    const int b = bd >> 3, d = bd & 7;
    const int pos0 = q * 128;

    for (int i = tid; i < 96 * 96; i += 256) {
        int row = i / 96, col = i - row * 96;
        lW[row * 104 + col] = wbf[i];
    }
    {
        const int pos = tid & 127;
        const int cc0 = (tid >> 7) * 48;
        const size_t gbase = ((size_t)b * 96 * 8 + d) * 1024 + pos0 + pos;
#pragma unroll
        for (int g = 0; g < 6; g++) {
            short8 v;
#pragma unroll
            for (int j = 0; j < 8; j++) {
                int cc = cc0 + g * 8 + j;
                v[j] = (short)f2bf(z[gbase + (size_t)cc * 8192]);
            }
            *(short8*)(lZ + pos * 104 + cc0 + g * 8) = v;
        }
    }
    __syncthreads();

    floatx4 acc[6][2];
#pragma unroll
    for (int m = 0; m < 6; m++)
#pragma unroll
        for (int nt = 0; nt < 2; nt++) acc[m][nt] = (floatx4){0.f, 0.f, 0.f, 0.f};

#pragma unroll
    for (int ks = 0; ks < 3; ks++) {
        short8 bfrg[2];
#pragma unroll
        for (int nt = 0; nt < 2; nt++)
            bfrg[nt] = *(const short8*)(lZ + (wv * 32 + nt * 16 + lr) * 104 + ks * 32 + koff);
#pragma unroll
        for (int m = 0; m < 6; m++) {
            short8 afr = *(const short8*)(lW + (m * 16 + lr) * 104 + ks * 32 + koff);
#pragma unroll
            for (int nt = 0; nt < 2; nt++)
                acc[m][nt] = __builtin_amdgcn_mfma_f32_16x16x32_bf16(afr, bfrg[nt], acc[m][nt], 0, 0, 0);
        }
    }

#pragma unroll
    for (int m = 0; m < 6; m++) {
#pragma unroll
        for (int r = 0; r < 4; r++) {
            int c = m * 16 + lq * 4 + r;
            float bv = bias[c];
            size_t rowbase = ((size_t)(b * 96 + c) * 8 + d) * 1024 + pos0;
#pragma unroll
            for (int nt = 0; nt < 2; nt++) {
                int pos = wv * 32 + nt * 16 + lr;
                size_t a = rowbase + pos;
                out[a] = out[a] + bv + acc[m][nt][r];
            }
        }
    }
}

extern "C" void kernel_launch(void* const* d_in, const int* in_sizes, int n_in,
                              void* d_out, int out_size, void* d_ws, size_t ws_size,
                              hipStream_t stream) {
    (void)in_sizes; (void)n_in; (void)out_size; (void)ws_size;
    const float* x      = (const float*)d_in[0];
    const float* pos    = (const float*)d_in[1];
    const float* qkv_w  = (const float*)d_in[2];
    const float* proj_w = (const float*)d_in[3];
    const float* proj_b = (const float*)d_in[4];
    const float* temp   = (const float*)d_in[5];
    const float* ln_g   = (const float*)d_in[6];
    const float* ln_b   = (const float*)d_in[7];
    const float* dw_w   = (const float*)d_in[8];
    const float* dw_b   = (const float*)d_in[9];
    const float* pw_w   = (const float*)d_in[10];
    const float* pw_b   = (const float*)d_in[11];
    float* out = (float*)d_out;
    char* ws = (char*)d_ws;

    u16* t    = (u16*)(ws + 0);           // swiz A, 12.58MB ; later aliased by o (swiz) and z
    u16* vT   = (u16*)(ws + 12582912);    // v swiz, 12.58MB
    u16* q    = (u16*)(ws + 25165824);    // row-major, 12.58MB ; later o2 (with kk)
    u16* kk   = (u16*)(ws + 37748736);    // k swiz, 12.58MB
    u16* wqb  = (u16*)(ws + 50331648);    // qkv_w swiz + proj_w swiz + pw_w, ~4.74MB
    float* cs   = (float*)(ws + 55150592);
    float* sqq  = (float*)(ws + 55175168);
    float* sqk  = (float*)(ws + 55199744);
    float* mu   = (float*)(ws + 55224320);
    float* rstd = (float*)(ws + 55257088);
    u16* wpb  = wqb + 2304 * 768;
    u16* wpwb = wqb + 2304 * 768 + 768 * 768;
    u16* o   = t;
    float* o2 = (float*)q;
    float* z  = (float*)t;
    float* y  = out;

    k_tpos<<<dim3(12, 16, 8), 256, 0, stream>>>(x, pos, t);
    k_cvt<<<1188, 256, 0, stream>>>(qkv_w, proj_w, pw_w, wqb);
    gemm_bt<0><<<1152, 256, 0, stream>>>(t, wqb, 8192, 2304, 768, q, kk, vT, nullptr, nullptr);
    hipMemsetAsync(sqq, 0, 49152, stream);
    k_sq<<<dim3(32, 8), 192, 0, stream>>>(q, kk, sqq, sqk);
    k_scale<<<32, 192, 0, stream>>>(sqq, sqk, temp, cs);
    k_attn<<<512, 256, 0, stream>>>(q, kk, vT, cs, o);
    gemm_bt<1><<<384, 256, 0, stream>>>(o, wpb, 8192, 768, 768, nullptr, nullptr, nullptr, proj_b, o2);
    k_lnstats<<<8192, 256, 0, stream>>>(o2, mu, rstd);
    k_lnt<<<dim3(12, 16, 8), 256, 0, stream>>>(o2, mu, rstd, ln_g, ln_b, x, y);
    k_dw<<<768, 256, 0, stream>>>(y, dw_w, dw_b, z);
    k_pw<<<512, 256, 0, stream>>>(z, wpwb, pw_b, out);
}

// Round 8
// 288.809 us; speedup vs baseline: 1.4873x; 1.0222x over previous
//
#include <hip/hip_runtime.h>

typedef unsigned short u16;
typedef unsigned int u32;

typedef __attribute__((ext_vector_type(8))) short short8;
typedef __attribute__((ext_vector_type(4))) float floatx4;

__device__ __forceinline__ float bf2f(u16 u) { return __uint_as_float(((u32)u) << 16); }
__device__ __forceinline__ u16 f2bf(float f) {
    u32 x = __float_as_uint(f);
    x += 0x7fffu + ((x >> 16) & 1u);
    return (u16)(x >> 16);
}
__device__ __forceinline__ void gl_lds16(const void* g, void* l) {
    __builtin_amdgcn_global_load_lds((const __attribute__((address_space(1))) u32*)g,
                                     (__attribute__((address_space(3))) u32*)l, 16, 0, 0);
}

// Fragment-tiled ("swiz") layouts: data grouped in 1024B chunks of [16 rows x 32 k],
// element order = gl_lds16 lane order: u16 off = chunk*512 + (((k>>3)&3)*16 + (row&15))*8 + (k&7).
// A-operands (t, o): chunk = (row>>4)*24 + (k>>5)   [K=768 -> 24 kchunks]
// W-operands (qkv_w, proj_w): same with row=n.
// K-swiz (per bh, n x dh): chunk = (n>>4)*6 + (dh>>5)
// V-swiz (per bh): chunk = (n>>5)*12 + (dh>>4), lane = ((n>>3)&3)*16 + (dh&15), low3 = n&7

// ---------------- Kernel 1: x (B,C,D,H,W) -> t swiz bf16, + pos ----------------
__global__ __launch_bounds__(256) void k_tpos(const float* __restrict__ x,
                                              const float* __restrict__ pos,
                                              u16* __restrict__ t) {
    __shared__ float tile[64][65];
    const int b = blockIdx.z, hw0 = blockIdx.y * 64, cd0 = blockIdx.x * 64;
    const int tid = threadIdx.x;
#pragma unroll
    for (int i = 0; i < 16; i++) {
        int f = i * 256 + tid;
        int cdl = f >> 6, hwl = f & 63;
        int cd = cd0 + cdl, c = cd >> 3, d = cd & 7;
        tile[cdl][hwl] = x[(size_t)(((b * 96 + c) * 8 + d)) * 1024 + hw0 + hwl];
    }
    __syncthreads();
#pragma unroll
    for (int it = 0; it < 2; it++) {
        int u = it * 256 + tid;       // 512 units of 16B
        int ch = u >> 6, l = u & 63;
        int n16l = ch >> 1, kcl = ch & 1;
        int hwl = n16l * 16 + (l & 15);
        int cdl = kcl * 32 + (l >> 4) * 8;
        int row = b * 1024 + hw0 + hwl;
        int cd = cd0 + cdl;
        const float* pp = pos + (size_t)(hw0 + hwl) * 768 + cd;
        float4 p0 = *(const float4*)pp;
        float4 p1 = *(const float4*)(pp + 4);
        short8 v;
        v[0] = (short)f2bf(tile[cdl + 0][hwl] + p0.x);
        v[1] = (short)f2bf(tile[cdl + 1][hwl] + p0.y);
        v[2] = (short)f2bf(tile[cdl + 2][hwl] + p0.z);
        v[3] = (short)f2bf(tile[cdl + 3][hwl] + p0.w);
        v[4] = (short)f2bf(tile[cdl + 4][hwl] + p1.x);
        v[5] = (short)f2bf(tile[cdl + 5][hwl] + p1.y);
        v[6] = (short)f2bf(tile[cdl + 6][hwl] + p1.z);
        v[7] = (short)f2bf(tile[cdl + 7][hwl] + p1.w);
        size_t chunk = (size_t)(row >> 4) * 24 + (cd >> 5);
        *(short8*)(t + chunk * 512 + l * 8) = v;
    }
}

// ---------------- weight cvt: qkv_w swiz, proj_w swiz, pw_w row-major ----------------
__global__ __launch_bounds__(256) void k_cvt(const float* __restrict__ wq,
                                             const float* __restrict__ wp,
                                             const float* __restrict__ wpw,
                                             u16* __restrict__ out) {
    const int NQ = 144 * 24 * 64;          // qkv 16B-units
    const int NP = NQ + 48 * 24 * 64;      // + proj 16B-units
    int u = blockIdx.x * 256 + threadIdx.x;
    if (u < NP) {
        const float* w = (u < NQ) ? wq : wp;
        int ub = (u < NQ) ? u : u - NQ;
        int chunk = ub >> 6, l = ub & 63;
        int n16 = chunk / 24, kc = chunk - n16 * 24;
        int n = n16 * 16 + (l & 15);
        int k0 = kc * 32 + (l >> 4) * 8;
        const float* src = w + (size_t)n * 768 + k0;
        float4 a = *(const float4*)src;
        float4 b2 = *(const float4*)(src + 4);
        short8 v;
        v[0] = (short)f2bf(a.x);  v[1] = (short)f2bf(a.y);
        v[2] = (short)f2bf(a.z);  v[3] = (short)f2bf(a.w);
        v[4] = (short)f2bf(b2.x); v[5] = (short)f2bf(b2.y);
        v[6] = (short)f2bf(b2.z); v[7] = (short)f2bf(b2.w);
        *(short8*)(out + (size_t)u * 8) = v;
    } else {
        int i = u - NP;  // 9216 pw elements
        out[(size_t)NP * 8 + i] = f2bf(wpw[i]);
    }
}

// ---------------- GEMM: C(M,N) = A_swiz(M,K) * W_swiz(N,K)^T, bf16 MFMA ----------------
// BK=64, XCD-pinned swizzle. MODE 0 k/v epilogue staged through LDS -> 1024B coalesced stores.
template <int MODE>
__global__ __launch_bounds__(256) void gemm_bt(const u16* __restrict__ A,
                                               const u16* __restrict__ Bw,
                                               int M, int N, int K,
                                               u16* __restrict__ qo, u16* __restrict__ ko,
                                               u16* __restrict__ vo,
                                               const float* __restrict__ bias,
                                               float* __restrict__ Co) {
    __shared__ __align__(16) u16 lAB[32 * 512];  // 32KB: lA = [0..16), lB = [16..32) chunks
    u16* lA = lAB;
    u16* lB = lAB + 16 * 512;
    const int tid = threadIdx.x;
    const int lane = tid & 63;
    const int wv = tid >> 6;
    const int wr = wv >> 1, wc = wv & 1;
    const int ntiles = N >> 7;
    const int mtiles = M >> 7;                 // 64
    const int lin = blockIdx.x;
    const int xcd = lin & 7;
    const int idx = lin >> 3;
    const int mlocal = idx / ntiles;
    const int ntile = idx - mlocal * ntiles;
    const int m0 = (xcd * (mtiles >> 3) + mlocal) << 7;
    const int n0 = ntile << 7;
    const int lr = lane & 15;
    const int lq = lane >> 4;

    floatx4 acc[4][4];
#pragma unroll
    for (int i = 0; i < 4; i++)
#pragma unroll
        for (int j = 0; j < 4; j++) acc[i][j] = (floatx4){0.f, 0.f, 0.f, 0.f};

    const int m16 = m0 >> 4, n16 = n0 >> 4;
    for (int kc2 = 0; kc2 < (K >> 6); kc2++) {
        __syncthreads();
#pragma unroll
        for (int kh = 0; kh < 2; kh++) {
#pragma unroll
            for (int i = 0; i < 2; i++) {
                int ch16 = i * 4 + wv;       // 16-row block of the 128-row tile
                int kc = kc2 * 2 + kh;
                const u16* ga = A + ((size_t)(m16 + ch16) * 24 + kc) * 512 + lane * 8;
                gl_lds16(ga, (char*)lA + (kh * 8 + ch16) * 1024);
                const u16* gb = Bw + ((size_t)(n16 + ch16) * 24 + kc) * 512 + lane * 8;
                gl_lds16(gb, (char*)lB + (kh * 8 + ch16) * 1024);
            }
        }
        __syncthreads();
#pragma unroll
        for (int kh = 0; kh < 2; kh++) {
            short8 af[4], bfr[4];
#pragma unroll
            for (int tt = 0; tt < 4; tt++) {
                af[tt] = *(const short8*)(lA + ((kh * 8 + wr * 4 + tt) * 64 + lane) * 8);
                bfr[tt] = *(const short8*)(lB + ((kh * 8 + wc * 4 + tt) * 64 + lane) * 8);
            }
#pragma unroll
            for (int mt = 0; mt < 4; mt++)
#pragma unroll
                for (int nt = 0; nt < 4; nt++)
                    acc[mt][nt] = __builtin_amdgcn_mfma_f32_16x16x32_bf16(af[mt], bfr[nt], acc[mt][nt], 0, 0, 0);
        }
    }

    if (MODE == 0) {
        const int region = n0 / 768;       // whole block is q, k, or v
        const int n0r = n0 - region * 768;
        if (region == 0) {
            // q: direct row-major stores (32B segments)
#pragma unroll
            for (int nt = 0; nt < 4; nt++) {
                int colb = n0r + wc * 64 + nt * 16;
                int h = colb / 192;
                int dh = colb - h * 192 + lr;
#pragma unroll
                for (int mt = 0; mt < 4; mt++) {
#pragma unroll
                    for (int r = 0; r < 4; r++) {
                        int row = m0 + wr * 64 + mt * 16 + lq * 4 + r;
                        int b = row >> 10, n = row & 1023;
                        qo[((size_t)(b * 4 + h) * 1024 + n) * 192 + dh] = f2bf(acc[mt][nt][r]);
                    }
                }
            }
        } else {
            // k/v: stage the 128x128 bf16 tile in LDS at swiz-exact offsets, bulk-copy out
            __syncthreads();
            if (region == 1) {
#pragma unroll
                for (int nt = 0; nt < 4; nt++) {
                    int lch = wc * 2 + (nt >> 1);
                    int offbase = (((nt & 1) * 2 + (lr >> 3)) * 16) * 8 + (lr & 7);
#pragma unroll
                    for (int mt = 0; mt < 4; mt++) {
                        u16* cp2 = lAB + (((wr * 4 + mt) * 4 + lch) * 512);
#pragma unroll
                        for (int r = 0; r < 4; r++)
                            cp2[offbase + (lq * 4 + r) * 8] = f2bf(acc[mt][nt][r]);
                    }
                }
            } else {
#pragma unroll
                for (int nt = 0; nt < 4; nt++) {
#pragma unroll
                    for (int mt = 0; mt < 4; mt++) {
                        u16* cp2 = lAB + (((wr * 2 + (mt >> 1)) * 8 + wc * 4 + nt) * 512);
                        int ob = (((mt & 1) * 2 + (lq >> 1)) * 16 + lr) * 8 + (lq & 1) * 4;
#pragma unroll
                        for (int r = 0; r < 4; r++)
                            cp2[ob + r] = f2bf(acc[mt][nt][r]);
                    }
                }
            }
            __syncthreads();
            const int b = m0 >> 10;
            const int ml = m0 & 1023;
#pragma unroll
            for (int i = 0; i < 8; i++) {
                int ci = wv * 8 + i;
                short8 val = *(const short8*)(lAB + ci * 512 + lane * 8);
                if (region == 1) {
                    int a = ci >> 2, bb = ci & 3;
                    int cg = n0r + bb * 32;
                    int h = cg / 192;
                    int dh32 = (cg - h * 192) >> 5;
                    size_t gaddr = (size_t)(b * 4 + h) * 196608 +
                                   (size_t)((((ml >> 4) + a) * 6 + dh32)) * 512 + lane * 8;
                    *(short8*)(ko + gaddr) = val;
                } else {
                    int a = ci >> 3, bb = ci & 7;
                    int cg = n0r + bb * 16;
                    int h = cg / 192;
                    int dh16 = (cg - h * 192) >> 4;
                    size_t gaddr = (size_t)(b * 4 + h) * 196608 +
                                   (size_t)((((ml >> 5) + a) * 12 + dh16)) * 512 + lane * 8;
                    *(short8*)(vo + gaddr) = val;
                }
            }
        }
    } else {
#pragma unroll
        for (int nt = 0; nt < 4; nt++) {
            int col = n0 + wc * 64 + nt * 16 + lr;
            float bv = bias[col];
#pragma unroll
            for (int mt = 0; mt < 4; mt++) {
#pragma unroll
                for (int r = 0; r < 4; r++) {
                    int row = m0 + wr * 64 + mt * 16 + lq * 4 + r;
                    Co[(size_t)row * N + col] = acc[mt][nt][r] + bv;
                }
            }
        }
    }
}

// ---------------- column sum-of-squares over sequence (q row-major, k swiz) ----------------
__global__ void k_sq(const u16* __restrict__ q, const u16* __restrict__ k,
                     float* __restrict__ sqq, float* __restrict__ sqk) {
    int bh = blockIdx.x;
    int part = blockIdx.y;
    int dh = threadIdx.x;  // 192
    const u16* qp = q + ((size_t)bh * 1024 + part * 128) * 192 + dh;
    float aq = 0.f;
#pragma unroll 4
    for (int n = 0; n < 128; n++) {
        float a = bf2f(qp[(size_t)n * 192]);
        aq += a * a;
    }
    const u16* kbase = k + (size_t)bh * 196608 + (dh >> 5) * 512 + ((dh >> 3) & 3) * 128 + (dh & 7);
    float ak = 0.f;
#pragma unroll 4
    for (int n = 0; n < 128; n++) {
        int nn = part * 128 + n;
        float c2 = bf2f(kbase[(nn >> 4) * 3072 + (nn & 15) * 8]);
        ak += c2 * c2;
    }
    atomicAdd(&sqq[bh * 192 + dh], aq);
    atomicAdd(&sqk[bh * 192 + dh], ak);
}

__global__ void k_scale(const float* __restrict__ sqq, const float* __restrict__ sqk,
                        const float* __restrict__ temp, float* __restrict__ cs) {
    int bh = blockIdx.x;
    int dh = threadIdx.x;
    float rq = 1.f / fmaxf(sqrtf(sqq[bh * 192 + dh]), 1e-12f);
    float rk = 1.f / fmaxf(sqrtf(sqk[bh * 192 + dh]), 1e-12f);
    cs[bh * 192 + dh] = rq * rk * temp[bh & 3];
}

// ---------------- flash attention: 2-wave blocks, 32 q-rows/wave (2 tiles), no-max softmax ----
// Softmax shift-invariance: with L2-normalized q,k and temp, |s|<<1, so exp(s) without
// max-subtraction is exact-in-math and safe-in-range; kills rmax shuffles + oacc rescale.
// Each kf/vf ds_read feeds 2 MFMAs (2 q-tiles) -> LDS read per covered element halved.
__global__ __launch_bounds__(128) void k_attn(const u16* __restrict__ q,
                                              const u16* __restrict__ kmat,
                                              const u16* __restrict__ vT,
                                              const float* __restrict__ cs,
                                              u16* __restrict__ o) {
    __shared__ __align__(16) u16 lK[24 * 512];
    __shared__ __align__(16) u16 lV[24 * 512];
    __shared__ __align__(16) u16 lP[2 * 2048];  // per-wave 2 P-tiles
    const int lin = blockIdx.x;
    const int qb = (lin >> 3) & 15;
    const int bh = (lin & 7) * 4 + (lin >> 7);
    const int b = bh >> 2, h = bh & 3;
    const int tid = threadIdx.x;
    const int lane = tid & 63;
    const int wv = tid >> 6;   // 0..1
    const int lr = lane & 15;
    const int lq = lane >> 4;
    const int koff = lq * 8;

    const u16* qbase = q + (size_t)bh * 1024 * 192;
    const u16* kbase = kmat + (size_t)bh * 196608;
    const u16* vbase = vT + (size_t)bh * 196608;
    const float* cp = cs + bh * 192;

    // Q fragments for the wave's 2 row-tiles, pre-scaled
    short8 qf[2][6];
#pragma unroll
    for (int t = 0; t < 2; t++) {
        const int qrow = qb * 64 + wv * 32 + t * 16 + lr;
        const u16* qp = qbase + (size_t)qrow * 192;
#pragma unroll
        for (int ks = 0; ks < 6; ks++) {
            short8 raw = *(const short8*)(qp + ks * 32 + koff);
            short8 sc;
#pragma unroll
            for (int j = 0; j < 8; j++) {
                float f = bf2f((u16)raw[j]) * cp[ks * 32 + koff + j];
                sc[j] = (short)f2bf(f);
            }
            qf[t][ks] = sc;
        }
    }

    float l_r[2][4];
    floatx4 oacc[2][12];
#pragma unroll
    for (int t = 0; t < 2; t++) {
#pragma unroll
        for (int r = 0; r < 4; r++) l_r[t][r] = 0.f;
#pragma unroll
        for (int vt = 0; vt < 12; vt++) oacc[t][vt] = (floatx4){0.f, 0.f, 0.f, 0.f};
    }

    u16* lp = lP + wv * 2048;

    for (int kb = 0; kb < 16; kb++) {
        __syncthreads();
        // stage 24 K chunks + 24 V chunks with 2 waves
#pragma unroll
        for (int i = 0; i < 12; i++) {
            int ch = i * 2 + wv;  // 0..23
            int ks = ch >> 2, nt = ch & 3;
            const u16* gk = kbase + ((size_t)(kb * 4 + nt) * 6 + ks) * 512 + lane * 8;
            gl_lds16(gk, (char*)lK + ch * 1024);
            int ks2 = ch / 12, vt2 = ch - ks2 * 12;
            const u16* gv = vbase + ((size_t)(kb * 2 + ks2) * 12 + vt2) * 512 + lane * 8;
            gl_lds16(gv, (char*)lV + ch * 1024);
        }
        __syncthreads();

        // S = Qs * K^T for both row-tiles; each kf read feeds 2 MFMAs
        floatx4 s0[4], s1[4];
#pragma unroll
        for (int nt = 0; nt < 4; nt++) {
            s0[nt] = (floatx4){0.f, 0.f, 0.f, 0.f};
            s1[nt] = (floatx4){0.f, 0.f, 0.f, 0.f};
        }
#pragma unroll
        for (int ks = 0; ks < 6; ks++) {
#pragma unroll
            for (int nt = 0; nt < 4; nt++) {
                short8 kf = *(const short8*)(lK + ((ks * 4 + nt) * 64 + lane) * 8);
                s0[nt] = __builtin_amdgcn_mfma_f32_16x16x32_bf16(qf[0][ks], kf, s0[nt], 0, 0, 0);
                s1[nt] = __builtin_amdgcn_mfma_f32_16x16x32_bf16(qf[1][ks], kf, s1[nt], 0, 0, 0);
            }
        }

        // exp (no max shift) + row-sum + P write (A-frag order), both tiles
        float rs0[4] = {0.f, 0.f, 0.f, 0.f}, rs1[4] = {0.f, 0.f, 0.f, 0.f};
#pragma unroll
        for (int nt = 0; nt < 4; nt++)
#pragma unroll
            for (int r = 0; r < 4; r++) {
                float p0 = __expf(s0[nt][r]);
                s0[nt][r] = p0;
                rs0[r] += p0;
                float p1 = __expf(s1[nt][r]);
                s1[nt][r] = p1;
                rs1[r] += p1;
            }
#pragma unroll
        for (int m = 1; m < 16; m <<= 1)
#pragma unroll
            for (int r = 0; r < 4; r++) {
                rs0[r] += __shfl_xor(rs0[r], m);
                rs1[r] += __shfl_xor(rs1[r], m);
            }
#pragma unroll
        for (int r = 0; r < 4; r++) {
            l_r[0][r] += rs0[r];
            l_r[1][r] += rs1[r];
        }
#pragma unroll
        for (int nt = 0; nt < 4; nt++) {
            int base2 = (nt >> 1) * 512 + ((nt & 1) * 2 + (lr >> 3)) * 128 + (lr & 7);
#pragma unroll
            for (int r = 0; r < 4; r++) {
                lp[base2 + (lq * 4 + r) * 8] = f2bf(s0[nt][r]);
                lp[1024 + base2 + (lq * 4 + r) * 8] = f2bf(s1[nt][r]);
            }
        }

        // O += P * V; each vf read feeds 2 MFMAs
#pragma unroll
        for (int ks2 = 0; ks2 < 2; ks2++) {
            short8 pf0 = *(const short8*)(lp + ks2 * 512 + lane * 8);
            short8 pf1 = *(const short8*)(lp + 1024 + ks2 * 512 + lane * 8);
#pragma unroll
            for (int vt = 0; vt < 12; vt++) {
                short8 vf = *(const short8*)(lV + ((ks2 * 12 + vt) * 64 + lane) * 8);
                oacc[0][vt] = __builtin_amdgcn_mfma_f32_16x16x32_bf16(pf0, vf, oacc[0][vt], 0, 0, 0);
                oacc[1][vt] = __builtin_amdgcn_mfma_f32_16x16x32_bf16(pf1, vf, oacc[1][vt], 0, 0, 0);
            }
        }
    }

    // epilogue: divide by l, write o in swiz (A-operand) layout for proj gemm
#pragma unroll
    for (int t = 0; t < 2; t++) {
        float inv[4];
#pragma unroll
        for (int r = 0; r < 4; r++) inv[r] = 1.f / l_r[t][r];
#pragma unroll
        for (int vt = 0; vt < 12; vt++) {
            int col = h * 192 + vt * 16 + lr;
#pragma unroll
            for (int r = 0; r < 4; r++) {
                int rowg = b * 1024 + qb * 64 + wv * 32 + t * 16 + lq * 4 + r;
                size_t addr = (size_t)(rowg >> 4) * 12288 + (col >> 5) * 512 +
                              ((col >> 3) & 3) * 128 + (rowg & 15) * 8 + (col & 7);
                o[addr] = f2bf(oacc[t][vt][r] * inv[r]);
            }
        }
    }
}

// ---------------- LN stats per row ----------------
__global__ __launch_bounds__(256) void k_lnstats(const float* __restrict__ o2,
                                                 float* __restrict__ mu,
                                                 float* __restrict__ rstd) {
    int row = blockIdx.x;
    int tid = threadIdx.x;
    const float* p = o2 + (size_t)row * 768;
    float s = 0.f, ss = 0.f;
    for (int i = tid; i < 768; i += 256) {
        float v = p[i];
        s += v;
        ss += v * v;
    }
#pragma unroll
    for (int m = 32; m >= 1; m >>= 1) {
        s += __shfl_xor(s, m);
        ss += __shfl_xor(ss, m);
    }
    __shared__ float as[4], ass[4];
    if ((tid & 63) == 0) {
        as[tid >> 6] = s;
        ass[tid >> 6] = ss;
    }
    __syncthreads();
    if (tid == 0) {
        float S = as[0] + as[1] + as[2] + as[3];
        float SS = ass[0] + ass[1] + ass[2] + ass[3];
        float m_ = S * (1.f / 768.f);
        float v = SS * (1.f / 768.f) - m_ * m_;
        v = fmaxf(v, 0.f);
        mu[row] = m_;
        rstd[row] = rsqrtf(v + 1e-5f);
    }
}

// ---------------- LN apply + transpose back + residual: y = LN(o2)^T + x ----------------
__global__ __launch_bounds__(256) void k_lnt(const float* __restrict__ o2,
                                             const float* __restrict__ mu,
                                             const float* __restrict__ rstd,
                                             const float* __restrict__ gamma,
                                             const float* __restrict__ beta,
                                             const float* __restrict__ x,
                                             float* __restrict__ y) {
    __shared__ float tile[64][65];
    const int b = blockIdx.z, hw0 = blockIdx.y * 64, cd0 = blockIdx.x * 64;
    const int tid = threadIdx.x;
#pragma unroll
    for (int i = 0; i < 16; i++) {
        int f = i * 256 + tid;
        int hwl = f >> 6, cdl = f & 63;
        int row = b * 1024 + hw0 + hwl;
        float v = o2[(size_t)row * 768 + cd0 + cdl];
        v = (v - mu[row]) * rstd[row] * gamma[cd0 + cdl] + beta[cd0 + cdl];
        tile[hwl][cdl] = v;
    }
    __syncthreads();
#pragma unroll
    for (int i = 0; i < 16; i++) {
        int f = i * 256 + tid;
        int cdl = f >> 6, hwl = f & 63;
        int cd = cd0 + cdl, c = cd >> 3, d = cd & 7;
        size_t addr = (size_t)((b * 96 + c) * 8 + d) * 1024 + hw0 + hwl;
        y[addr] = tile[hwl][cdl] + x[addr];
    }
}

// ---------------- depthwise 3x3x3 conv: LDS-staged channel + rolling d-window ----------------
__global__ __launch_bounds__(256) void k_dw(const float* __restrict__ y,
                                            const float* __restrict__ w,
                                            const float* __restrict__ bias,
                                            float* __restrict__ z) {
    __shared__ float ly[8192];  // [d][h][w]
    const int bc = blockIdx.x;
    const int c = bc % 96;
    const int tid = threadIdx.x;
    const size_t base = (size_t)bc * 8192;

#pragma unroll
    for (int i = 0; i < 8; i++) {
        int i4 = i * 256 + tid;
        *(float4*)(ly + i4 * 4) = *(const float4*)(y + base + i4 * 4);
    }
    float wt[27];
#pragma unroll
    for (int j = 0; j < 27; j++) wt[j] = w[c * 27 + j];
    const float bv = bias[c];
    __syncthreads();

    const int wcol = tid & 31;
    const int hh = tid >> 5;  // 0..7

    for (int hb = 0; hb < 4; hb++) {
        const int h = hb * 8 + hh;
        float pl[3][9];
        auto loadplane = [&](int dd, float* p) {
#pragma unroll
            for (int kh = 0; kh < 3; kh++) {
                int h2 = h + kh - 1;
                bool hok = (unsigned)h2 < 32u;
                const float* row = ly + dd * 1024 + h2 * 32;
#pragma unroll
                for (int kw = 0; kw < 3; kw++) {
                    int w2 = wcol + kw - 1;
                    bool ok = hok && (unsigned)w2 < 32u;
                    p[kh * 3 + kw] = ok ? row[w2] : 0.f;
                }
            }
        };
#pragma unroll
        for (int j = 0; j < 9; j++) pl[0][j] = 0.f;  // d=-1 plane
        loadplane(0, pl[1]);
#pragma unroll
        for (int d = 0; d < 8; d++) {
            if (d < 7) loadplane(d + 1, pl[2]);
            else {
#pragma unroll
                for (int j = 0; j < 9; j++) pl[2][j] = 0.f;
            }
            float acc = bv;
#pragma unroll
            for (int kd = 0; kd < 3; kd++)
#pragma unroll
                for (int j = 0; j < 9; j++) acc += wt[kd * 9 + j] * pl[kd][j];
            z[base + d * 1024 + h * 32 + wcol] = acc;
#pragma unroll
            for (int j = 0; j < 9; j++) { pl[0][j] = pl[1][j]; pl[1][j] = pl[2][j]; }
        }
    }
}

// ---------------- pointwise conv via MFMA: out = y + pw_b + W(96x96) * Z(96 x pos) ----------------
__global__ __launch_bounds__(256) void k_pw(const float* __restrict__ z,
                                            const u16* __restrict__ wbf,   // bf16 96x96 row-major
                                            const float* __restrict__ bias,
                                            float* __restrict__ out) {
    __shared__ __align__(16) u16 lZ[128 * 104];
    __shared__ __align__(16) u16 lW[96 * 104];
    const int tid = threadIdx.x;
    const int lane = tid & 63;
    const int wv = tid >> 6;
    const int lr = lane & 15;
    const int lq = lane >> 4;
    const int koff = lq * 8;

    const int idx = blockIdx.x;
    const int q = idx & 7;
    const int bd = idx >> 3;
    const int b = bd >> 3, d = bd & 7;
    const int pos0 = q * 128;

    for (int i = tid; i < 96 * 96; i += 256) {
        int row = i / 96, col = i - row * 96;
        lW[row * 104 + col] = wbf[i];
    }
    {
        const int pos = tid & 127;
        const int cc0 = (tid >> 7) * 48;
        const size_t gbase = ((size_t)b * 96 * 8 + d) * 1024 + pos0 + pos;
#pragma unroll
        for (int g = 0; g < 6; g++) {
            short8 v;
#pragma unroll
            for (int j = 0; j < 8; j++) {
                int cc = cc0 + g * 8 + j;
                v[j] = (short)f2bf(z[gbase + (size_t)cc * 8192]);
            }
            *(short8*)(lZ + pos * 104 + cc0 + g * 8) = v;
        }
    }
    __syncthreads();

    floatx4 acc[6][2];
#pragma unroll
    for (int m = 0; m < 6; m++)
#pragma unroll
        for (int nt = 0; nt < 2; nt++) acc[m][nt] = (floatx4){0.f, 0.f, 0.f, 0.f};

#pragma unroll
    for (int ks = 0; ks < 3; ks++) {
        short8 bfrg[2];
#pragma unroll
        for (int nt = 0; nt < 2; nt++)
            bfrg[nt] = *(const short8*)(lZ + (wv * 32 + nt * 16 + lr) * 104 + ks * 32 + koff);
#pragma unroll
        for (int m = 0; m < 6; m++) {
            short8 afr = *(const short8*)(lW + (m * 16 + lr) * 104 + ks * 32 + koff);
#pragma unroll
            for (int nt = 0; nt < 2; nt++)
                acc[m][nt] = __builtin_amdgcn_mfma_f32_16x16x32_bf16(afr, bfrg[nt], acc[m][nt], 0, 0, 0);
        }
    }

#pragma unroll
    for (int m = 0; m < 6; m++) {
#pragma unroll
        for (int r = 0; r < 4; r++) {
            int c = m * 16 + lq * 4 + r;
            float bv = bias[c];
            size_t rowbase = ((size_t)(b * 96 + c) * 8 + d) * 1024 + pos0;
#pragma unroll
            for (int nt = 0; nt < 2; nt++) {
                int pos = wv * 32 + nt * 16 + lr;
                size_t a = rowbase + pos;
                out[a] = out[a] + bv + acc[m][nt][r];
            }
        }
    }
}

extern "C" void kernel_launch(void* const* d_in, const int* in_sizes, int n_in,
                              void* d_out, int out_size, void* d_ws, size_t ws_size,
                              hipStream_t stream) {
    (void)in_sizes; (void)n_in; (void)out_size; (void)ws_size;
    const float* x      = (const float*)d_in[0];
    const float* pos    = (const float*)d_in[1];
    const float* qkv_w  = (const float*)d_in[2];
    const float* proj_w = (const float*)d_in[3];
    const float* proj_b = (const float*)d_in[4];
    const float* temp   = (const float*)d_in[5];
    const float* ln_g   = (const float*)d_in[6];
    const float* ln_b   = (const float*)d_in[7];
    const float* dw_w   = (const float*)d_in[8];
    const float* dw_b   = (const float*)d_in[9];
    const float* pw_w   = (const float*)d_in[10];
    const float* pw_b   = (const float*)d_in[11];
    float* out = (float*)d_out;
    char* ws = (char*)d_ws;

    u16* t    = (u16*)(ws + 0);           // swiz A, 12.58MB ; later aliased by o (swiz) and z
    u16* vT   = (u16*)(ws + 12582912);    // v swiz, 12.58MB
    u16* q    = (u16*)(ws + 25165824);    // row-major, 12.58MB ; later o2 (with kk)
    u16* kk   = (u16*)(ws + 37748736);    // k swiz, 12.58MB
    u16* wqb  = (u16*)(ws + 50331648);    // qkv_w swiz + proj_w swiz + pw_w, ~4.74MB
    float* cs   = (float*)(ws + 55150592);
    float* sqq  = (float*)(ws + 55175168);
    float* sqk  = (float*)(ws + 55199744);
    float* mu   = (float*)(ws + 55224320);
    float* rstd = (float*)(ws + 55257088);
    u16* wpb  = wqb + 2304 * 768;
    u16* wpwb = wqb + 2304 * 768 + 768 * 768;
    u16* o   = t;
    float* o2 = (float*)q;
    float* z  = (float*)t;
    float* y  = out;

    k_tpos<<<dim3(12, 16, 8), 256, 0, stream>>>(x, pos, t);
    k_cvt<<<1188, 256, 0, stream>>>(qkv_w, proj_w, pw_w, wqb);
    gemm_bt<0><<<1152, 256, 0, stream>>>(t, wqb, 8192, 2304, 768, q, kk, vT, nullptr, nullptr);
    hipMemsetAsync(sqq, 0, 49152, stream);
    k_sq<<<dim3(32, 8), 192, 0, stream>>>(q, kk, sqq, sqk);
    k_scale<<<32, 192, 0, stream>>>(sqq, sqk, temp, cs);
    k_attn<<<512, 128, 0, stream>>>(q, kk, vT, cs, o);
    gemm_bt<1><<<384, 256, 0, stream>>>(o, wpb, 8192, 768, 768, nullptr, nullptr, nullptr, proj_b, o2);
    k_lnstats<<<8192, 256, 0, stream>>>(o2, mu, rstd);
    k_lnt<<<dim3(12, 16, 8), 256, 0, stream>>>(o2, mu, rstd, ln_g, ln_b, x, y);
    k_dw<<<768, 256, 0, stream>>>(y, dw_w, dw_b, z);
    k_pw<<<512, 256, 0, stream>>>(z, wpwb, pw_b, out);
}

// Round 9
// 276.260 us; speedup vs baseline: 1.5549x; 1.0454x over previous
//
#include <hip/hip_runtime.h>

typedef unsigned short u16;
typedef unsigned int u32;

typedef __attribute__((ext_vector_type(8))) short short8;
typedef __attribute__((ext_vector_type(4))) float floatx4;

__device__ __forceinline__ float bf2f(u16 u) { return __uint_as_float(((u32)u) << 16); }
__device__ __forceinline__ u16 f2bf(float f) {
    u32 x = __float_as_uint(f);
    x += 0x7fffu + ((x >> 16) & 1u);
    return (u16)(x >> 16);
}
__device__ __forceinline__ void gl_lds16(const void* g, void* l) {
    __builtin_amdgcn_global_load_lds((const __attribute__((address_space(1))) u32*)g,
                                     (__attribute__((address_space(3))) u32*)l, 16, 0, 0);
}

// Fragment-tiled ("swiz") layouts: data grouped in 1024B chunks of [16 rows x 32 k],
// element order = gl_lds16 lane order: u16 off = chunk*512 + (((k>>3)&3)*16 + (row&15))*8 + (k&7).
// A-operands (t, o): chunk = (row>>4)*24 + (k>>5)   [K=768 -> 24 kchunks]
// W-operands (qkv_w, proj_w): same with row=n.
// K-swiz (per bh, n x dh): chunk = (n>>4)*6 + (dh>>5)
// V-swiz (per bh): chunk = (n>>5)*12 + (dh>>4), lane = ((n>>3)&3)*16 + (dh&15), low3 = n&7

// ---------------- Kernel 1: x (B,C,D,H,W) -> t swiz bf16, + pos ----------------
__global__ __launch_bounds__(256) void k_tpos(const float* __restrict__ x,
                                              const float* __restrict__ pos,
                                              u16* __restrict__ t) {
    __shared__ float tile[64][65];
    const int b = blockIdx.z, hw0 = blockIdx.y * 64, cd0 = blockIdx.x * 64;
    const int tid = threadIdx.x;
#pragma unroll
    for (int i = 0; i < 16; i++) {
        int f = i * 256 + tid;
        int cdl = f >> 6, hwl = f & 63;
        int cd = cd0 + cdl, c = cd >> 3, d = cd & 7;
        tile[cdl][hwl] = x[(size_t)(((b * 96 + c) * 8 + d)) * 1024 + hw0 + hwl];
    }
    __syncthreads();
#pragma unroll
    for (int it = 0; it < 2; it++) {
        int u = it * 256 + tid;       // 512 units of 16B
        int ch = u >> 6, l = u & 63;
        int n16l = ch >> 1, kcl = ch & 1;
        int hwl = n16l * 16 + (l & 15);
        int cdl = kcl * 32 + (l >> 4) * 8;
        int row = b * 1024 + hw0 + hwl;
        int cd = cd0 + cdl;
        const float* pp = pos + (size_t)(hw0 + hwl) * 768 + cd;
        float4 p0 = *(const float4*)pp;
        float4 p1 = *(const float4*)(pp + 4);
        short8 v;
        v[0] = (short)f2bf(tile[cdl + 0][hwl] + p0.x);
        v[1] = (short)f2bf(tile[cdl + 1][hwl] + p0.y);
        v[2] = (short)f2bf(tile[cdl + 2][hwl] + p0.z);
        v[3] = (short)f2bf(tile[cdl + 3][hwl] + p0.w);
        v[4] = (short)f2bf(tile[cdl + 4][hwl] + p1.x);
        v[5] = (short)f2bf(tile[cdl + 5][hwl] + p1.y);
        v[6] = (short)f2bf(tile[cdl + 6][hwl] + p1.z);
        v[7] = (short)f2bf(tile[cdl + 7][hwl] + p1.w);
        size_t chunk = (size_t)(row >> 4) * 24 + (cd >> 5);
        *(short8*)(t + chunk * 512 + l * 8) = v;
    }
}

// ---------------- weight cvt: qkv_w swiz, proj_w swiz, pw_w row-major ----------------
__global__ __launch_bounds__(256) void k_cvt(const float* __restrict__ wq,
                                             const float* __restrict__ wp,
                                             const float* __restrict__ wpw,
                                             u16* __restrict__ out) {
    const int NQ = 144 * 24 * 64;          // qkv 16B-units
    const int NP = NQ + 48 * 24 * 64;      // + proj 16B-units
    int u = blockIdx.x * 256 + threadIdx.x;
    if (u < NP) {
        const float* w = (u < NQ) ? wq : wp;
        int ub = (u < NQ) ? u : u - NQ;
        int chunk = ub >> 6, l = ub & 63;
        int n16 = chunk / 24, kc = chunk - n16 * 24;
        int n = n16 * 16 + (l & 15);
        int k0 = kc * 32 + (l >> 4) * 8;
        const float* src = w + (size_t)n * 768 + k0;
        float4 a = *(const float4*)src;
        float4 b2 = *(const float4*)(src + 4);
        short8 v;
        v[0] = (short)f2bf(a.x);  v[1] = (short)f2bf(a.y);
        v[2] = (short)f2bf(a.z);  v[3] = (short)f2bf(a.w);
        v[4] = (short)f2bf(b2.x); v[5] = (short)f2bf(b2.y);
        v[6] = (short)f2bf(b2.z); v[7] = (short)f2bf(b2.w);
        *(short8*)(out + (size_t)u * 8) = v;
    } else {
        int i = u - NP;  // 9216 pw elements
        out[(size_t)NP * 8 + i] = f2bf(wpw[i]);
    }
}

// ---------------- GEMM: C(M,N) = A_swiz(M,K) * W_swiz(N,K)^T, bf16 MFMA ----------------
// BK=64, XCD-pinned swizzle. MODE 0 k/v epilogue staged through LDS -> 1024B coalesced stores.
// Fused stats: MODE 0 accumulates column sum-of-squares (q,k) into sqa/ska (replaces k_sq);
// MODE 1 accumulates row sum / sum-of-squares into musum/sqsum (replaces k_lnstats).
template <int MODE>
__global__ __launch_bounds__(256) void gemm_bt(const u16* __restrict__ A,
                                               const u16* __restrict__ Bw,
                                               int M, int N, int K,
                                               u16* __restrict__ qo, u16* __restrict__ ko,
                                               u16* __restrict__ vo,
                                               const float* __restrict__ bias,
                                               float* __restrict__ Co,
                                               float* __restrict__ sqa,
                                               float* __restrict__ ska,
                                               float* __restrict__ musum,
                                               float* __restrict__ sqsum) {
    __shared__ __align__(16) u16 lAB[32 * 512];  // 32KB: lA = [0..16), lB = [16..32) chunks
    u16* lA = lAB;
    u16* lB = lAB + 16 * 512;
    const int tid = threadIdx.x;
    const int lane = tid & 63;
    const int wv = tid >> 6;
    const int wr = wv >> 1, wc = wv & 1;
    const int ntiles = N >> 7;
    const int mtiles = M >> 7;                 // 64
    const int lin = blockIdx.x;
    const int xcd = lin & 7;
    const int idx = lin >> 3;
    const int mlocal = idx / ntiles;
    const int ntile = idx - mlocal * ntiles;
    const int m0 = (xcd * (mtiles >> 3) + mlocal) << 7;
    const int n0 = ntile << 7;
    const int lr = lane & 15;
    const int lq = lane >> 4;

    floatx4 acc[4][4];
#pragma unroll
    for (int i = 0; i < 4; i++)
#pragma unroll
        for (int j = 0; j < 4; j++) acc[i][j] = (floatx4){0.f, 0.f, 0.f, 0.f};

    const int m16 = m0 >> 4, n16 = n0 >> 4;
    for (int kc2 = 0; kc2 < (K >> 6); kc2++) {
        __syncthreads();
#pragma unroll
        for (int kh = 0; kh < 2; kh++) {
#pragma unroll
            for (int i = 0; i < 2; i++) {
                int ch16 = i * 4 + wv;       // 16-row block of the 128-row tile
                int kc = kc2 * 2 + kh;
                const u16* ga = A + ((size_t)(m16 + ch16) * 24 + kc) * 512 + lane * 8;
                gl_lds16(ga, (char*)lA + (kh * 8 + ch16) * 1024);
                const u16* gb = Bw + ((size_t)(n16 + ch16) * 24 + kc) * 512 + lane * 8;
                gl_lds16(gb, (char*)lB + (kh * 8 + ch16) * 1024);
            }
        }
        __syncthreads();
#pragma unroll
        for (int kh = 0; kh < 2; kh++) {
            short8 af[4], bfr[4];
#pragma unroll
            for (int tt = 0; tt < 4; tt++) {
                af[tt] = *(const short8*)(lA + ((kh * 8 + wr * 4 + tt) * 64 + lane) * 8);
                bfr[tt] = *(const short8*)(lB + ((kh * 8 + wc * 4 + tt) * 64 + lane) * 8);
            }
#pragma unroll
            for (int mt = 0; mt < 4; mt++)
#pragma unroll
                for (int nt = 0; nt < 4; nt++)
                    acc[mt][nt] = __builtin_amdgcn_mfma_f32_16x16x32_bf16(af[mt], bfr[nt], acc[mt][nt], 0, 0, 0);
        }
    }

    if (MODE == 0) {
        const int region = n0 / 768;       // whole block is q, k, or v
        const int n0r = n0 - region * 768;
        const int bb0 = m0 >> 10;
        // fused column sum-of-squares for q (region 0) and k (region 1)
        if (region < 2) {
            float* dst = (region == 0) ? sqa : ska;
#pragma unroll
            for (int nt = 0; nt < 4; nt++) {
                int colb = n0r + wc * 64 + nt * 16;
                int h = colb / 192;
                int dh = colb - h * 192 + lr;
                float s = 0.f;
#pragma unroll
                for (int mt = 0; mt < 4; mt++)
#pragma unroll
                    for (int r = 0; r < 4; r++) s += acc[mt][nt][r] * acc[mt][nt][r];
                s += __shfl_xor(s, 16);
                s += __shfl_xor(s, 32);
                if (lq == 0) atomicAdd(&dst[(bb0 * 4 + h) * 192 + dh], s);
            }
        }
        if (region == 0) {
            // q: direct row-major stores (32B segments)
#pragma unroll
            for (int nt = 0; nt < 4; nt++) {
                int colb = n0r + wc * 64 + nt * 16;
                int h = colb / 192;
                int dh = colb - h * 192 + lr;
#pragma unroll
                for (int mt = 0; mt < 4; mt++) {
#pragma unroll
                    for (int r = 0; r < 4; r++) {
                        int row = m0 + wr * 64 + mt * 16 + lq * 4 + r;
                        int b = row >> 10, n = row & 1023;
                        qo[((size_t)(b * 4 + h) * 1024 + n) * 192 + dh] = f2bf(acc[mt][nt][r]);
                    }
                }
            }
        } else {
            // k/v: stage the 128x128 bf16 tile in LDS at swiz-exact offsets, bulk-copy out
            __syncthreads();
            if (region == 1) {
#pragma unroll
                for (int nt = 0; nt < 4; nt++) {
                    int lch = wc * 2 + (nt >> 1);
                    int offbase = (((nt & 1) * 2 + (lr >> 3)) * 16) * 8 + (lr & 7);
#pragma unroll
                    for (int mt = 0; mt < 4; mt++) {
                        u16* cp2 = lAB + (((wr * 4 + mt) * 4 + lch) * 512);
#pragma unroll
                        for (int r = 0; r < 4; r++)
                            cp2[offbase + (lq * 4 + r) * 8] = f2bf(acc[mt][nt][r]);
                    }
                }
            } else {
#pragma unroll
                for (int nt = 0; nt < 4; nt++) {
#pragma unroll
                    for (int mt = 0; mt < 4; mt++) {
                        u16* cp2 = lAB + (((wr * 2 + (mt >> 1)) * 8 + wc * 4 + nt) * 512);
                        int ob = (((mt & 1) * 2 + (lq >> 1)) * 16 + lr) * 8 + (lq & 1) * 4;
#pragma unroll
                        for (int r = 0; r < 4; r++)
                            cp2[ob + r] = f2bf(acc[mt][nt][r]);
                    }
                }
            }
            __syncthreads();
            const int b = m0 >> 10;
            const int ml = m0 & 1023;
#pragma unroll
            for (int i = 0; i < 8; i++) {
                int ci = wv * 8 + i;
                short8 val = *(const short8*)(lAB + ci * 512 + lane * 8);
                if (region == 1) {
                    int a = ci >> 2, bb = ci & 3;
                    int cg = n0r + bb * 32;
                    int h = cg / 192;
                    int dh32 = (cg - h * 192) >> 5;
                    size_t gaddr = (size_t)(b * 4 + h) * 196608 +
                                   (size_t)((((ml >> 4) + a) * 6 + dh32)) * 512 + lane * 8;
                    *(short8*)(ko + gaddr) = val;
                } else {
                    int a = ci >> 3, bb = ci & 7;
                    int cg = n0r + bb * 16;
                    int h = cg / 192;
                    int dh16 = (cg - h * 192) >> 4;
                    size_t gaddr = (size_t)(b * 4 + h) * 196608 +
                                   (size_t)((((ml >> 5) + a) * 12 + dh16)) * 512 + lane * 8;
                    *(short8*)(vo + gaddr) = val;
                }
            }
        }
    } else {
        float bvv[4];
#pragma unroll
        for (int nt = 0; nt < 4; nt++) bvv[nt] = bias[n0 + wc * 64 + nt * 16 + lr];
#pragma unroll
        for (int nt = 0; nt < 4; nt++) {
            int col = n0 + wc * 64 + nt * 16 + lr;
#pragma unroll
            for (int mt = 0; mt < 4; mt++) {
#pragma unroll
                for (int r = 0; r < 4; r++) {
                    int row = m0 + wr * 64 + mt * 16 + lq * 4 + r;
                    Co[(size_t)row * N + col] = acc[mt][nt][r] + bvv[nt];
                }
            }
        }
        // fused LN row stats: sum and sum-of-squares over this block's 128 cols
#pragma unroll
        for (int mt = 0; mt < 4; mt++) {
#pragma unroll
            for (int r = 0; r < 4; r++) {
                float s = 0.f, ss = 0.f;
#pragma unroll
                for (int nt = 0; nt < 4; nt++) {
                    float v = acc[mt][nt][r] + bvv[nt];
                    s += v;
                    ss += v * v;
                }
#pragma unroll
                for (int m = 1; m < 16; m <<= 1) {
                    s += __shfl_xor(s, m);
                    ss += __shfl_xor(ss, m);
                }
                if (lr == 0) {
                    int row = m0 + wr * 64 + mt * 16 + lq * 4 + r;
                    atomicAdd(&musum[row], s);
                    atomicAdd(&sqsum[row], ss);
                }
            }
        }
    }
}

__global__ void k_scale(const float* __restrict__ sqq, const float* __restrict__ sqk,
                        const float* __restrict__ temp, float* __restrict__ cs) {
    int bh = blockIdx.x;
    int dh = threadIdx.x;
    float rq = 1.f / fmaxf(sqrtf(sqq[bh * 192 + dh]), 1e-12f);
    float rk = 1.f / fmaxf(sqrtf(sqk[bh * 192 + dh]), 1e-12f);
    cs[bh * 192 + dh] = rq * rk * temp[bh & 3];
}

// ---------------- LN stats finalize: sums -> mu, rstd ----------------
__global__ __launch_bounds__(256) void k_lnfin(const float* __restrict__ musum,
                                               const float* __restrict__ sqsum,
                                               float* __restrict__ mu,
                                               float* __restrict__ rstd) {
    int row = blockIdx.x * 256 + threadIdx.x;
    float m_ = musum[row] * (1.f / 768.f);
    float v = sqsum[row] * (1.f / 768.f) - m_ * m_;
    v = fmaxf(v, 0.f);
    mu[row] = m_;
    rstd[row] = rsqrtf(v + 1e-5f);
}

// ---------------- flash attention: 2-wave blocks, 32 q-rows/wave (2 tiles), no-max softmax ----
__global__ __launch_bounds__(128) void k_attn(const u16* __restrict__ q,
                                              const u16* __restrict__ kmat,
                                              const u16* __restrict__ vT,
                                              const float* __restrict__ cs,
                                              u16* __restrict__ o) {
    __shared__ __align__(16) u16 lK[24 * 512];
    __shared__ __align__(16) u16 lV[24 * 512];
    __shared__ __align__(16) u16 lP[2 * 2048];  // per-wave 2 P-tiles
    const int lin = blockIdx.x;
    const int qb = (lin >> 3) & 15;
    const int bh = (lin & 7) * 4 + (lin >> 7);
    const int b = bh >> 2, h = bh & 3;
    const int tid = threadIdx.x;
    const int lane = tid & 63;
    const int wv = tid >> 6;   // 0..1
    const int lr = lane & 15;
    const int lq = lane >> 4;
    const int koff = lq * 8;

    const u16* qbase = q + (size_t)bh * 1024 * 192;
    const u16* kbase = kmat + (size_t)bh * 196608;
    const u16* vbase = vT + (size_t)bh * 196608;
    const float* cp = cs + bh * 192;

    // Q fragments for the wave's 2 row-tiles, pre-scaled
    short8 qf[2][6];
#pragma unroll
    for (int t = 0; t < 2; t++) {
        const int qrow = qb * 64 + wv * 32 + t * 16 + lr;
        const u16* qp = qbase + (size_t)qrow * 192;
#pragma unroll
        for (int ks = 0; ks < 6; ks++) {
            short8 raw = *(const short8*)(qp + ks * 32 + koff);
            short8 sc;
#pragma unroll
            for (int j = 0; j < 8; j++) {
                float f = bf2f((u16)raw[j]) * cp[ks * 32 + koff + j];
                sc[j] = (short)f2bf(f);
            }
            qf[t][ks] = sc;
        }
    }

    float l_r[2][4];
    floatx4 oacc[2][12];
#pragma unroll
    for (int t = 0; t < 2; t++) {
#pragma unroll
        for (int r = 0; r < 4; r++) l_r[t][r] = 0.f;
#pragma unroll
        for (int vt = 0; vt < 12; vt++) oacc[t][vt] = (floatx4){0.f, 0.f, 0.f, 0.f};
    }

    u16* lp = lP + wv * 2048;

    for (int kb = 0; kb < 16; kb++) {
        __syncthreads();
        // stage 24 K chunks + 24 V chunks with 2 waves
#pragma unroll
        for (int i = 0; i < 12; i++) {
            int ch = i * 2 + wv;  // 0..23
            int ks = ch >> 2, nt = ch & 3;
            const u16* gk = kbase + ((size_t)(kb * 4 + nt) * 6 + ks) * 512 + lane * 8;
            gl_lds16(gk, (char*)lK + ch * 1024);
            int ks2 = ch / 12, vt2 = ch - ks2 * 12;
            const u16* gv = vbase + ((size_t)(kb * 2 + ks2) * 12 + vt2) * 512 + lane * 8;
            gl_lds16(gv, (char*)lV + ch * 1024);
        }
        __syncthreads();

        // S = Qs * K^T for both row-tiles; each kf read feeds 2 MFMAs
        floatx4 s0[4], s1[4];
#pragma unroll
        for (int nt = 0; nt < 4; nt++) {
            s0[nt] = (floatx4){0.f, 0.f, 0.f, 0.f};
            s1[nt] = (floatx4){0.f, 0.f, 0.f, 0.f};
        }
#pragma unroll
        for (int ks = 0; ks < 6; ks++) {
#pragma unroll
            for (int nt = 0; nt < 4; nt++) {
                short8 kf = *(const short8*)(lK + ((ks * 4 + nt) * 64 + lane) * 8);
                s0[nt] = __builtin_amdgcn_mfma_f32_16x16x32_bf16(qf[0][ks], kf, s0[nt], 0, 0, 0);
                s1[nt] = __builtin_amdgcn_mfma_f32_16x16x32_bf16(qf[1][ks], kf, s1[nt], 0, 0, 0);
            }
        }

        // exp (no max shift) + row-sum + P write (A-frag order), both tiles
        float rs0[4] = {0.f, 0.f, 0.f, 0.f}, rs1[4] = {0.f, 0.f, 0.f, 0.f};
#pragma unroll
        for (int nt = 0; nt < 4; nt++)
#pragma unroll
            for (int r = 0; r < 4; r++) {
                float p0 = __expf(s0[nt][r]);
                s0[nt][r] = p0;
                rs0[r] += p0;
                float p1 = __expf(s1[nt][r]);
                s1[nt][r] = p1;
                rs1[r] += p1;
            }
#pragma unroll
        for (int m = 1; m < 16; m <<= 1)
#pragma unroll
            for (int r = 0; r < 4; r++) {
                rs0[r] += __shfl_xor(rs0[r], m);
                rs1[r] += __shfl_xor(rs1[r], m);
            }
#pragma unroll
        for (int r = 0; r < 4; r++) {
            l_r[0][r] += rs0[r];
            l_r[1][r] += rs1[r];
        }
#pragma unroll
        for (int nt = 0; nt < 4; nt++) {
            int base2 = (nt >> 1) * 512 + ((nt & 1) * 2 + (lr >> 3)) * 128 + (lr & 7);
#pragma unroll
            for (int r = 0; r < 4; r++) {
                lp[base2 + (lq * 4 + r) * 8] = f2bf(s0[nt][r]);
                lp[1024 + base2 + (lq * 4 + r) * 8] = f2bf(s1[nt][r]);
            }
        }

        // O += P * V; each vf read feeds 2 MFMAs
#pragma unroll
        for (int ks2 = 0; ks2 < 2; ks2++) {
            short8 pf0 = *(const short8*)(lp + ks2 * 512 + lane * 8);
            short8 pf1 = *(const short8*)(lp + 1024 + ks2 * 512 + lane * 8);
#pragma unroll
            for (int vt = 0; vt < 12; vt++) {
                short8 vf = *(const short8*)(lV + ((ks2 * 12 + vt) * 64 + lane) * 8);
                oacc[0][vt] = __builtin_amdgcn_mfma_f32_16x16x32_bf16(pf0, vf, oacc[0][vt], 0, 0, 0);
                oacc[1][vt] = __builtin_amdgcn_mfma_f32_16x16x32_bf16(pf1, vf, oacc[1][vt], 0, 0, 0);
            }
        }
    }

    // epilogue: divide by l, write o in swiz (A-operand) layout for proj gemm
#pragma unroll
    for (int t = 0; t < 2; t++) {
        float inv[4];
#pragma unroll
        for (int r = 0; r < 4; r++) inv[r] = 1.f / l_r[t][r];
#pragma unroll
        for (int vt = 0; vt < 12; vt++) {
            int col = h * 192 + vt * 16 + lr;
#pragma unroll
            for (int r = 0; r < 4; r++) {
                int rowg = b * 1024 + qb * 64 + wv * 32 + t * 16 + lq * 4 + r;
                size_t addr = (size_t)(rowg >> 4) * 12288 + (col >> 5) * 512 +
                              ((col >> 3) & 3) * 128 + (rowg & 15) * 8 + (col & 7);
                o[addr] = f2bf(oacc[t][vt][r] * inv[r]);
            }
        }
    }
}

// ---------------- LN apply + transpose back + residual: y = LN(o2)^T + x ----------------
__global__ __launch_bounds__(256) void k_lnt(const float* __restrict__ o2,
                                             const float* __restrict__ mu,
                                             const float* __restrict__ rstd,
                                             const float* __restrict__ gamma,
                                             const float* __restrict__ beta,
                                             const float* __restrict__ x,
                                             float* __restrict__ y) {
    __shared__ float tile[64][65];
    const int b = blockIdx.z, hw0 = blockIdx.y * 64, cd0 = blockIdx.x * 64;
    const int tid = threadIdx.x;
#pragma unroll
    for (int i = 0; i < 16; i++) {
        int f = i * 256 + tid;
        int hwl = f >> 6, cdl = f & 63;
        int row = b * 1024 + hw0 + hwl;
        float v = o2[(size_t)row * 768 + cd0 + cdl];
        v = (v - mu[row]) * rstd[row] * gamma[cd0 + cdl] + beta[cd0 + cdl];
        tile[hwl][cdl] = v;
    }
    __syncthreads();
#pragma unroll
    for (int i = 0; i < 16; i++) {
        int f = i * 256 + tid;
        int cdl = f >> 6, hwl = f & 63;
        int cd = cd0 + cdl, c = cd >> 3, d = cd & 7;
        size_t addr = (size_t)((b * 96 + c) * 8 + d) * 1024 + hw0 + hwl;
        y[addr] = tile[hwl][cdl] + x[addr];
    }
}

// ---------------- depthwise 3x3x3 conv: LDS-staged channel + rolling d-window ----------------
__global__ __launch_bounds__(256) void k_dw(const float* __restrict__ y,
                                            const float* __restrict__ w,
                                            const float* __restrict__ bias,
                                            float* __restrict__ z) {
    __shared__ float ly[8192];  // [d][h][w]
    const int bc = blockIdx.x;
    const int c = bc % 96;
    const int tid = threadIdx.x;
    const size_t base = (size_t)bc * 8192;

#pragma unroll
    for (int i = 0; i < 8; i++) {
        int i4 = i * 256 + tid;
        *(float4*)(ly + i4 * 4) = *(const float4*)(y + base + i4 * 4);
    }
    float wt[27];
#pragma unroll
    for (int j = 0; j < 27; j++) wt[j] = w[c * 27 + j];
    const float bv = bias[c];
    __syncthreads();

    const int wcol = tid & 31;
    const int hh = tid >> 5;  // 0..7

    for (int hb = 0; hb < 4; hb++) {
        const int h = hb * 8 + hh;
        float pl[3][9];
        auto loadplane = [&](int dd, float* p) {
#pragma unroll
            for (int kh = 0; kh < 3; kh++) {
                int h2 = h + kh - 1;
                bool hok = (unsigned)h2 < 32u;
                const float* row = ly + dd * 1024 + h2 * 32;
#pragma unroll
                for (int kw = 0; kw < 3; kw++) {
                    int w2 = wcol + kw - 1;
                    bool ok = hok && (unsigned)w2 < 32u;
                    p[kh * 3 + kw] = ok ? row[w2] : 0.f;
                }
            }
        };
#pragma unroll
        for (int j = 0; j < 9; j++) pl[0][j] = 0.f;  // d=-1 plane
        loadplane(0, pl[1]);
#pragma unroll
        for (int d = 0; d < 8; d++) {
            if (d < 7) loadplane(d + 1, pl[2]);
            else {
#pragma unroll
                for (int j = 0; j < 9; j++) pl[2][j] = 0.f;
            }
            float acc = bv;
#pragma unroll
            for (int kd = 0; kd < 3; kd++)
#pragma unroll
                for (int j = 0; j < 9; j++) acc += wt[kd * 9 + j] * pl[kd][j];
            z[base + d * 1024 + h * 32 + wcol] = acc;
#pragma unroll
            for (int j = 0; j < 9; j++) { pl[0][j] = pl[1][j]; pl[1][j] = pl[2][j]; }
        }
    }
}

// ---------------- pointwise conv via MFMA: out = y + pw_b + W(96x96) * Z(96 x pos) ----------------
__global__ __launch_bounds__(256) void k_pw(const float* __restrict__ z,
                                            const u16* __restrict__ wbf,   // bf16 96x96 row-major
                                            const float* __restrict__ bias,
                                            float* __restrict__ out) {
    __shared__ __align__(16) u16 lZ[128 * 104];
    __shared__ __align__(16) u16 lW[96 * 104];
    const int tid = threadIdx.x;
    const int lane = tid & 63;
    const int wv = tid >> 6;
    const int lr = lane & 15;
    const int lq = lane >> 4;
    const int koff = lq * 8;

    const int idx = blockIdx.x;
    const int q = idx & 7;
    const int bd = idx >> 3;
    const int b = bd >> 3, d = bd & 7;
    const int pos0 = q * 128;

    for (int i = tid; i < 96 * 96; i += 256) {
        int row = i / 96, col = i - row * 96;
        lW[row * 104 + col] = wbf[i];
    }
    {
        const int pos = tid & 127;
        const int cc0 = (tid >> 7) * 48;
        const size_t gbase = ((size_t)b * 96 * 8 + d) * 1024 + pos0 + pos;
#pragma unroll
        for (int g = 0; g < 6; g++) {
            short8 v;
#pragma unroll
            for (int j = 0; j < 8; j++) {
                int cc = cc0 + g * 8 + j;
                v[j] = (short)f2bf(z[gbase + (size_t)cc * 8192]);
            }
            *(short8*)(lZ + pos * 104 + cc0 + g * 8) = v;
        }
    }
    __syncthreads();

    floatx4 acc[6][2];
#pragma unroll
    for (int m = 0; m < 6; m++)
#pragma unroll
        for (int nt = 0; nt < 2; nt++) acc[m][nt] = (floatx4){0.f, 0.f, 0.f, 0.f};

#pragma unroll
    for (int ks = 0; ks < 3; ks++) {
        short8 bfrg[2];
#pragma unroll
        for (int nt = 0; nt < 2; nt++)
            bfrg[nt] = *(const short8*)(lZ + (wv * 32 + nt * 16 + lr) * 104 + ks * 32 + koff);
#pragma unroll
        for (int m = 0; m < 6; m++) {
            short8 afr = *(const short8*)(lW + (m * 16 + lr) * 104 + ks * 32 + koff);
#pragma unroll
            for (int nt = 0; nt < 2; nt++)
                acc[m][nt] = __builtin_amdgcn_mfma_f32_16x16x32_bf16(afr, bfrg[nt], acc[m][nt], 0, 0, 0);
        }
    }

#pragma unroll
    for (int m = 0; m < 6; m++) {
#pragma unroll
        for (int r = 0; r < 4; r++) {
            int c = m * 16 + lq * 4 + r;
            float bv = bias[c];
            size_t rowbase = ((size_t)(b * 96 + c) * 8 + d) * 1024 + pos0;
#pragma unroll
            for (int nt = 0; nt < 2; nt++) {
                int pos = wv * 32 + nt * 16 + lr;
                size_t a = rowbase + pos;
                out[a] = out[a] + bv + acc[m][nt][r];
            }
        }
    }
}

extern "C" void kernel_launch(void* const* d_in, const int* in_sizes, int n_in,
                              void* d_out, int out_size, void* d_ws, size_t ws_size,
                              hipStream_t stream) {
    (void)in_sizes; (void)n_in; (void)out_size; (void)ws_size;
    const float* x      = (const float*)d_in[0];
    const float* pos    = (const float*)d_in[1];
    const float* qkv_w  = (const float*)d_in[2];
    const float* proj_w = (const float*)d_in[3];
    const float* proj_b = (const float*)d_in[4];
    const float* temp   = (const float*)d_in[5];
    const float* ln_g   = (const float*)d_in[6];
    const float* ln_b   = (const float*)d_in[7];
    const float* dw_w   = (const float*)d_in[8];
    const float* dw_b   = (const float*)d_in[9];
    const float* pw_w   = (const float*)d_in[10];
    const float* pw_b   = (const float*)d_in[11];
    float* out = (float*)d_out;
    char* ws = (char*)d_ws;

    u16* t    = (u16*)(ws + 0);           // swiz A, 12.58MB ; later aliased by o (swiz) and z
    u16* vT   = (u16*)(ws + 12582912);    // v swiz, 12.58MB
    u16* q    = (u16*)(ws + 25165824);    // row-major, 12.58MB ; later o2 (with kk)
    u16* kk   = (u16*)(ws + 37748736);    // k swiz, 12.58MB
    u16* wqb  = (u16*)(ws + 50331648);    // qkv_w swiz + proj_w swiz + pw_w, ~4.74MB
    float* cs    = (float*)(ws + 55150592);
    float* sqq   = (float*)(ws + 55175168);
    float* sqk   = (float*)(ws + 55199744);
    float* musum = (float*)(ws + 55224320);
    float* sqsum = (float*)(ws + 55257088);
    float* mu    = (float*)(ws + 55289856);
    float* rstd  = (float*)(ws + 55322624);
    u16* wpb  = wqb + 2304 * 768;
    u16* wpwb = wqb + 2304 * 768 + 768 * 768;
    u16* o   = t;
    float* o2 = (float*)q;
    float* z  = (float*)t;
    float* y  = out;

    k_tpos<<<dim3(12, 16, 8), 256, 0, stream>>>(x, pos, t);
    k_cvt<<<1188, 256, 0, stream>>>(qkv_w, proj_w, pw_w, wqb);
    hipMemsetAsync(sqq, 0, 114688, stream);  // sqq + sqk + musum + sqsum
    gemm_bt<0><<<1152, 256, 0, stream>>>(t, wqb, 8192, 2304, 768, q, kk, vT, nullptr, nullptr,
                                         sqq, sqk, nullptr, nullptr);
    k_scale<<<32, 192, 0, stream>>>(sqq, sqk, temp, cs);
    k_attn<<<512, 128, 0, stream>>>(q, kk, vT, cs, o);
    gemm_bt<1><<<384, 256, 0, stream>>>(o, wpb, 8192, 768, 768, nullptr, nullptr, nullptr, proj_b,
                                        o2, nullptr, nullptr, musum, sqsum);
    k_lnfin<<<32, 256, 0, stream>>>(musum, sqsum, mu, rstd);
    k_lnt<<<dim3(12, 16, 8), 256, 0, stream>>>(o2, mu, rstd, ln_g, ln_b, x, y);
    k_dw<<<768, 256, 0, stream>>>(y, dw_w, dw_b, z);
    k_pw<<<512, 256, 0, stream>>>(z, wpwb, pw_b, out);
}